// Round 16
// baseline (1397.372 us; speedup 1.0000x reference)
//
#include <hip/hip_runtime.h>
#include <hip/hip_bf16.h>
#include <cstdint>
#include <cstddef>

// Problem constants
#define BB 4
#define SS 256
#define ID 512
#define HD 1024
#define MD 256
#define NKEY 65536
#define OD 512
#define ROWS 1024          // B*S
#define NWG_LSTM 256
#define NTH_LSTM 256
#define KPB 1024           // keys per sim block
#define KSPLITS (NKEY / KPB)   // 64

typedef __attribute__((ext_vector_type(8))) short bf16x8;
typedef __attribute__((ext_vector_type(4))) float f32x4;
typedef __attribute__((ext_vector_type(8))) unsigned short u16x8;

// ---------------------------------------------------------------------------
// Generic SGEMM: C[M,N] = A[M,K] * Bm[N,K]^T (+bias) or C += ...
// 64x64 tile, 256 threads, 4x4 micro-tile. Grid: (N/64, M/64).
// ---------------------------------------------------------------------------
__global__ __launch_bounds__(256) void sgemm_nt(
    const float* __restrict__ A, int lda,
    const float* __restrict__ Bm, int ldb,
    float* __restrict__ C, int ldc, int K,
    const float* __restrict__ bias, const float* __restrict__ bias2,
    int accum)
{
    __shared__ float As[64][17];
    __shared__ float Bs[64][17];
    const int t = threadIdx.x;
    const int tx = t & 15, ty = t >> 4;
    const int bm = blockIdx.y << 6, bn = blockIdx.x << 6;
    const int lrow = t >> 2, lk4 = (t & 3) << 2;
    float acc[4][4] = {};

    for (int kb = 0; kb < K; kb += 16) {
        const float4 av = *(const float4*)&A[(size_t)(bm + lrow) * lda + kb + lk4];
        const float4 bv = *(const float4*)&Bm[(size_t)(bn + lrow) * ldb + kb + lk4];
        __syncthreads();
        As[lrow][lk4 + 0] = av.x; As[lrow][lk4 + 1] = av.y;
        As[lrow][lk4 + 2] = av.z; As[lrow][lk4 + 3] = av.w;
        Bs[lrow][lk4 + 0] = bv.x; Bs[lrow][lk4 + 1] = bv.y;
        Bs[lrow][lk4 + 2] = bv.z; Bs[lrow][lk4 + 3] = bv.w;
        __syncthreads();
#pragma unroll
        for (int k = 0; k < 16; ++k) {
            const float a0 = As[4 * ty + 0][k], a1 = As[4 * ty + 1][k];
            const float a2 = As[4 * ty + 2][k], a3 = As[4 * ty + 3][k];
            const float b0 = Bs[4 * tx + 0][k], b1 = Bs[4 * tx + 1][k];
            const float b2 = Bs[4 * tx + 2][k], b3 = Bs[4 * tx + 3][k];
            acc[0][0] += a0 * b0; acc[0][1] += a0 * b1; acc[0][2] += a0 * b2; acc[0][3] += a0 * b3;
            acc[1][0] += a1 * b0; acc[1][1] += a1 * b1; acc[1][2] += a1 * b2; acc[1][3] += a1 * b3;
            acc[2][0] += a2 * b0; acc[2][1] += a2 * b1; acc[2][2] += a2 * b2; acc[2][3] += a2 * b3;
            acc[3][0] += a3 * b0; acc[3][1] += a3 * b1; acc[3][2] += a3 * b2; acc[3][3] += a3 * b3;
        }
    }

#pragma unroll
    for (int i = 0; i < 4; ++i) {
        const int row = bm + 4 * ty + i;
        const int col = bn + 4 * tx;
        float4* cp = (float4*)&C[(size_t)row * ldc + col];
        float4 r;
        if (accum) {
            const float4 old = *cp;
            r.x = old.x + acc[i][0]; r.y = old.y + acc[i][1];
            r.z = old.z + acc[i][2]; r.w = old.w + acc[i][3];
        } else {
            float bx = bias[col + 0], by = bias[col + 1], bz = bias[col + 2], bw = bias[col + 3];
            if (bias2) { bx += bias2[col + 0]; by += bias2[col + 1]; bz += bias2[col + 2]; bw += bias2[col + 3]; }
            r.x = acc[i][0] + bx; r.y = acc[i][1] + by;
            r.z = acc[i][2] + bz; r.w = acc[i][3] + bw;
        }
        *cp = r;
    }
}

// ---------------------------------------------------------------------------
// x_proj GEMM: C[1024,4096] = A[1024,512] @ Bm[4096,512]^T + bias1 + bias2.
// 64(M) x 128(N) tile, 256 threads, micro 4x8, k-major LDS. Grid (32, 16).
// ---------------------------------------------------------------------------
__global__ __launch_bounds__(256) void sgemm_nt_w(
    const float* __restrict__ A, const float* __restrict__ Bm,
    float* __restrict__ C, const float* __restrict__ bias, const float* __restrict__ bias2)
{
    __shared__ float As[16][64];
    __shared__ float Bs[16][128];
    const int t = threadIdx.x;
    const int tx = t & 15, ty = t >> 4;
    const int bm = blockIdx.y << 6, bn = blockIdx.x << 7;
    const int arow = t & 63, akq = t >> 6;       // A: 1 float4 per thread
    const int brow = t & 127, bkq = t >> 7;      // B: 2 float4 per thread
    float acc[4][8] = {};

    for (int kb = 0; kb < 512; kb += 16) {
        const float4 av  = *(const float4*)&A[(size_t)(bm + arow) * 512 + kb + (akq << 2)];
        const float4 bv0 = *(const float4*)&Bm[(size_t)(bn + brow) * 512 + kb + (bkq << 3)];
        const float4 bv1 = *(const float4*)&Bm[(size_t)(bn + brow) * 512 + kb + (bkq << 3) + 4];
        __syncthreads();
        As[(akq << 2) + 0][arow] = av.x; As[(akq << 2) + 1][arow] = av.y;
        As[(akq << 2) + 2][arow] = av.z; As[(akq << 2) + 3][arow] = av.w;
        Bs[(bkq << 3) + 0][brow] = bv0.x; Bs[(bkq << 3) + 1][brow] = bv0.y;
        Bs[(bkq << 3) + 2][brow] = bv0.z; Bs[(bkq << 3) + 3][brow] = bv0.w;
        Bs[(bkq << 3) + 4][brow] = bv1.x; Bs[(bkq << 3) + 5][brow] = bv1.y;
        Bs[(bkq << 3) + 6][brow] = bv1.z; Bs[(bkq << 3) + 7][brow] = bv1.w;
        __syncthreads();
#pragma unroll
        for (int k = 0; k < 16; ++k) {
            const float4 a  = *(const float4*)&As[k][ty << 2];
            const float4 b0 = *(const float4*)&Bs[k][tx << 3];
            const float4 b1 = *(const float4*)&Bs[k][(tx << 3) + 4];
            acc[0][0] += a.x * b0.x; acc[0][1] += a.x * b0.y; acc[0][2] += a.x * b0.z; acc[0][3] += a.x * b0.w;
            acc[0][4] += a.x * b1.x; acc[0][5] += a.x * b1.y; acc[0][6] += a.x * b1.z; acc[0][7] += a.x * b1.w;
            acc[1][0] += a.y * b0.x; acc[1][1] += a.y * b0.y; acc[1][2] += a.y * b0.z; acc[1][3] += a.y * b0.w;
            acc[1][4] += a.y * b1.x; acc[1][5] += a.y * b1.y; acc[1][6] += a.y * b1.z; acc[1][7] += a.y * b1.w;
            acc[2][0] += a.z * b0.x; acc[2][1] += a.z * b0.y; acc[2][2] += a.z * b0.z; acc[2][3] += a.z * b0.w;
            acc[2][4] += a.z * b1.x; acc[2][5] += a.z * b1.y; acc[2][6] += a.z * b1.z; acc[2][7] += a.z * b1.w;
            acc[3][0] += a.w * b0.x; acc[3][1] += a.w * b0.y; acc[3][2] += a.w * b0.z; acc[3][3] += a.w * b0.w;
            acc[3][4] += a.w * b1.x; acc[3][5] += a.w * b1.y; acc[3][6] += a.w * b1.z; acc[3][7] += a.w * b1.w;
        }
    }

#pragma unroll
    for (int i = 0; i < 4; ++i) {
        const int row = bm + (ty << 2) + i;
        const int col = bn + (tx << 3);
        float4 r0, r1;
        r0.x = acc[i][0] + bias[col + 0] + bias2[col + 0];
        r0.y = acc[i][1] + bias[col + 1] + bias2[col + 1];
        r0.z = acc[i][2] + bias[col + 2] + bias2[col + 2];
        r0.w = acc[i][3] + bias[col + 3] + bias2[col + 3];
        r1.x = acc[i][4] + bias[col + 4] + bias2[col + 4];
        r1.y = acc[i][5] + bias[col + 5] + bias2[col + 5];
        r1.z = acc[i][6] + bias[col + 6] + bias2[col + 6];
        r1.w = acc[i][7] + bias[col + 7] + bias2[col + 7];
        *(float4*)&C[(size_t)row * 4096 + col] = r0;
        *(float4*)&C[(size_t)row * 4096 + col + 4] = r1;
    }
}

__device__ inline unsigned pack_bf16(float a, float b) {
    return (__float_as_uint(a) >> 16) | (__float_as_uint(b) & 0xFFFF0000u);
}

// ---------------------------------------------------------------------------
// Row L2-normalization (256-col rows), for qn.
// ---------------------------------------------------------------------------
__global__ void rownorm(const float* __restrict__ X, float* __restrict__ Xn, int nrows)
{
    const int row = blockIdx.x * 4 + (threadIdx.x >> 6);
    const int lane = threadIdx.x & 63;
    if (row >= nrows) return;
    float4 v = *(const float4*)&X[(size_t)row * 256 + (lane << 2)];
    float ss = v.x * v.x + v.y * v.y + v.z * v.z + v.w * v.w;
#pragma unroll
    for (int o = 1; o < 64; o <<= 1) ss += __shfl_xor(ss, o);
    const float sc = 1.f / fmaxf(sqrtf(ss), 1e-12f);
    v.x *= sc; v.y *= sc; v.z *= sc; v.w *= sc;
    *(float4*)&Xn[(size_t)row * 256 + (lane << 2)] = v;
}

// ---------------------------------------------------------------------------
// Persistent LSTM (blocks 0..255, proven round-10 depth-1 pipeline) +
// key-prep rider blocks (256..511): rnk = imp/max(||key||,eps) and optional
// bf16(key*rnk) conversion, using the CUs' idle wave slots during the LSTM.
// Co-residency by capacity: 512 blocks x 4 waves x 16KB LDS x ~60 VGPR all
// fit simultaneously (8/32 waves per CU) -> LSTM invariant holds.
// ---------------------------------------------------------------------------
__device__ inline float sigm_f(float x) { return 1.f / (1.f + __expf(-x)); }
__device__ inline float tanh_f(float x) { return 1.f - 2.f / (__expf(2.f * x) + 1.f); }

#define SUBSTEP(B, U, UN, C4, XPC) do {                                           \
    asm volatile("s_waitcnt vmcnt(3)" ::: "memory");                              \
    __builtin_amdgcn_sched_barrier(0);                                            \
    const unsigned* pb_ = rec + (slot << 12) + (B << 10) + (t << 2);              \
    while ((((U.x ^ st) | (U.y ^ st) | (U.z ^ st) | (U.w ^ st)) & 0xFFu) != 0u) { \
        __builtin_amdgcn_s_sleep(1);                                              \
        asm volatile("global_load_dwordx4 %0, %1, off sc0 sc1\n\ts_waitcnt vmcnt(0)" \
                     : "=&v"(U) : "v"(pb_) : "memory");                           \
    }                                                                             \
    {                                                                             \
        float4 hw_;                                                               \
        hw_.x = __uint_as_float(U.x & 0xFFFFFF00u);                               \
        hw_.y = __uint_as_float(U.y & 0xFFFFFF00u);                               \
        hw_.z = __uint_as_float(U.z & 0xFFFFFF00u);                               \
        hw_.w = __uint_as_float(U.w & 0xFFFFFF00u);                               \
        *(float4*)&h_lds[B][t << 2] = hw_;                                        \
    }                                                                             \
    asm volatile("s_waitcnt lgkmcnt(0)" ::: "memory");                            \
    __builtin_amdgcn_sched_barrier(0);                                            \
    __builtin_amdgcn_s_barrier();                                                 \
    {                                                                             \
        const unsigned* pn_ = rec + (((B == 3) ? (slot ^ 1) : slot) << 12)        \
                              + (((B + 1) & 3) << 10) + (t << 2);                 \
        asm volatile("global_load_dwordx4 %0, %1, off sc0 sc1"                    \
                     : "=&v"(UN) : "v"(pn_) : "memory");                          \
    }                                                                             \
    const float* hb_ = &h_lds[B][0];                                              \
    float ax_ = 0.f, ay_ = 0.f, az_ = 0.f, aw_ = 0.f;                             \
    _Pragma("unroll")                                                             \
    for (int j = 0; j < 16; ++j) {                                                \
        const float4 hv_ = *(const float4*)&hb_[(ksub << 2) + (j << 6)];          \
        ax_ += w4[j].x * hv_.x; ay_ += w4[j].y * hv_.y;                           \
        az_ += w4[j].z * hv_.z; aw_ += w4[j].w * hv_.w;                           \
    }                                                                             \
    float sm_ = (ax_ + ay_) + (az_ + aw_);                                        \
    sm_ += __shfl_xor(sm_, 1); sm_ += __shfl_xor(sm_, 2);                         \
    sm_ += __shfl_xor(sm_, 4); sm_ += __shfl_xor(sm_, 8);                         \
    sm_ += XPC;                                                                   \
    const float vi_ = __shfl(sm_, ksub);                                          \
    const float vf_ = __shfl(sm_, ksub + 16);                                     \
    const float vg_ = __shfl(sm_, ksub + 32);                                     \
    const float vo_ = __shfl(sm_, ksub + 48);                                     \
    const float iv_ = sigm_f(vi_), fv_ = sigm_f(vf_);                             \
    const float gv_ = tanh_f(vg_), ov_ = sigm_f(vo_);                             \
    C4 = fv_ * C4 + iv_ * gv_;                                                    \
    const float hvv_ = ov_ * tanh_f(C4);                                          \
    if (lane == 0) {                                                              \
        unsigned* dst_ = rec + ((slot ^ 1) << 12) + (B << 10) + unit;             \
        const unsigned uv_ = (__float_as_uint(hvv_) & 0xFFFFFF00u) |              \
                             ((unsigned)(s + 1) & 0xFFu);                         \
        float* ha_ = &h_all[(size_t)((B << 8) + s) * 1024 + unit];                \
        asm volatile("global_store_dword %0, %1, off sc0 sc1"                     \
                     :: "v"(dst_), "v"(uv_) : "memory");                          \
        asm volatile("global_store_dword %0, %1, off"                             \
                     :: "v"(ha_), "v"(hvv_) : "memory");                          \
    }                                                                             \
    {                                                                             \
        const float* px_ = &xp[(size_t)((B << 8) + sn) * 4096 + wrow];            \
        asm volatile("global_load_dword %0, %1, off"                              \
                     : "=&v"(XPC) : "v"(px_) : "memory");                         \
    }                                                                             \
} while (0)

__global__ __launch_bounds__(256) void lstm_kernel(
    const float* __restrict__ xp, const float* __restrict__ W_hh,
    unsigned* __restrict__ rec, float* __restrict__ h_all,
    const float* __restrict__ keys, const float* __restrict__ imp,
    float* __restrict__ rnk, unsigned short* __restrict__ kb)
{
    __shared__ float h_lds[4][1024];
    const int t = threadIdx.x;

    if (blockIdx.x >= NWG_LSTM) {
        // ---- key-prep rider: 256 rows per block ----
        const int base_row = (blockIdx.x - NWG_LSTM) << 8;
        const int lane = t & 63;
        for (int it = 0; it < 64; ++it) {
            const int row = base_row + (it << 2) + (t >> 6);
            float4 v = *(const float4*)&keys[(size_t)row * 256 + (lane << 2)];
            float ss = v.x * v.x + v.y * v.y + v.z * v.z + v.w * v.w;
#pragma unroll
            for (int o = 1; o < 64; o <<= 1) ss += __shfl_xor(ss, o);
            const float sc = imp[row] / fmaxf(sqrtf(ss), 1e-12f);
            if (lane == 0) rnk[row] = sc;
            if (kb) {
                uint2 p;
                p.x = pack_bf16(v.x * sc, v.y * sc);
                p.y = pack_bf16(v.z * sc, v.w * sc);
                *(uint2*)&kb[(size_t)row * 256 + (lane << 2)] = p;
            }
        }
        return;
    }

    const int wave = t >> 6, lane = t & 63;
    const int gt = lane >> 4, ksub = lane & 15;   // gate 0..3 (i,f,g,o), k-sub 0..15
    const int unit = (blockIdx.x << 2) + wave;
    const int wrow = (gt << 10) + unit;           // W_hh row

    float4 w4[16];
#pragma unroll
    for (int j = 0; j < 16; ++j)
        w4[j] = *(const float4*)&W_hh[(size_t)wrow * 1024 + (ksub << 2) + (j << 6)];

    float c40 = 0.f, c41 = 0.f, c42 = 0.f, c43 = 0.f;   // cell state (per-lane)
    float xpc0 = xp[(size_t)(0 * 256 + 0) * 4096 + wrow];
    float xpc1 = xp[(size_t)(1 * 256 + 0) * 4096 + wrow];
    float xpc2 = xp[(size_t)(2 * 256 + 0) * 4096 + wrow];
    float xpc3 = xp[(size_t)(3 * 256 + 0) * 4096 + wrow];

    uint4 u0 = make_uint4(~0u, ~0u, ~0u, ~0u);    // tag 0xFF -> retry path on
    uint4 u1 = u0, u2 = u0, u3 = u0;              // first use (never a step tag)

    // prologue: issue poll for (s=0,b=0) and drain so the pipeline count is exact
    {
        const unsigned* p00 = rec + (t << 2);
        asm volatile("global_load_dwordx4 %0, %1, off sc0 sc1\n\ts_waitcnt vmcnt(0)"
                     : "=&v"(u0) : "v"(p00) : "memory");
        __builtin_amdgcn_sched_barrier(0);
    }

    for (int s = 0; s < 256; ++s) {
        const int slot = s & 1;
        const unsigned st = (unsigned)s & 0xFFu;
        const int sn = (s < 255) ? s + 1 : 255;   // clamped next-step xp row
        SUBSTEP(0, u0, u1, c40, xpc0);
        SUBSTEP(1, u1, u2, c41, xpc1);
        SUBSTEP(2, u2, u3, c42, xpc2);
        SUBSTEP(3, u3, u0, c43, xpc3);
    }
}

// ---------------------------------------------------------------------------
// Static-register top-8 insertion (sorted v0>=...>=v7).
// ---------------------------------------------------------------------------
#define SWAP1(A, B, IA, IB) { float _t = A; A = B; B = _t; int _u = IA; IA = IB; IB = _u; }
#define INS8G(P, V, ID) do {                                          \
    const float _v = (V); const int _id = (ID);                       \
    if (_v > P##v7) {                                                 \
        P##v7 = _v; P##i7 = _id;                                      \
        if (P##v7 > P##v6) SWAP1(P##v6, P##v7, P##i6, P##i7);         \
        if (P##v6 > P##v5) SWAP1(P##v5, P##v6, P##i5, P##i6);         \
        if (P##v5 > P##v4) SWAP1(P##v4, P##v5, P##i4, P##i5);         \
        if (P##v4 > P##v3) SWAP1(P##v3, P##v4, P##i3, P##i4);         \
        if (P##v3 > P##v2) SWAP1(P##v2, P##v3, P##i2, P##i3);         \
        if (P##v2 > P##v1) SWAP1(P##v1, P##v2, P##i1, P##i2);         \
        if (P##v1 > P##v0) SWAP1(P##v0, P##v1, P##i0, P##i1);         \
    }                                                                 \
} while (0)
#define DECL8(P) float P##v0=-3e38f,P##v1=-3e38f,P##v2=-3e38f,P##v3=-3e38f, \
                       P##v4=-3e38f,P##v5=-3e38f,P##v6=-3e38f,P##v7=-3e38f; \
                 int P##i0=0x7fffffff,P##i1=0x7fffffff,P##i2=0x7fffffff,P##i3=0x7fffffff, \
                     P##i4=0x7fffffff,P##i5=0x7fffffff,P##i6=0x7fffffff,P##i7=0x7fffffff;

// ---------------------------------------------------------------------------
// sim_mfma_b2: bf16 MFMA candidate scoring, 2 query groups per wave, from
// pre-converted bf16 keys. Grid (KSPLITS=64, 8) = 512 blocks (2/CU).
// Wave w scores queries {q0+w*16} (A) and {q0+64+w*16} (B); each staged key
// fragment feeds two MFMAs -> 256 MB total key traffic. Merge phase aliases
// the cand arrays onto k_lds (32 KB <= 33 KB).
// ---------------------------------------------------------------------------
__global__ __launch_bounds__(256) void sim_mfma_b2(
    const float* __restrict__ qn, const unsigned short* __restrict__ kb,
    float* __restrict__ part_v8, int* __restrict__ part_i8)
{
    __shared__ unsigned short k_lds[64 * 264];    // also aliased as cand arrays
    const int t = threadIdx.x;
    const int wave = t >> 6, lane = t & 63;
    const int ks = blockIdx.x, qs = blockIdx.y;
    const int key_base = ks * KPB;
    const int q0 = qs << 7;                       // 128 queries per block
    const int qrowA = q0 + (wave << 4) + (lane & 15);
    const int qrowB = qrowA + 64;
    const int kg = lane >> 4;                     // k-group 0..3

    bf16x8 bqA[8], bqB[8];
#pragma unroll
    for (int kc = 0; kc < 8; ++kc) {
        const float* qpA = &qn[(size_t)qrowA * 256 + (kc << 5) + (kg << 3)];
        const float* qpB = &qn[(size_t)qrowB * 256 + (kc << 5) + (kg << 3)];
        const float4 a0 = *(const float4*)qpA;
        const float4 a1 = *(const float4*)(qpA + 4);
        const float4 b0 = *(const float4*)qpB;
        const float4 b1 = *(const float4*)(qpB + 4);
        union { unsigned int u[4]; bf16x8 h; } ca, cb;
        ca.u[0] = pack_bf16(a0.x, a0.y); ca.u[1] = pack_bf16(a0.z, a0.w);
        ca.u[2] = pack_bf16(a1.x, a1.y); ca.u[3] = pack_bf16(a1.z, a1.w);
        cb.u[0] = pack_bf16(b0.x, b0.y); cb.u[1] = pack_bf16(b0.z, b0.w);
        cb.u[2] = pack_bf16(b1.x, b1.y); cb.u[3] = pack_bf16(b1.z, b1.w);
        bqA[kc] = ca.h; bqB[kc] = cb.h;
    }

    DECL8(tA)
    DECL8(tB)

    const int srow = t >> 2, scol0 = (t & 3) << 6;   // staging: row, 64-col slice

    for (int stg = 0; stg < KPB / 64; ++stg) {
        __syncthreads();
        {
            const unsigned short* kp = &kb[(size_t)(key_base + (stg << 6) + srow) * 256 + scol0];
#pragma unroll
            for (int i = 0; i < 8; ++i)
                *(u16x8*)&k_lds[srow * 264 + scol0 + (i << 3)] = *(const u16x8*)(kp + (i << 3));
        }
        __syncthreads();

#pragma unroll
        for (int kt = 0; kt < 4; ++kt) {
            f32x4 aA = {0.f, 0.f, 0.f, 0.f};
            f32x4 aB = {0.f, 0.f, 0.f, 0.f};
#pragma unroll
            for (int kc = 0; kc < 8; ++kc) {
                const bf16x8 af = *(const bf16x8*)&k_lds[((kt << 4) + (lane & 15)) * 264 +
                                                         (kc << 5) + (kg << 3)];
                aA = __builtin_amdgcn_mfma_f32_16x16x32_bf16(af, bqA[kc], aA, 0, 0, 0);
                aB = __builtin_amdgcn_mfma_f32_16x16x32_bf16(af, bqB[kc], aB, 0, 0, 0);
            }
            const int kidx = key_base + (stg << 6) + (kt << 4) + (kg << 2);
            INS8G(tA, aA[0], kidx + 0); INS8G(tB, aB[0], kidx + 0);
            INS8G(tA, aA[1], kidx + 1); INS8G(tB, aB[1], kidx + 1);
            INS8G(tA, aA[2], kidx + 2); INS8G(tB, aB[2], kidx + 2);
            INS8G(tA, aA[3], kidx + 3); INS8G(tB, aB[3], kidx + 3);
        }
    }

    // ---- merge phase: alias cand arrays onto k_lds ----
    float* cand_v = (float*)k_lds;                 // [512][8] floats, 16 KB
    int*   cand_i = (int*)(k_lds + 8192);          // [512][8] ints,   16 KB
    __syncthreads();
    cand_v[t * 8 + 0] = tAv0; cand_i[t * 8 + 0] = tAi0;
    cand_v[t * 8 + 1] = tAv1; cand_i[t * 8 + 1] = tAi1;
    cand_v[t * 8 + 2] = tAv2; cand_i[t * 8 + 2] = tAi2;
    cand_v[t * 8 + 3] = tAv3; cand_i[t * 8 + 3] = tAi3;
    cand_v[t * 8 + 4] = tAv4; cand_i[t * 8 + 4] = tAi4;
    cand_v[t * 8 + 5] = tAv5; cand_i[t * 8 + 5] = tAi5;
    cand_v[t * 8 + 6] = tAv6; cand_i[t * 8 + 6] = tAi6;
    cand_v[t * 8 + 7] = tAv7; cand_i[t * 8 + 7] = tAi7;
    cand_v[(256 + t) * 8 + 0] = tBv0; cand_i[(256 + t) * 8 + 0] = tBi0;
    cand_v[(256 + t) * 8 + 1] = tBv1; cand_i[(256 + t) * 8 + 1] = tBi1;
    cand_v[(256 + t) * 8 + 2] = tBv2; cand_i[(256 + t) * 8 + 2] = tBi2;
    cand_v[(256 + t) * 8 + 3] = tBv3; cand_i[(256 + t) * 8 + 3] = tBi3;
    cand_v[(256 + t) * 8 + 4] = tBv4; cand_i[(256 + t) * 8 + 4] = tBi4;
    cand_v[(256 + t) * 8 + 5] = tBv5; cand_i[(256 + t) * 8 + 5] = tBi5;
    cand_v[(256 + t) * 8 + 6] = tBv6; cand_i[(256 + t) * 8 + 6] = tBi6;
    cand_v[(256 + t) * 8 + 7] = tBv7; cand_i[(256 + t) * 8 + 7] = tBi7;
    __syncthreads();
    if (t < 128) {
        DECL8(m)
        const int tt = t & 63;                     // query within set
        const int setoff = (t < 64) ? 0 : 256;
        const int w = tt >> 4, c = tt & 15;
        for (int g = 0; g < 4; ++g) {
            const int src = (setoff + (w << 6) + (g << 4) + c) * 8;
            for (int r = 0; r < 8; ++r)
                INS8G(m, cand_v[src + r], cand_i[src + r]);
        }
        const size_t base = (size_t)(q0 + t) * (KSPLITS * 8) + ks * 8;
        part_v8[base + 0] = mv0; part_i8[base + 0] = mi0;
        part_v8[base + 1] = mv1; part_i8[base + 1] = mi1;
        part_v8[base + 2] = mv2; part_i8[base + 2] = mi2;
        part_v8[base + 3] = mv3; part_i8[base + 3] = mi3;
        part_v8[base + 4] = mv4; part_i8[base + 4] = mi4;
        part_v8[base + 5] = mv5; part_i8[base + 5] = mi5;
        part_v8[base + 6] = mv6; part_i8[base + 6] = mi6;
        part_v8[base + 7] = mv7; part_i8[base + 7] = mi7;
    }
}

// ---------------------------------------------------------------------------
// sim_mfma_f2: fp32-key fallback, same dual-group geometry (staging converts
// fp32*rnk -> bf16 in-flight).
// ---------------------------------------------------------------------------
__global__ __launch_bounds__(256) void sim_mfma_f2(
    const float* __restrict__ qn, const float* __restrict__ keys,
    const float* __restrict__ rnk, float* __restrict__ part_v8, int* __restrict__ part_i8)
{
    __shared__ unsigned short k_lds[64 * 264];
    const int t = threadIdx.x;
    const int wave = t >> 6, lane = t & 63;
    const int ks = blockIdx.x, qs = blockIdx.y;
    const int key_base = ks * KPB;
    const int q0 = qs << 7;
    const int qrowA = q0 + (wave << 4) + (lane & 15);
    const int qrowB = qrowA + 64;
    const int kg = lane >> 4;

    bf16x8 bqA[8], bqB[8];
#pragma unroll
    for (int kc = 0; kc < 8; ++kc) {
        const float* qpA = &qn[(size_t)qrowA * 256 + (kc << 5) + (kg << 3)];
        const float* qpB = &qn[(size_t)qrowB * 256 + (kc << 5) + (kg << 3)];
        const float4 a0 = *(const float4*)qpA;
        const float4 a1 = *(const float4*)(qpA + 4);
        const float4 b0 = *(const float4*)qpB;
        const float4 b1 = *(const float4*)(qpB + 4);
        union { unsigned int u[4]; bf16x8 h; } ca, cb;
        ca.u[0] = pack_bf16(a0.x, a0.y); ca.u[1] = pack_bf16(a0.z, a0.w);
        ca.u[2] = pack_bf16(a1.x, a1.y); ca.u[3] = pack_bf16(a1.z, a1.w);
        cb.u[0] = pack_bf16(b0.x, b0.y); cb.u[1] = pack_bf16(b0.z, b0.w);
        cb.u[2] = pack_bf16(b1.x, b1.y); cb.u[3] = pack_bf16(b1.z, b1.w);
        bqA[kc] = ca.h; bqB[kc] = cb.h;
    }

    DECL8(tA)
    DECL8(tB)

    const int srow = t >> 2, scol0 = (t & 3) << 6;

    for (int stg = 0; stg < KPB / 64; ++stg) {
        __syncthreads();
        {
            const int krow = key_base + (stg << 6) + srow;
            const float sc = rnk[krow];
            const float* kp = &keys[(size_t)krow * 256 + scol0];
#pragma unroll
            for (int i = 0; i < 8; ++i) {
                float4 f0 = *(const float4*)(kp + (i << 3));
                float4 f1 = *(const float4*)(kp + (i << 3) + 4);
                f0.x *= sc; f0.y *= sc; f0.z *= sc; f0.w *= sc;
                f1.x *= sc; f1.y *= sc; f1.z *= sc; f1.w *= sc;
                union { unsigned int u[4]; u16x8 h; } cv;
                cv.u[0] = pack_bf16(f0.x, f0.y);
                cv.u[1] = pack_bf16(f0.z, f0.w);
                cv.u[2] = pack_bf16(f1.x, f1.y);
                cv.u[3] = pack_bf16(f1.z, f1.w);
                *(u16x8*)&k_lds[srow * 264 + scol0 + (i << 3)] = cv.h;
            }
        }
        __syncthreads();

#pragma unroll
        for (int kt = 0; kt < 4; ++kt) {
            f32x4 aA = {0.f, 0.f, 0.f, 0.f};
            f32x4 aB = {0.f, 0.f, 0.f, 0.f};
#pragma unroll
            for (int kc = 0; kc < 8; ++kc) {
                const bf16x8 af = *(const bf16x8*)&k_lds[((kt << 4) + (lane & 15)) * 264 +
                                                         (kc << 5) + (kg << 3)];
                aA = __builtin_amdgcn_mfma_f32_16x16x32_bf16(af, bqA[kc], aA, 0, 0, 0);
                aB = __builtin_amdgcn_mfma_f32_16x16x32_bf16(af, bqB[kc], aB, 0, 0, 0);
            }
            const int kidx = key_base + (stg << 6) + (kt << 4) + (kg << 2);
            INS8G(tA, aA[0], kidx + 0); INS8G(tB, aB[0], kidx + 0);
            INS8G(tA, aA[1], kidx + 1); INS8G(tB, aB[1], kidx + 1);
            INS8G(tA, aA[2], kidx + 2); INS8G(tB, aB[2], kidx + 2);
            INS8G(tA, aA[3], kidx + 3); INS8G(tB, aB[3], kidx + 3);
        }
    }

    float* cand_v = (float*)k_lds;
    int*   cand_i = (int*)(k_lds + 8192);
    __syncthreads();
    cand_v[t * 8 + 0] = tAv0; cand_i[t * 8 + 0] = tAi0;
    cand_v[t * 8 + 1] = tAv1; cand_i[t * 8 + 1] = tAi1;
    cand_v[t * 8 + 2] = tAv2; cand_i[t * 8 + 2] = tAi2;
    cand_v[t * 8 + 3] = tAv3; cand_i[t * 8 + 3] = tAi3;
    cand_v[t * 8 + 4] = tAv4; cand_i[t * 8 + 4] = tAi4;
    cand_v[t * 8 + 5] = tAv5; cand_i[t * 8 + 5] = tAi5;
    cand_v[t * 8 + 6] = tAv6; cand_i[t * 8 + 6] = tAi6;
    cand_v[t * 8 + 7] = tAv7; cand_i[t * 8 + 7] = tAi7;
    cand_v[(256 + t) * 8 + 0] = tBv0; cand_i[(256 + t) * 8 + 0] = tBi0;
    cand_v[(256 + t) * 8 + 1] = tBv1; cand_i[(256 + t) * 8 + 1] = tBi1;
    cand_v[(256 + t) * 8 + 2] = tBv2; cand_i[(256 + t) * 8 + 2] = tBi2;
    cand_v[(256 + t) * 8 + 3] = tBv3; cand_i[(256 + t) * 8 + 3] = tBi3;
    cand_v[(256 + t) * 8 + 4] = tBv4; cand_i[(256 + t) * 8 + 4] = tBi4;
    cand_v[(256 + t) * 8 + 5] = tBv5; cand_i[(256 + t) * 8 + 5] = tBi5;
    cand_v[(256 + t) * 8 + 6] = tBv6; cand_i[(256 + t) * 8 + 6] = tBi6;
    cand_v[(256 + t) * 8 + 7] = tBv7; cand_i[(256 + t) * 8 + 7] = tBi7;
    __syncthreads();
    if (t < 128) {
        DECL8(m)
        const int tt = t & 63;
        const int setoff = (t < 64) ? 0 : 256;
        const int w = tt >> 4, c = tt & 15;
        for (int g = 0; g < 4; ++g) {
            const int src = (setoff + (w << 6) + (g << 4) + c) * 8;
            for (int r = 0; r < 8; ++r)
                INS8G(m, cand_v[src + r], cand_i[src + r]);
        }
        const size_t base = (size_t)(q0 + t) * (KSPLITS * 8) + ks * 8;
        part_v8[base + 0] = mv0; part_i8[base + 0] = mi0;
        part_v8[base + 1] = mv1; part_i8[base + 1] = mi1;
        part_v8[base + 2] = mv2; part_i8[base + 2] = mi2;
        part_v8[base + 3] = mv3; part_i8[base + 3] = mi3;
        part_v8[base + 4] = mv4; part_i8[base + 4] = mi4;
        part_v8[base + 5] = mv5; part_i8[base + 5] = mi5;
        part_v8[base + 6] = mv6; part_i8[base + 6] = mi6;
        part_v8[base + 7] = mv7; part_i8[base + 7] = mi7;
    }
}

// ---------------------------------------------------------------------------
__global__ void cand_merge(const float* __restrict__ part_v8, const int* __restrict__ part_i8,
                           int* __restrict__ cand8_i)
{
    const int q = blockIdx.x * 256 + threadIdx.x;
    if (q >= ROWS) return;
    DECL8(c)
    for (int j = 0; j < KSPLITS * 8; ++j)
        INS8G(c, part_v8[(size_t)q * (KSPLITS * 8) + j], part_i8[(size_t)q * (KSPLITS * 8) + j]);
    cand8_i[q * 8 + 0] = ci0; cand8_i[q * 8 + 1] = ci1;
    cand8_i[q * 8 + 2] = ci2; cand8_i[q * 8 + 3] = ci3;
    cand8_i[q * 8 + 4] = ci4; cand8_i[q * 8 + 5] = ci5;
    cand8_i[q * 8 + 6] = ci6; cand8_i[q * 8 + 7] = ci7;
}

// ---------------------------------------------------------------------------
// Fused: fp32 rescore of the 8 candidates -> exact top-3 (reference
// tie-break) -> gather values -> attention softmax -> weighted sum.
// ---------------------------------------------------------------------------
__global__ void rescore_gather(const float* __restrict__ qn, const float* __restrict__ keys,
                               const float* __restrict__ rnk, const int* __restrict__ cand8_i,
                               const float* __restrict__ values, const float* __restrict__ Wa,
                               const float* __restrict__ ba, float* __restrict__ mem_raw)
{
    const int q = blockIdx.x;
    const int lane = threadIdx.x;
    const float4 qv = *(const float4*)&qn[(size_t)q * 256 + (lane << 2)];
    float s0, s1, s2, s3, s4, s5, s6, s7;
    int j0, j1, j2, j3, j4, j5, j6, j7;
#define RES(R, S, J) { J = cand8_i[q * 8 + R]; \
    const float4 kv = *(const float4*)&keys[(size_t)J * 256 + (lane << 2)]; \
    float d = qv.x * kv.x + qv.y * kv.y + qv.z * kv.z + qv.w * kv.w; \
    d += __shfl_xor(d, 1); d += __shfl_xor(d, 2); d += __shfl_xor(d, 4); \
    d += __shfl_xor(d, 8); d += __shfl_xor(d, 16); d += __shfl_xor(d, 32); \
    S = d * rnk[J]; }
    RES(0, s0, j0) RES(1, s1, j1) RES(2, s2, j2) RES(3, s3, j3)
    RES(4, s4, j4) RES(5, s5, j5) RES(6, s6, j6) RES(7, s7, j7)
#undef RES
    int top[3];
#define BET(SV, JV) if (SV > bv || (SV == bv && JV < bi)) { bv = SV; bi = JV; }
#pragma unroll
    for (int k = 0; k < 3; ++k) {
        float bv = s0; int bi = j0;
        BET(s1, j1) BET(s2, j2) BET(s3, j3) BET(s4, j4)
        BET(s5, j5) BET(s6, j6) BET(s7, j7)
        top[k] = bi;
        if (j0 == bi) s0 = -3e38f;
        if (j1 == bi) s1 = -3e38f;
        if (j2 == bi) s2 = -3e38f;
        if (j3 == bi) s3 = -3e38f;
        if (j4 == bi) s4 = -3e38f;
        if (j5 == bi) s5 = -3e38f;
        if (j6 == bi) s6 = -3e38f;
        if (j7 == bi) s7 = -3e38f;
    }
#undef BET
    const float4 wa = *(const float4*)&Wa[lane << 2];
    float4 vr[3];
    float lg[3];
#pragma unroll
    for (int r = 0; r < 3; ++r) {
        const float4 v = *(const float4*)&values[(size_t)top[r] * 256 + (lane << 2)];
        vr[r] = v;
        float d = v.x * wa.x + v.y * wa.y + v.z * wa.z + v.w * wa.w;
#pragma unroll
        for (int o = 1; o < 64; o <<= 1) d += __shfl_xor(d, o);
        lg[r] = d + ba[0];
    }
    const float mx = fmaxf(lg[0], fmaxf(lg[1], lg[2]));
    float e0 = __expf(lg[0] - mx), e1 = __expf(lg[1] - mx), e2 = __expf(lg[2] - mx);
    const float inv = 1.f / (e0 + e1 + e2);
    e0 *= inv; e1 *= inv; e2 *= inv;
    float4 m;
    m.x = e0 * vr[0].x + e1 * vr[1].x + e2 * vr[2].x;
    m.y = e0 * vr[0].y + e1 * vr[1].y + e2 * vr[2].y;
    m.z = e0 * vr[0].z + e1 * vr[1].z + e2 * vr[2].z;
    m.w = e0 * vr[0].w + e1 * vr[1].w + e2 * vr[2].w;
    *(float4*)&mem_raw[(size_t)q * 256 + (lane << 2)] = m;
}

// ---------------------------------------------------------------------------
extern "C" void kernel_launch(void* const* d_in, const int* in_sizes, int n_in,
                              void* d_out, int out_size, void* d_ws, size_t ws_size,
                              hipStream_t stream)
{
    (void)in_sizes; (void)n_in; (void)out_size;
    const float* x     = (const float*)d_in[0];
    const float* keys  = (const float*)d_in[1];
    const float* values= (const float*)d_in[2];
    const float* imp   = (const float*)d_in[3];
    const float* W_ih  = (const float*)d_in[4];
    const float* W_hh  = (const float*)d_in[5];
    const float* b_ih  = (const float*)d_in[6];
    const float* b_hh  = (const float*)d_in[7];
    const float* Wq    = (const float*)d_in[8];
    const float* bq    = (const float*)d_in[9];
    const float* Wa    = (const float*)d_in[10];
    const float* ba    = (const float*)d_in[11];
    const float* Wc    = (const float*)d_in[12];
    const float* bc    = (const float*)d_in[13];
    const float* Wo    = (const float*)d_in[14];
    const float* bo    = (const float*)d_in[15];
    float* out = (float*)d_out;

    float* ws = (float*)d_ws;
    size_t o = 0;
    float* xp      = ws + o; o += (size_t)1024 * 4096;           // 16 MB
    float* h_all   = ws + o; o += (size_t)1024 * 1024;           // 4 MB
    unsigned* rec  = (unsigned*)(ws + o); o += 2 * 4096;         // tagged records
    float* rnk     = ws + o; o += NKEY;                          // imp/||key||
    float* qbuf    = ws + o; o += (size_t)ROWS * 256;
    float* qn      = ws + o; o += (size_t)ROWS * 256;
    float* part_v8 = ws + o; o += (size_t)ROWS * KSPLITS * 8;    // 2 MB
    int*   part_i8 = (int*)(ws + o); o += (size_t)ROWS * KSPLITS * 8;
    int*   cand8_i = (int*)(ws + o); o += ROWS * 8;
    float* mem_raw = ws + o; o += (size_t)ROWS * 256;
    float* memb    = ws + o; o += (size_t)ROWS * 256;
    unsigned short* kb = (unsigned short*)(ws + o);              // bf16 keys, 32 MB
    const size_t need_bf16 = (o + (size_t)NKEY * 256 / 2) * sizeof(float);
    const bool use_bf16 = ws_size >= need_bf16;                  // deterministic

    // zero records: slot-0 tag byte = 0 (= step-0 tag) with h = +0.0
    hipMemsetAsync(rec, 0, 2 * 4096 * 4, stream);

    // x_proj = x @ W_ih^T + b_ih + b_hh : [1024, 4096]
    sgemm_nt_w<<<dim3(32, 16), 256, 0, stream>>>(x, W_ih, xp, b_ih, b_hh);

    // LSTM recurrence (blocks 0-255) + key-prep riders (blocks 256-511)
    lstm_kernel<<<2 * NWG_LSTM, NTH_LSTM, 0, stream>>>(
        xp, W_hh, rec, h_all, keys, imp, rnk, use_bf16 ? kb : nullptr);

    // q = h @ Wq^T + bq : [1024, 256]
    sgemm_nt<<<dim3(4, 16), 256, 0, stream>>>(h_all, HD, Wq, HD, qbuf, MD, HD, bq, nullptr, 0);

    rownorm<<<ROWS / 4, 256, 0, stream>>>(qbuf, qn, ROWS);

    // bf16 MFMA candidate scoring (dual query groups) + fp32 rescore + gather
    if (use_bf16)
        sim_mfma_b2<<<dim3(KSPLITS, 8), 256, 0, stream>>>(qn, kb, part_v8, part_i8);
    else
        sim_mfma_f2<<<dim3(KSPLITS, 8), 256, 0, stream>>>(qn, keys, rnk, part_v8, part_i8);
    cand_merge<<<ROWS / 256, 256, 0, stream>>>(part_v8, part_i8, cand8_i);
    rescore_gather<<<ROWS, 64, 0, stream>>>(qn, keys, rnk, cand8_i, values, Wa, ba, mem_raw);

    // mem = mem_raw @ Wc^T + bc
    sgemm_nt<<<dim3(4, 16), 256, 0, stream>>>(mem_raw, MD, Wc, MD, memb, MD, MD, bc, nullptr, 0);

    // out = [h, mem] @ Wo^T + bo  (split K)
    sgemm_nt<<<dim3(8, 16), 256, 0, stream>>>(h_all, HD, Wo, HD + MD, out, OD, HD, bo, nullptr, 0);
    sgemm_nt<<<dim3(8, 16), 256, 0, stream>>>(memb, MD, Wo + HD, HD + MD, out, OD, MD, nullptr, nullptr, 1);
}

// Round 17
// 1325.046 us; speedup vs baseline: 1.0546x; 1.0546x over previous
//
#include <hip/hip_runtime.h>
#include <hip/hip_bf16.h>
#include <cstdint>
#include <cstddef>

// Problem constants
#define BB 4
#define SS 256
#define ID 512
#define HD 1024
#define MD 256
#define NKEY 65536
#define OD 512
#define ROWS 1024          // B*S
#define NWG_LSTM 256
#define NTH_LSTM 256
#define KPB 2048           // keys per sim block
#define KSPLITS (NKEY / KPB)   // 32

typedef __attribute__((ext_vector_type(8))) short bf16x8;
typedef __attribute__((ext_vector_type(4))) float f32x4;
typedef __attribute__((ext_vector_type(8))) unsigned short u16x8;

// ---------------------------------------------------------------------------
// Generic SGEMM: C[M,N] = A[M,K] * Bm[N,K]^T (+bias) or C += ...
// 64x64 tile, 256 threads, 4x4 micro-tile. Grid: (N/64, M/64).
// ---------------------------------------------------------------------------
__global__ __launch_bounds__(256) void sgemm_nt(
    const float* __restrict__ A, int lda,
    const float* __restrict__ Bm, int ldb,
    float* __restrict__ C, int ldc, int K,
    const float* __restrict__ bias, const float* __restrict__ bias2,
    int accum)
{
    __shared__ float As[64][17];
    __shared__ float Bs[64][17];
    const int t = threadIdx.x;
    const int tx = t & 15, ty = t >> 4;
    const int bm = blockIdx.y << 6, bn = blockIdx.x << 6;
    const int lrow = t >> 2, lk4 = (t & 3) << 2;
    float acc[4][4] = {};

    for (int kb = 0; kb < K; kb += 16) {
        const float4 av = *(const float4*)&A[(size_t)(bm + lrow) * lda + kb + lk4];
        const float4 bv = *(const float4*)&Bm[(size_t)(bn + lrow) * ldb + kb + lk4];
        __syncthreads();
        As[lrow][lk4 + 0] = av.x; As[lrow][lk4 + 1] = av.y;
        As[lrow][lk4 + 2] = av.z; As[lrow][lk4 + 3] = av.w;
        Bs[lrow][lk4 + 0] = bv.x; Bs[lrow][lk4 + 1] = bv.y;
        Bs[lrow][lk4 + 2] = bv.z; Bs[lrow][lk4 + 3] = bv.w;
        __syncthreads();
#pragma unroll
        for (int k = 0; k < 16; ++k) {
            const float a0 = As[4 * ty + 0][k], a1 = As[4 * ty + 1][k];
            const float a2 = As[4 * ty + 2][k], a3 = As[4 * ty + 3][k];
            const float b0 = Bs[4 * tx + 0][k], b1 = Bs[4 * tx + 1][k];
            const float b2 = Bs[4 * tx + 2][k], b3 = Bs[4 * tx + 3][k];
            acc[0][0] += a0 * b0; acc[0][1] += a0 * b1; acc[0][2] += a0 * b2; acc[0][3] += a0 * b3;
            acc[1][0] += a1 * b0; acc[1][1] += a1 * b1; acc[1][2] += a1 * b2; acc[1][3] += a1 * b3;
            acc[2][0] += a2 * b0; acc[2][1] += a2 * b1; acc[2][2] += a2 * b2; acc[2][3] += a2 * b3;
            acc[3][0] += a3 * b0; acc[3][1] += a3 * b1; acc[3][2] += a3 * b2; acc[3][3] += a3 * b3;
        }
    }

#pragma unroll
    for (int i = 0; i < 4; ++i) {
        const int row = bm + 4 * ty + i;
        const int col = bn + 4 * tx;
        float4* cp = (float4*)&C[(size_t)row * ldc + col];
        float4 r;
        if (accum) {
            const float4 old = *cp;
            r.x = old.x + acc[i][0]; r.y = old.y + acc[i][1];
            r.z = old.z + acc[i][2]; r.w = old.w + acc[i][3];
        } else {
            float bx = bias[col + 0], by = bias[col + 1], bz = bias[col + 2], bw = bias[col + 3];
            if (bias2) { bx += bias2[col + 0]; by += bias2[col + 1]; bz += bias2[col + 2]; bw += bias2[col + 3]; }
            r.x = acc[i][0] + bx; r.y = acc[i][1] + by;
            r.z = acc[i][2] + bz; r.w = acc[i][3] + bw;
        }
        *cp = r;
    }
}

// ---------------------------------------------------------------------------
// x_proj GEMM: C[1024,4096] = A[1024,512] @ Bm[4096,512]^T + bias1 + bias2.
// 64(M) x 128(N) tile, 256 threads, micro 4x8, k-major LDS. Grid (32, 16).
// ---------------------------------------------------------------------------
__global__ __launch_bounds__(256) void sgemm_nt_w(
    const float* __restrict__ A, const float* __restrict__ Bm,
    float* __restrict__ C, const float* __restrict__ bias, const float* __restrict__ bias2)
{
    __shared__ float As[16][64];
    __shared__ float Bs[16][128];
    const int t = threadIdx.x;
    const int tx = t & 15, ty = t >> 4;
    const int bm = blockIdx.y << 6, bn = blockIdx.x << 7;
    const int arow = t & 63, akq = t >> 6;       // A: 1 float4 per thread
    const int brow = t & 127, bkq = t >> 7;      // B: 2 float4 per thread
    float acc[4][8] = {};

    for (int kb = 0; kb < 512; kb += 16) {
        const float4 av  = *(const float4*)&A[(size_t)(bm + arow) * 512 + kb + (akq << 2)];
        const float4 bv0 = *(const float4*)&Bm[(size_t)(bn + brow) * 512 + kb + (bkq << 3)];
        const float4 bv1 = *(const float4*)&Bm[(size_t)(bn + brow) * 512 + kb + (bkq << 3) + 4];
        __syncthreads();
        As[(akq << 2) + 0][arow] = av.x; As[(akq << 2) + 1][arow] = av.y;
        As[(akq << 2) + 2][arow] = av.z; As[(akq << 2) + 3][arow] = av.w;
        Bs[(bkq << 3) + 0][brow] = bv0.x; Bs[(bkq << 3) + 1][brow] = bv0.y;
        Bs[(bkq << 3) + 2][brow] = bv0.z; Bs[(bkq << 3) + 3][brow] = bv0.w;
        Bs[(bkq << 3) + 4][brow] = bv1.x; Bs[(bkq << 3) + 5][brow] = bv1.y;
        Bs[(bkq << 3) + 6][brow] = bv1.z; Bs[(bkq << 3) + 7][brow] = bv1.w;
        __syncthreads();
#pragma unroll
        for (int k = 0; k < 16; ++k) {
            const float4 a  = *(const float4*)&As[k][ty << 2];
            const float4 b0 = *(const float4*)&Bs[k][tx << 3];
            const float4 b1 = *(const float4*)&Bs[k][(tx << 3) + 4];
            acc[0][0] += a.x * b0.x; acc[0][1] += a.x * b0.y; acc[0][2] += a.x * b0.z; acc[0][3] += a.x * b0.w;
            acc[0][4] += a.x * b1.x; acc[0][5] += a.x * b1.y; acc[0][6] += a.x * b1.z; acc[0][7] += a.x * b1.w;
            acc[1][0] += a.y * b0.x; acc[1][1] += a.y * b0.y; acc[1][2] += a.y * b0.z; acc[1][3] += a.y * b0.w;
            acc[1][4] += a.y * b1.x; acc[1][5] += a.y * b1.y; acc[1][6] += a.y * b1.z; acc[1][7] += a.y * b1.w;
            acc[2][0] += a.z * b0.x; acc[2][1] += a.z * b0.y; acc[2][2] += a.z * b0.z; acc[2][3] += a.z * b0.w;
            acc[2][4] += a.z * b1.x; acc[2][5] += a.z * b1.y; acc[2][6] += a.z * b1.z; acc[2][7] += a.z * b1.w;
            acc[3][0] += a.w * b0.x; acc[3][1] += a.w * b0.y; acc[3][2] += a.w * b0.z; acc[3][3] += a.w * b0.w;
            acc[3][4] += a.w * b1.x; acc[3][5] += a.w * b1.y; acc[3][6] += a.w * b1.z; acc[3][7] += a.w * b1.w;
        }
    }

#pragma unroll
    for (int i = 0; i < 4; ++i) {
        const int row = bm + (ty << 2) + i;
        const int col = bn + (tx << 3);
        float4 r0, r1;
        r0.x = acc[i][0] + bias[col + 0] + bias2[col + 0];
        r0.y = acc[i][1] + bias[col + 1] + bias2[col + 1];
        r0.z = acc[i][2] + bias[col + 2] + bias2[col + 2];
        r0.w = acc[i][3] + bias[col + 3] + bias2[col + 3];
        r1.x = acc[i][4] + bias[col + 4] + bias2[col + 4];
        r1.y = acc[i][5] + bias[col + 5] + bias2[col + 5];
        r1.z = acc[i][6] + bias[col + 6] + bias2[col + 6];
        r1.w = acc[i][7] + bias[col + 7] + bias2[col + 7];
        *(float4*)&C[(size_t)row * 4096 + col] = r0;
        *(float4*)&C[(size_t)row * 4096 + col + 4] = r1;
    }
}

__device__ inline unsigned pack_bf16(float a, float b) {
    return (__float_as_uint(a) >> 16) | (__float_as_uint(b) & 0xFFFF0000u);
}

// ---------------------------------------------------------------------------
// Row L2-normalization (256-col rows), for qn.
// ---------------------------------------------------------------------------
__global__ void rownorm(const float* __restrict__ X, float* __restrict__ Xn, int nrows)
{
    const int row = blockIdx.x * 4 + (threadIdx.x >> 6);
    const int lane = threadIdx.x & 63;
    if (row >= nrows) return;
    float4 v = *(const float4*)&X[(size_t)row * 256 + (lane << 2)];
    float ss = v.x * v.x + v.y * v.y + v.z * v.z + v.w * v.w;
#pragma unroll
    for (int o = 1; o < 64; o <<= 1) ss += __shfl_xor(ss, o);
    const float sc = 1.f / fmaxf(sqrtf(ss), 1e-12f);
    v.x *= sc; v.y *= sc; v.z *= sc; v.w *= sc;
    *(float4*)&Xn[(size_t)row * 256 + (lane << 2)] = v;
}

// ---------------------------------------------------------------------------
// Persistent LSTM (blocks 0..255, proven round-10 depth-1 pipeline) +
// key-prep rider blocks (256..511): rnk = imp/max(||key||,eps) + bf16(key*rnk)
// conversion, using the CUs' idle wave slots during the LSTM (proven r16:
// LSTM duration unchanged while absorbing the 96 MB of key-prep traffic).
// ---------------------------------------------------------------------------
__device__ inline float sigm_f(float x) { return 1.f / (1.f + __expf(-x)); }
__device__ inline float tanh_f(float x) { return 1.f - 2.f / (__expf(2.f * x) + 1.f); }

#define SUBSTEP(B, U, UN, C4, XPC) do {                                           \
    asm volatile("s_waitcnt vmcnt(3)" ::: "memory");                              \
    __builtin_amdgcn_sched_barrier(0);                                            \
    const unsigned* pb_ = rec + (slot << 12) + (B << 10) + (t << 2);              \
    while ((((U.x ^ st) | (U.y ^ st) | (U.z ^ st) | (U.w ^ st)) & 0xFFu) != 0u) { \
        __builtin_amdgcn_s_sleep(1);                                              \
        asm volatile("global_load_dwordx4 %0, %1, off sc0 sc1\n\ts_waitcnt vmcnt(0)" \
                     : "=&v"(U) : "v"(pb_) : "memory");                           \
    }                                                                             \
    {                                                                             \
        float4 hw_;                                                               \
        hw_.x = __uint_as_float(U.x & 0xFFFFFF00u);                               \
        hw_.y = __uint_as_float(U.y & 0xFFFFFF00u);                               \
        hw_.z = __uint_as_float(U.z & 0xFFFFFF00u);                               \
        hw_.w = __uint_as_float(U.w & 0xFFFFFF00u);                               \
        *(float4*)&h_lds[B][t << 2] = hw_;                                        \
    }                                                                             \
    asm volatile("s_waitcnt lgkmcnt(0)" ::: "memory");                            \
    __builtin_amdgcn_sched_barrier(0);                                            \
    __builtin_amdgcn_s_barrier();                                                 \
    {                                                                             \
        const unsigned* pn_ = rec + (((B == 3) ? (slot ^ 1) : slot) << 12)        \
                              + (((B + 1) & 3) << 10) + (t << 2);                 \
        asm volatile("global_load_dwordx4 %0, %1, off sc0 sc1"                    \
                     : "=&v"(UN) : "v"(pn_) : "memory");                          \
    }                                                                             \
    const float* hb_ = &h_lds[B][0];                                              \
    float ax_ = 0.f, ay_ = 0.f, az_ = 0.f, aw_ = 0.f;                             \
    _Pragma("unroll")                                                             \
    for (int j = 0; j < 16; ++j) {                                                \
        const float4 hv_ = *(const float4*)&hb_[(ksub << 2) + (j << 6)];          \
        ax_ += w4[j].x * hv_.x; ay_ += w4[j].y * hv_.y;                           \
        az_ += w4[j].z * hv_.z; aw_ += w4[j].w * hv_.w;                           \
    }                                                                             \
    float sm_ = (ax_ + ay_) + (az_ + aw_);                                        \
    sm_ += __shfl_xor(sm_, 1); sm_ += __shfl_xor(sm_, 2);                         \
    sm_ += __shfl_xor(sm_, 4); sm_ += __shfl_xor(sm_, 8);                         \
    sm_ += XPC;                                                                   \
    const float vi_ = __shfl(sm_, ksub);                                          \
    const float vf_ = __shfl(sm_, ksub + 16);                                     \
    const float vg_ = __shfl(sm_, ksub + 32);                                     \
    const float vo_ = __shfl(sm_, ksub + 48);                                     \
    const float iv_ = sigm_f(vi_), fv_ = sigm_f(vf_);                             \
    const float gv_ = tanh_f(vg_), ov_ = sigm_f(vo_);                             \
    C4 = fv_ * C4 + iv_ * gv_;                                                    \
    const float hvv_ = ov_ * tanh_f(C4);                                          \
    if (lane == 0) {                                                              \
        unsigned* dst_ = rec + ((slot ^ 1) << 12) + (B << 10) + unit;             \
        const unsigned uv_ = (__float_as_uint(hvv_) & 0xFFFFFF00u) |              \
                             ((unsigned)(s + 1) & 0xFFu);                         \
        float* ha_ = &h_all[(size_t)((B << 8) + s) * 1024 + unit];                \
        asm volatile("global_store_dword %0, %1, off sc0 sc1"                     \
                     :: "v"(dst_), "v"(uv_) : "memory");                          \
        asm volatile("global_store_dword %0, %1, off"                             \
                     :: "v"(ha_), "v"(hvv_) : "memory");                          \
    }                                                                             \
    {                                                                             \
        const float* px_ = &xp[(size_t)((B << 8) + sn) * 4096 + wrow];            \
        asm volatile("global_load_dword %0, %1, off"                              \
                     : "=&v"(XPC) : "v"(px_) : "memory");                         \
    }                                                                             \
} while (0)

__global__ __launch_bounds__(256) void lstm_kernel(
    const float* __restrict__ xp, const float* __restrict__ W_hh,
    unsigned* __restrict__ rec, float* __restrict__ h_all,
    const float* __restrict__ keys, const float* __restrict__ imp,
    float* __restrict__ rnk, unsigned short* __restrict__ kb)
{
    __shared__ float h_lds[4][1024];
    const int t = threadIdx.x;

    if (blockIdx.x >= NWG_LSTM) {
        // ---- key-prep rider: 256 rows per block ----
        const int base_row = (blockIdx.x - NWG_LSTM) << 8;
        const int lane = t & 63;
        for (int it = 0; it < 64; ++it) {
            const int row = base_row + (it << 2) + (t >> 6);
            float4 v = *(const float4*)&keys[(size_t)row * 256 + (lane << 2)];
            float ss = v.x * v.x + v.y * v.y + v.z * v.z + v.w * v.w;
#pragma unroll
            for (int o = 1; o < 64; o <<= 1) ss += __shfl_xor(ss, o);
            const float sc = imp[row] / fmaxf(sqrtf(ss), 1e-12f);
            if (lane == 0) rnk[row] = sc;
            if (kb) {
                uint2 p;
                p.x = pack_bf16(v.x * sc, v.y * sc);
                p.y = pack_bf16(v.z * sc, v.w * sc);
                *(uint2*)&kb[(size_t)row * 256 + (lane << 2)] = p;
            }
        }
        return;
    }

    const int wave = t >> 6, lane = t & 63;
    const int gt = lane >> 4, ksub = lane & 15;   // gate 0..3 (i,f,g,o), k-sub 0..15
    const int unit = (blockIdx.x << 2) + wave;
    const int wrow = (gt << 10) + unit;           // W_hh row

    float4 w4[16];
#pragma unroll
    for (int j = 0; j < 16; ++j)
        w4[j] = *(const float4*)&W_hh[(size_t)wrow * 1024 + (ksub << 2) + (j << 6)];

    float c40 = 0.f, c41 = 0.f, c42 = 0.f, c43 = 0.f;   // cell state (per-lane)
    float xpc0 = xp[(size_t)(0 * 256 + 0) * 4096 + wrow];
    float xpc1 = xp[(size_t)(1 * 256 + 0) * 4096 + wrow];
    float xpc2 = xp[(size_t)(2 * 256 + 0) * 4096 + wrow];
    float xpc3 = xp[(size_t)(3 * 256 + 0) * 4096 + wrow];

    uint4 u0 = make_uint4(~0u, ~0u, ~0u, ~0u);    // tag 0xFF -> retry path on
    uint4 u1 = u0, u2 = u0, u3 = u0;              // first use (never a step tag)

    // prologue: issue poll for (s=0,b=0) and drain so the pipeline count is exact
    {
        const unsigned* p00 = rec + (t << 2);
        asm volatile("global_load_dwordx4 %0, %1, off sc0 sc1\n\ts_waitcnt vmcnt(0)"
                     : "=&v"(u0) : "v"(p00) : "memory");
        __builtin_amdgcn_sched_barrier(0);
    }

    for (int s = 0; s < 256; ++s) {
        const int slot = s & 1;
        const unsigned st = (unsigned)s & 0xFFu;
        const int sn = (s < 255) ? s + 1 : 255;   // clamped next-step xp row
        SUBSTEP(0, u0, u1, c40, xpc0);
        SUBSTEP(1, u1, u2, c41, xpc1);
        SUBSTEP(2, u2, u3, c42, xpc2);
        SUBSTEP(3, u3, u0, c43, xpc3);
    }
}

// ---------------------------------------------------------------------------
// Static-register top-8 insertion (sorted v0>=...>=v7).
// ---------------------------------------------------------------------------
#define SWAP1(A, B, IA, IB) { float _t = A; A = B; B = _t; int _u = IA; IA = IB; IB = _u; }
#define INS8G(P, V, ID) do {                                          \
    const float _v = (V); const int _id = (ID);                       \
    if (_v > P##v7) {                                                 \
        P##v7 = _v; P##i7 = _id;                                      \
        if (P##v7 > P##v6) SWAP1(P##v6, P##v7, P##i6, P##i7);         \
        if (P##v6 > P##v5) SWAP1(P##v5, P##v6, P##i5, P##i6);         \
        if (P##v5 > P##v4) SWAP1(P##v4, P##v5, P##i4, P##i5);         \
        if (P##v4 > P##v3) SWAP1(P##v3, P##v4, P##i3, P##i4);         \
        if (P##v3 > P##v2) SWAP1(P##v2, P##v3, P##i2, P##i3);         \
        if (P##v2 > P##v1) SWAP1(P##v1, P##v2, P##i1, P##i2);         \
        if (P##v1 > P##v0) SWAP1(P##v0, P##v1, P##i0, P##i1);         \
    }                                                                 \
} while (0)
#define DECL8(P) float P##v0=-3e38f,P##v1=-3e38f,P##v2=-3e38f,P##v3=-3e38f, \
                       P##v4=-3e38f,P##v5=-3e38f,P##v6=-3e38f,P##v7=-3e38f; \
                 int P##i0=0x7fffffff,P##i1=0x7fffffff,P##i2=0x7fffffff,P##i3=0x7fffffff, \
                     P##i4=0x7fffffff,P##i5=0x7fffffff,P##i6=0x7fffffff,P##i7=0x7fffffff;

// ---------------------------------------------------------------------------
// sim_mfma_b: bf16 MFMA candidate scoring from PRE-CONVERTED bf16 keys.
// r15-proven shape: grid (KSPLITS=32, 16) = 512 blocks, block 256 = 4 waves,
// wave w scores queries qs*64 + w*16..+16. Staging = pure 16B copies.
// ---------------------------------------------------------------------------
__global__ __launch_bounds__(256) void sim_mfma_b(
    const float* __restrict__ qn, const unsigned short* __restrict__ kb,
    float* __restrict__ part_v8, int* __restrict__ part_i8)
{
    __shared__ unsigned short k_lds[64 * 264];
    __shared__ float cand_v[256 * 8];
    __shared__ int   cand_i[256 * 8];
    const int t = threadIdx.x;
    const int wave = t >> 6, lane = t & 63;
    const int ks = blockIdx.x, qs = blockIdx.y;
    const int key_base = ks * KPB;
    const int q0 = qs << 6;
    const int qrow = q0 + (wave << 4) + (lane & 15);
    const int kg = lane >> 4;                 // k-group 0..3

    bf16x8 bq[8];
#pragma unroll
    for (int kc = 0; kc < 8; ++kc) {
        const float* qp = &qn[(size_t)qrow * 256 + (kc << 5) + (kg << 3)];
        const float4 f0 = *(const float4*)qp;
        const float4 f1 = *(const float4*)(qp + 4);
        union { unsigned int u[4]; bf16x8 h; } cv;
        cv.u[0] = pack_bf16(f0.x, f0.y);
        cv.u[1] = pack_bf16(f0.z, f0.w);
        cv.u[2] = pack_bf16(f1.x, f1.y);
        cv.u[3] = pack_bf16(f1.z, f1.w);
        bq[kc] = cv.h;
    }

    DECL8(t)

    const int srow = t >> 2, scol0 = (t & 3) << 6;   // staging: row, 64-col slice

    for (int stg = 0; stg < KPB / 64; ++stg) {
        __syncthreads();
        {
            const unsigned short* kp = &kb[(size_t)(key_base + (stg << 6) + srow) * 256 + scol0];
#pragma unroll
            for (int i = 0; i < 8; ++i)
                *(u16x8*)&k_lds[srow * 264 + scol0 + (i << 3)] = *(const u16x8*)(kp + (i << 3));
        }
        __syncthreads();

#pragma unroll
        for (int kt = 0; kt < 4; ++kt) {
            f32x4 a0 = {0.f, 0.f, 0.f, 0.f};
            f32x4 a1 = {0.f, 0.f, 0.f, 0.f};
#pragma unroll
            for (int kc = 0; kc < 4; ++kc) {
                const bf16x8 af = *(const bf16x8*)&k_lds[((kt << 4) + (lane & 15)) * 264 +
                                                         (kc << 5) + (kg << 3)];
                a0 = __builtin_amdgcn_mfma_f32_16x16x32_bf16(af, bq[kc], a0, 0, 0, 0);
            }
#pragma unroll
            for (int kc = 4; kc < 8; ++kc) {
                const bf16x8 af = *(const bf16x8*)&k_lds[((kt << 4) + (lane & 15)) * 264 +
                                                         (kc << 5) + (kg << 3)];
                a1 = __builtin_amdgcn_mfma_f32_16x16x32_bf16(af, bq[kc], a1, 0, 0, 0);
            }
            const int kidx = key_base + (stg << 6) + (kt << 4) + (kg << 2);
            INS8G(t, a0[0] + a1[0], kidx + 0);
            INS8G(t, a0[1] + a1[1], kidx + 1);
            INS8G(t, a0[2] + a1[2], kidx + 2);
            INS8G(t, a0[3] + a1[3], kidx + 3);
        }
    }

    __syncthreads();
    cand_v[t * 8 + 0] = tv0; cand_i[t * 8 + 0] = ti0;
    cand_v[t * 8 + 1] = tv1; cand_i[t * 8 + 1] = ti1;
    cand_v[t * 8 + 2] = tv2; cand_i[t * 8 + 2] = ti2;
    cand_v[t * 8 + 3] = tv3; cand_i[t * 8 + 3] = ti3;
    cand_v[t * 8 + 4] = tv4; cand_i[t * 8 + 4] = ti4;
    cand_v[t * 8 + 5] = tv5; cand_i[t * 8 + 5] = ti5;
    cand_v[t * 8 + 6] = tv6; cand_i[t * 8 + 6] = ti6;
    cand_v[t * 8 + 7] = tv7; cand_i[t * 8 + 7] = ti7;
    __syncthreads();
    if (t < 64) {
        DECL8(m)
        const int w = t >> 4, c = t & 15;
        for (int g = 0; g < 4; ++g) {
            const int src = ((w << 6) + c + (g << 4)) * 8;
            for (int r = 0; r < 8; ++r)
                INS8G(m, cand_v[src + r], cand_i[src + r]);
        }
        const size_t base = (size_t)(q0 + t) * (KSPLITS * 8) + ks * 8;
        part_v8[base + 0] = mv0; part_i8[base + 0] = mi0;
        part_v8[base + 1] = mv1; part_i8[base + 1] = mi1;
        part_v8[base + 2] = mv2; part_i8[base + 2] = mi2;
        part_v8[base + 3] = mv3; part_i8[base + 3] = mi3;
        part_v8[base + 4] = mv4; part_i8[base + 4] = mi4;
        part_v8[base + 5] = mv5; part_i8[base + 5] = mi5;
        part_v8[base + 6] = mv6; part_i8[base + 6] = mi6;
        part_v8[base + 7] = mv7; part_i8[base + 7] = mi7;
    }
}

// ---------------------------------------------------------------------------
// sim_mfma_f: fp32-key fallback (r12 config) if ws too small for kb.
// ---------------------------------------------------------------------------
__global__ __launch_bounds__(256) void sim_mfma_f(
    const float* __restrict__ qn, const float* __restrict__ keys,
    const float* __restrict__ rnk, float* __restrict__ part_v8, int* __restrict__ part_i8)
{
    __shared__ unsigned short k_lds[64 * 264];
    __shared__ float cand_v[256 * 8];
    __shared__ int   cand_i[256 * 8];
    const int t = threadIdx.x;
    const int wave = t >> 6, lane = t & 63;
    const int ks = blockIdx.x, qs = blockIdx.y;
    const int key_base = ks * KPB;
    const int q0 = qs << 6;
    const int qrow = q0 + (wave << 4) + (lane & 15);
    const int kg = lane >> 4;

    bf16x8 bq[8];
#pragma unroll
    for (int kc = 0; kc < 8; ++kc) {
        const float* qp = &qn[(size_t)qrow * 256 + (kc << 5) + (kg << 3)];
        const float4 f0 = *(const float4*)qp;
        const float4 f1 = *(const float4*)(qp + 4);
        union { unsigned int u[4]; bf16x8 h; } cv;
        cv.u[0] = pack_bf16(f0.x, f0.y);
        cv.u[1] = pack_bf16(f0.z, f0.w);
        cv.u[2] = pack_bf16(f1.x, f1.y);
        cv.u[3] = pack_bf16(f1.z, f1.w);
        bq[kc] = cv.h;
    }

    DECL8(t)

    for (int stg = 0; stg < KPB / 64; ++stg) {
        __syncthreads();
#pragma unroll
        for (int i = 0; i < 8; ++i) {
            const int g = (i << 11) + (t << 3);
            const int row = g >> 8, col = g & 255;
            const int krow = key_base + (stg << 6) + row;
            const float sc = rnk[krow];
            const float* kp = &keys[(size_t)krow * 256 + col];
            float4 f0 = *(const float4*)kp;
            float4 f1 = *(const float4*)(kp + 4);
            f0.x *= sc; f0.y *= sc; f0.z *= sc; f0.w *= sc;
            f1.x *= sc; f1.y *= sc; f1.z *= sc; f1.w *= sc;
            union { unsigned int u[4]; u16x8 h; } cv;
            cv.u[0] = pack_bf16(f0.x, f0.y);
            cv.u[1] = pack_bf16(f0.z, f0.w);
            cv.u[2] = pack_bf16(f1.x, f1.y);
            cv.u[3] = pack_bf16(f1.z, f1.w);
            *(u16x8*)&k_lds[row * 264 + col] = cv.h;
        }
        __syncthreads();

#pragma unroll
        for (int kt = 0; kt < 4; ++kt) {
            f32x4 a0 = {0.f, 0.f, 0.f, 0.f};
            f32x4 a1 = {0.f, 0.f, 0.f, 0.f};
#pragma unroll
            for (int kc = 0; kc < 4; ++kc) {
                const bf16x8 af = *(const bf16x8*)&k_lds[((kt << 4) + (lane & 15)) * 264 +
                                                         (kc << 5) + (kg << 3)];
                a0 = __builtin_amdgcn_mfma_f32_16x16x32_bf16(af, bq[kc], a0, 0, 0, 0);
            }
#pragma unroll
            for (int kc = 4; kc < 8; ++kc) {
                const bf16x8 af = *(const bf16x8*)&k_lds[((kt << 4) + (lane & 15)) * 264 +
                                                         (kc << 5) + (kg << 3)];
                a1 = __builtin_amdgcn_mfma_f32_16x16x32_bf16(af, bq[kc], a1, 0, 0, 0);
            }
            const int kidx = key_base + (stg << 6) + (kt << 4) + (kg << 2);
            INS8G(t, a0[0] + a1[0], kidx + 0);
            INS8G(t, a0[1] + a1[1], kidx + 1);
            INS8G(t, a0[2] + a1[2], kidx + 2);
            INS8G(t, a0[3] + a1[3], kidx + 3);
        }
    }

    __syncthreads();
    cand_v[t * 8 + 0] = tv0; cand_i[t * 8 + 0] = ti0;
    cand_v[t * 8 + 1] = tv1; cand_i[t * 8 + 1] = ti1;
    cand_v[t * 8 + 2] = tv2; cand_i[t * 8 + 2] = ti2;
    cand_v[t * 8 + 3] = tv3; cand_i[t * 8 + 3] = ti3;
    cand_v[t * 8 + 4] = tv4; cand_i[t * 8 + 4] = ti4;
    cand_v[t * 8 + 5] = tv5; cand_i[t * 8 + 5] = ti5;
    cand_v[t * 8 + 6] = tv6; cand_i[t * 8 + 6] = ti6;
    cand_v[t * 8 + 7] = tv7; cand_i[t * 8 + 7] = ti7;
    __syncthreads();
    if (t < 64) {
        DECL8(m)
        const int w = t >> 4, c = t & 15;
        for (int g = 0; g < 4; ++g) {
            const int src = ((w << 6) + c + (g << 4)) * 8;
            for (int r = 0; r < 8; ++r)
                INS8G(m, cand_v[src + r], cand_i[src + r]);
        }
        const size_t base = (size_t)(q0 + t) * (KSPLITS * 8) + ks * 8;
        part_v8[base + 0] = mv0; part_i8[base + 0] = mi0;
        part_v8[base + 1] = mv1; part_i8[base + 1] = mi1;
        part_v8[base + 2] = mv2; part_i8[base + 2] = mi2;
        part_v8[base + 3] = mv3; part_i8[base + 3] = mi3;
        part_v8[base + 4] = mv4; part_i8[base + 4] = mi4;
        part_v8[base + 5] = mv5; part_i8[base + 5] = mi5;
        part_v8[base + 6] = mv6; part_i8[base + 6] = mi6;
        part_v8[base + 7] = mv7; part_i8[base + 7] = mi7;
    }
}

// ---------------------------------------------------------------------------
__global__ void cand_merge(const float* __restrict__ part_v8, const int* __restrict__ part_i8,
                           int* __restrict__ cand8_i)
{
    const int q = blockIdx.x * 256 + threadIdx.x;
    if (q >= ROWS) return;
    DECL8(c)
    for (int j = 0; j < KSPLITS * 8; ++j)
        INS8G(c, part_v8[(size_t)q * (KSPLITS * 8) + j], part_i8[(size_t)q * (KSPLITS * 8) + j]);
    cand8_i[q * 8 + 0] = ci0; cand8_i[q * 8 + 1] = ci1;
    cand8_i[q * 8 + 2] = ci2; cand8_i[q * 8 + 3] = ci3;
    cand8_i[q * 8 + 4] = ci4; cand8_i[q * 8 + 5] = ci5;
    cand8_i[q * 8 + 6] = ci6; cand8_i[q * 8 + 7] = ci7;
}

// ---------------------------------------------------------------------------
// Fused: fp32 rescore of the 8 candidates -> exact top-3 (reference
// tie-break) -> gather values -> attention softmax -> weighted sum.
// ---------------------------------------------------------------------------
__global__ void rescore_gather(const float* __restrict__ qn, const float* __restrict__ keys,
                               const float* __restrict__ rnk, const int* __restrict__ cand8_i,
                               const float* __restrict__ values, const float* __restrict__ Wa,
                               const float* __restrict__ ba, float* __restrict__ mem_raw)
{
    const int q = blockIdx.x;
    const int lane = threadIdx.x;
    const float4 qv = *(const float4*)&qn[(size_t)q * 256 + (lane << 2)];
    float s0, s1, s2, s3, s4, s5, s6, s7;
    int j0, j1, j2, j3, j4, j5, j6, j7;
#define RES(R, S, J) { J = cand8_i[q * 8 + R]; \
    const float4 kv = *(const float4*)&keys[(size_t)J * 256 + (lane << 2)]; \
    float d = qv.x * kv.x + qv.y * kv.y + qv.z * kv.z + qv.w * kv.w; \
    d += __shfl_xor(d, 1); d += __shfl_xor(d, 2); d += __shfl_xor(d, 4); \
    d += __shfl_xor(d, 8); d += __shfl_xor(d, 16); d += __shfl_xor(d, 32); \
    S = d * rnk[J]; }
    RES(0, s0, j0) RES(1, s1, j1) RES(2, s2, j2) RES(3, s3, j3)
    RES(4, s4, j4) RES(5, s5, j5) RES(6, s6, j6) RES(7, s7, j7)
#undef RES
    int top[3];
#define BET(SV, JV) if (SV > bv || (SV == bv && JV < bi)) { bv = SV; bi = JV; }
#pragma unroll
    for (int k = 0; k < 3; ++k) {
        float bv = s0; int bi = j0;
        BET(s1, j1) BET(s2, j2) BET(s3, j3) BET(s4, j4)
        BET(s5, j5) BET(s6, j6) BET(s7, j7)
        top[k] = bi;
        if (j0 == bi) s0 = -3e38f;
        if (j1 == bi) s1 = -3e38f;
        if (j2 == bi) s2 = -3e38f;
        if (j3 == bi) s3 = -3e38f;
        if (j4 == bi) s4 = -3e38f;
        if (j5 == bi) s5 = -3e38f;
        if (j6 == bi) s6 = -3e38f;
        if (j7 == bi) s7 = -3e38f;
    }
#undef BET
    const float4 wa = *(const float4*)&Wa[lane << 2];
    float4 vr[3];
    float lg[3];
#pragma unroll
    for (int r = 0; r < 3; ++r) {
        const float4 v = *(const float4*)&values[(size_t)top[r] * 256 + (lane << 2)];
        vr[r] = v;
        float d = v.x * wa.x + v.y * wa.y + v.z * wa.z + v.w * wa.w;
#pragma unroll
        for (int o = 1; o < 64; o <<= 1) d += __shfl_xor(d, o);
        lg[r] = d + ba[0];
    }
    const float mx = fmaxf(lg[0], fmaxf(lg[1], lg[2]));
    float e0 = __expf(lg[0] - mx), e1 = __expf(lg[1] - mx), e2 = __expf(lg[2] - mx);
    const float inv = 1.f / (e0 + e1 + e2);
    e0 *= inv; e1 *= inv; e2 *= inv;
    float4 m;
    m.x = e0 * vr[0].x + e1 * vr[1].x + e2 * vr[2].x;
    m.y = e0 * vr[0].y + e1 * vr[1].y + e2 * vr[2].y;
    m.z = e0 * vr[0].z + e1 * vr[1].z + e2 * vr[2].z;
    m.w = e0 * vr[0].w + e1 * vr[1].w + e2 * vr[2].w;
    *(float4*)&mem_raw[(size_t)q * 256 + (lane << 2)] = m;
}

// ---------------------------------------------------------------------------
extern "C" void kernel_launch(void* const* d_in, const int* in_sizes, int n_in,
                              void* d_out, int out_size, void* d_ws, size_t ws_size,
                              hipStream_t stream)
{
    (void)in_sizes; (void)n_in; (void)out_size;
    const float* x     = (const float*)d_in[0];
    const float* keys  = (const float*)d_in[1];
    const float* values= (const float*)d_in[2];
    const float* imp   = (const float*)d_in[3];
    const float* W_ih  = (const float*)d_in[4];
    const float* W_hh  = (const float*)d_in[5];
    const float* b_ih  = (const float*)d_in[6];
    const float* b_hh  = (const float*)d_in[7];
    const float* Wq    = (const float*)d_in[8];
    const float* bq    = (const float*)d_in[9];
    const float* Wa    = (const float*)d_in[10];
    const float* ba    = (const float*)d_in[11];
    const float* Wc    = (const float*)d_in[12];
    const float* bc    = (const float*)d_in[13];
    const float* Wo    = (const float*)d_in[14];
    const float* bo    = (const float*)d_in[15];
    float* out = (float*)d_out;

    float* ws = (float*)d_ws;
    size_t o = 0;
    float* xp      = ws + o; o += (size_t)1024 * 4096;           // 16 MB
    float* h_all   = ws + o; o += (size_t)1024 * 1024;           // 4 MB
    unsigned* rec  = (unsigned*)(ws + o); o += 2 * 4096;         // tagged records
    float* rnk     = ws + o; o += NKEY;                          // imp/||key||
    float* qbuf    = ws + o; o += (size_t)ROWS * 256;
    float* qn      = ws + o; o += (size_t)ROWS * 256;
    float* part_v8 = ws + o; o += (size_t)ROWS * KSPLITS * 8;    // 1 MB
    int*   part_i8 = (int*)(ws + o); o += (size_t)ROWS * KSPLITS * 8;
    int*   cand8_i = (int*)(ws + o); o += ROWS * 8;
    float* mem_raw = ws + o; o += (size_t)ROWS * 256;
    float* memb    = ws + o; o += (size_t)ROWS * 256;
    unsigned short* kb = (unsigned short*)(ws + o);              // bf16 keys, 32 MB
    const size_t need_bf16 = (o + (size_t)NKEY * 256 / 2) * sizeof(float);
    const bool use_bf16 = ws_size >= need_bf16;                  // deterministic

    // zero records: slot-0 tag byte = 0 (= step-0 tag) with h = +0.0
    hipMemsetAsync(rec, 0, 2 * 4096 * 4, stream);

    // x_proj = x @ W_ih^T + b_ih + b_hh : [1024, 4096]
    sgemm_nt_w<<<dim3(32, 16), 256, 0, stream>>>(x, W_ih, xp, b_ih, b_hh);

    // LSTM recurrence (blocks 0-255) + key-prep riders (blocks 256-511)
    lstm_kernel<<<2 * NWG_LSTM, NTH_LSTM, 0, stream>>>(
        xp, W_hh, rec, h_all, keys, imp, rnk, use_bf16 ? kb : nullptr);

    // q = h @ Wq^T + bq : [1024, 256]
    sgemm_nt<<<dim3(4, 16), 256, 0, stream>>>(h_all, HD, Wq, HD, qbuf, MD, HD, bq, nullptr, 0);

    rownorm<<<ROWS / 4, 256, 0, stream>>>(qbuf, qn, ROWS);

    // bf16 MFMA candidate scoring + fp32 rescore -> exact top-3 + gather
    if (use_bf16)
        sim_mfma_b<<<dim3(KSPLITS, 16), 256, 0, stream>>>(qn, kb, part_v8, part_i8);
    else
        sim_mfma_f<<<dim3(KSPLITS, 16), 256, 0, stream>>>(qn, keys, rnk, part_v8, part_i8);
    cand_merge<<<ROWS / 256, 256, 0, stream>>>(part_v8, part_i8, cand8_i);
    rescore_gather<<<ROWS, 64, 0, stream>>>(qn, keys, rnk, cand8_i, values, Wa, ba, mem_raw);

    // mem = mem_raw @ Wc^T + bc
    sgemm_nt<<<dim3(4, 16), 256, 0, stream>>>(mem_raw, MD, Wc, MD, memb, MD, MD, bc, nullptr, 0);

    // out = [h, mem] @ Wo^T + bo  (split K)
    sgemm_nt<<<dim3(8, 16), 256, 0, stream>>>(h_all, HD, Wo, HD + MD, out, OD, HD, bo, nullptr, 0);
    sgemm_nt<<<dim3(8, 16), 256, 0, stream>>>(memb, MD, Wo + HD, HD + MD, out, OD, MD, nullptr, nullptr, 1);
}

// Round 18
// 1261.799 us; speedup vs baseline: 1.1074x; 1.0501x over previous
//
#include <hip/hip_runtime.h>
#include <hip/hip_bf16.h>
#include <cstdint>
#include <cstddef>

// Problem constants
#define BB 4
#define SS 256
#define ID 512
#define HD 1024
#define MD 256
#define NKEY 65536
#define OD 512
#define ROWS 1024          // B*S
#define NWG_LSTM 256
#define NTH_LSTM 256
#define KPB 2048           // keys per sim block
#define KSPLITS (NKEY / KPB)   // 32

typedef __attribute__((ext_vector_type(8))) short bf16x8;
typedef __attribute__((ext_vector_type(4))) float f32x4;
typedef __attribute__((ext_vector_type(8))) unsigned short u16x8;

// ---------------------------------------------------------------------------
// Generic SGEMM: C[M,N] = A[M,K] * Bm[N,K]^T (+bias) or C += ...
// 64x64 tile, 256 threads, 4x4 micro-tile. Grid: (N/64, M/64).
// ---------------------------------------------------------------------------
__global__ __launch_bounds__(256) void sgemm_nt(
    const float* __restrict__ A, int lda,
    const float* __restrict__ Bm, int ldb,
    float* __restrict__ C, int ldc, int K,
    const float* __restrict__ bias, const float* __restrict__ bias2,
    int accum)
{
    __shared__ float As[64][17];
    __shared__ float Bs[64][17];
    const int t = threadIdx.x;
    const int tx = t & 15, ty = t >> 4;
    const int bm = blockIdx.y << 6, bn = blockIdx.x << 6;
    const int lrow = t >> 2, lk4 = (t & 3) << 2;
    float acc[4][4] = {};

    for (int kb = 0; kb < K; kb += 16) {
        const float4 av = *(const float4*)&A[(size_t)(bm + lrow) * lda + kb + lk4];
        const float4 bv = *(const float4*)&Bm[(size_t)(bn + lrow) * ldb + kb + lk4];
        __syncthreads();
        As[lrow][lk4 + 0] = av.x; As[lrow][lk4 + 1] = av.y;
        As[lrow][lk4 + 2] = av.z; As[lrow][lk4 + 3] = av.w;
        Bs[lrow][lk4 + 0] = bv.x; Bs[lrow][lk4 + 1] = bv.y;
        Bs[lrow][lk4 + 2] = bv.z; Bs[lrow][lk4 + 3] = bv.w;
        __syncthreads();
#pragma unroll
        for (int k = 0; k < 16; ++k) {
            const float a0 = As[4 * ty + 0][k], a1 = As[4 * ty + 1][k];
            const float a2 = As[4 * ty + 2][k], a3 = As[4 * ty + 3][k];
            const float b0 = Bs[4 * tx + 0][k], b1 = Bs[4 * tx + 1][k];
            const float b2 = Bs[4 * tx + 2][k], b3 = Bs[4 * tx + 3][k];
            acc[0][0] += a0 * b0; acc[0][1] += a0 * b1; acc[0][2] += a0 * b2; acc[0][3] += a0 * b3;
            acc[1][0] += a1 * b0; acc[1][1] += a1 * b1; acc[1][2] += a1 * b2; acc[1][3] += a1 * b3;
            acc[2][0] += a2 * b0; acc[2][1] += a2 * b1; acc[2][2] += a2 * b2; acc[2][3] += a2 * b3;
            acc[3][0] += a3 * b0; acc[3][1] += a3 * b1; acc[3][2] += a3 * b2; acc[3][3] += a3 * b3;
        }
    }

#pragma unroll
    for (int i = 0; i < 4; ++i) {
        const int row = bm + 4 * ty + i;
        const int col = bn + 4 * tx;
        float4* cp = (float4*)&C[(size_t)row * ldc + col];
        float4 r;
        if (accum) {
            const float4 old = *cp;
            r.x = old.x + acc[i][0]; r.y = old.y + acc[i][1];
            r.z = old.z + acc[i][2]; r.w = old.w + acc[i][3];
        } else {
            float bx = bias[col + 0], by = bias[col + 1], bz = bias[col + 2], bw = bias[col + 3];
            if (bias2) { bx += bias2[col + 0]; by += bias2[col + 1]; bz += bias2[col + 2]; bw += bias2[col + 3]; }
            r.x = acc[i][0] + bx; r.y = acc[i][1] + by;
            r.z = acc[i][2] + bz; r.w = acc[i][3] + bw;
        }
        *cp = r;
    }
}

// ---------------------------------------------------------------------------
// x_proj GEMM: C[1024,4096] = A[1024,512] @ Bm[4096,512]^T + bias1 + bias2.
// 64(M) x 128(N) tile, 256 threads, micro 4x8, k-major LDS. Grid (32, 16).
// ---------------------------------------------------------------------------
__global__ __launch_bounds__(256) void sgemm_nt_w(
    const float* __restrict__ A, const float* __restrict__ Bm,
    float* __restrict__ C, const float* __restrict__ bias, const float* __restrict__ bias2)
{
    __shared__ float As[16][64];
    __shared__ float Bs[16][128];
    const int t = threadIdx.x;
    const int tx = t & 15, ty = t >> 4;
    const int bm = blockIdx.y << 6, bn = blockIdx.x << 7;
    const int arow = t & 63, akq = t >> 6;       // A: 1 float4 per thread
    const int brow = t & 127, bkq = t >> 7;      // B: 2 float4 per thread
    float acc[4][8] = {};

    for (int kb = 0; kb < 512; kb += 16) {
        const float4 av  = *(const float4*)&A[(size_t)(bm + arow) * 512 + kb + (akq << 2)];
        const float4 bv0 = *(const float4*)&Bm[(size_t)(bn + brow) * 512 + kb + (bkq << 3)];
        const float4 bv1 = *(const float4*)&Bm[(size_t)(bn + brow) * 512 + kb + (bkq << 3) + 4];
        __syncthreads();
        As[(akq << 2) + 0][arow] = av.x; As[(akq << 2) + 1][arow] = av.y;
        As[(akq << 2) + 2][arow] = av.z; As[(akq << 2) + 3][arow] = av.w;
        Bs[(bkq << 3) + 0][brow] = bv0.x; Bs[(bkq << 3) + 1][brow] = bv0.y;
        Bs[(bkq << 3) + 2][brow] = bv0.z; Bs[(bkq << 3) + 3][brow] = bv0.w;
        Bs[(bkq << 3) + 4][brow] = bv1.x; Bs[(bkq << 3) + 5][brow] = bv1.y;
        Bs[(bkq << 3) + 6][brow] = bv1.z; Bs[(bkq << 3) + 7][brow] = bv1.w;
        __syncthreads();
#pragma unroll
        for (int k = 0; k < 16; ++k) {
            const float4 a  = *(const float4*)&As[k][ty << 2];
            const float4 b0 = *(const float4*)&Bs[k][tx << 3];
            const float4 b1 = *(const float4*)&Bs[k][(tx << 3) + 4];
            acc[0][0] += a.x * b0.x; acc[0][1] += a.x * b0.y; acc[0][2] += a.x * b0.z; acc[0][3] += a.x * b0.w;
            acc[0][4] += a.x * b1.x; acc[0][5] += a.x * b1.y; acc[0][6] += a.x * b1.z; acc[0][7] += a.x * b1.w;
            acc[1][0] += a.y * b0.x; acc[1][1] += a.y * b0.y; acc[1][2] += a.y * b0.z; acc[1][3] += a.y * b0.w;
            acc[1][4] += a.y * b1.x; acc[1][5] += a.y * b1.y; acc[1][6] += a.y * b1.z; acc[1][7] += a.y * b1.w;
            acc[2][0] += a.z * b0.x; acc[2][1] += a.z * b0.y; acc[2][2] += a.z * b0.z; acc[2][3] += a.z * b0.w;
            acc[2][4] += a.z * b1.x; acc[2][5] += a.z * b1.y; acc[2][6] += a.z * b1.z; acc[2][7] += a.z * b1.w;
            acc[3][0] += a.w * b0.x; acc[3][1] += a.w * b0.y; acc[3][2] += a.w * b0.z; acc[3][3] += a.w * b0.w;
            acc[3][4] += a.w * b1.x; acc[3][5] += a.w * b1.y; acc[3][6] += a.w * b1.z; acc[3][7] += a.w * b1.w;
        }
    }

#pragma unroll
    for (int i = 0; i < 4; ++i) {
        const int row = bm + (ty << 2) + i;
        const int col = bn + (tx << 3);
        float4 r0, r1;
        r0.x = acc[i][0] + bias[col + 0] + bias2[col + 0];
        r0.y = acc[i][1] + bias[col + 1] + bias2[col + 1];
        r0.z = acc[i][2] + bias[col + 2] + bias2[col + 2];
        r0.w = acc[i][3] + bias[col + 3] + bias2[col + 3];
        r1.x = acc[i][4] + bias[col + 4] + bias2[col + 4];
        r1.y = acc[i][5] + bias[col + 5] + bias2[col + 5];
        r1.z = acc[i][6] + bias[col + 6] + bias2[col + 6];
        r1.w = acc[i][7] + bias[col + 7] + bias2[col + 7];
        *(float4*)&C[(size_t)row * 4096 + col] = r0;
        *(float4*)&C[(size_t)row * 4096 + col + 4] = r1;
    }
}

__device__ inline unsigned pack_bf16(float a, float b) {
    return (__float_as_uint(a) >> 16) | (__float_as_uint(b) & 0xFFFF0000u);
}

// ---------------------------------------------------------------------------
// Row L2-normalization (256-col rows), for qn.
// ---------------------------------------------------------------------------
__global__ void rownorm(const float* __restrict__ X, float* __restrict__ Xn, int nrows)
{
    const int row = blockIdx.x * 4 + (threadIdx.x >> 6);
    const int lane = threadIdx.x & 63;
    if (row >= nrows) return;
    float4 v = *(const float4*)&X[(size_t)row * 256 + (lane << 2)];
    float ss = v.x * v.x + v.y * v.y + v.z * v.z + v.w * v.w;
#pragma unroll
    for (int o = 1; o < 64; o <<= 1) ss += __shfl_xor(ss, o);
    const float sc = 1.f / fmaxf(sqrtf(ss), 1e-12f);
    v.x *= sc; v.y *= sc; v.z *= sc; v.w *= sc;
    *(float4*)&Xn[(size_t)row * 256 + (lane << 2)] = v;
}

// ---------------------------------------------------------------------------
// Persistent LSTM (blocks 0..255, proven round-10 depth-1 pipeline) +
// key-prep rider blocks (256..511).
// ---------------------------------------------------------------------------
__device__ inline float sigm_f(float x) { return 1.f / (1.f + __expf(-x)); }
__device__ inline float tanh_f(float x) { return 1.f - 2.f / (__expf(2.f * x) + 1.f); }

#define SUBSTEP(B, U, UN, C4, XPC) do {                                           \
    asm volatile("s_waitcnt vmcnt(3)" ::: "memory");                              \
    __builtin_amdgcn_sched_barrier(0);                                            \
    const unsigned* pb_ = rec + (slot << 12) + (B << 10) + (t << 2);              \
    while ((((U.x ^ st) | (U.y ^ st) | (U.z ^ st) | (U.w ^ st)) & 0xFFu) != 0u) { \
        __builtin_amdgcn_s_sleep(1);                                              \
        asm volatile("global_load_dwordx4 %0, %1, off sc0 sc1\n\ts_waitcnt vmcnt(0)" \
                     : "=&v"(U) : "v"(pb_) : "memory");                           \
    }                                                                             \
    {                                                                             \
        float4 hw_;                                                               \
        hw_.x = __uint_as_float(U.x & 0xFFFFFF00u);                               \
        hw_.y = __uint_as_float(U.y & 0xFFFFFF00u);                               \
        hw_.z = __uint_as_float(U.z & 0xFFFFFF00u);                               \
        hw_.w = __uint_as_float(U.w & 0xFFFFFF00u);                               \
        *(float4*)&h_lds[B][t << 2] = hw_;                                        \
    }                                                                             \
    asm volatile("s_waitcnt lgkmcnt(0)" ::: "memory");                            \
    __builtin_amdgcn_sched_barrier(0);                                            \
    __builtin_amdgcn_s_barrier();                                                 \
    {                                                                             \
        const unsigned* pn_ = rec + (((B == 3) ? (slot ^ 1) : slot) << 12)        \
                              + (((B + 1) & 3) << 10) + (t << 2);                 \
        asm volatile("global_load_dwordx4 %0, %1, off sc0 sc1"                    \
                     : "=&v"(UN) : "v"(pn_) : "memory");                          \
    }                                                                             \
    const float* hb_ = &h_lds[B][0];                                              \
    float ax_ = 0.f, ay_ = 0.f, az_ = 0.f, aw_ = 0.f;                             \
    _Pragma("unroll")                                                             \
    for (int j = 0; j < 16; ++j) {                                                \
        const float4 hv_ = *(const float4*)&hb_[(ksub << 2) + (j << 6)];          \
        ax_ += w4[j].x * hv_.x; ay_ += w4[j].y * hv_.y;                           \
        az_ += w4[j].z * hv_.z; aw_ += w4[j].w * hv_.w;                           \
    }                                                                             \
    float sm_ = (ax_ + ay_) + (az_ + aw_);                                        \
    sm_ += __shfl_xor(sm_, 1); sm_ += __shfl_xor(sm_, 2);                         \
    sm_ += __shfl_xor(sm_, 4); sm_ += __shfl_xor(sm_, 8);                         \
    sm_ += XPC;                                                                   \
    const float vi_ = __shfl(sm_, ksub);                                          \
    const float vf_ = __shfl(sm_, ksub + 16);                                     \
    const float vg_ = __shfl(sm_, ksub + 32);                                     \
    const float vo_ = __shfl(sm_, ksub + 48);                                     \
    const float iv_ = sigm_f(vi_), fv_ = sigm_f(vf_);                             \
    const float gv_ = tanh_f(vg_), ov_ = sigm_f(vo_);                             \
    C4 = fv_ * C4 + iv_ * gv_;                                                    \
    const float hvv_ = ov_ * tanh_f(C4);                                          \
    if (lane == 0) {                                                              \
        unsigned* dst_ = rec + ((slot ^ 1) << 12) + (B << 10) + unit;             \
        const unsigned uv_ = (__float_as_uint(hvv_) & 0xFFFFFF00u) |              \
                             ((unsigned)(s + 1) & 0xFFu);                         \
        float* ha_ = &h_all[(size_t)((B << 8) + s) * 1024 + unit];                \
        asm volatile("global_store_dword %0, %1, off sc0 sc1"                     \
                     :: "v"(dst_), "v"(uv_) : "memory");                          \
        asm volatile("global_store_dword %0, %1, off"                             \
                     :: "v"(ha_), "v"(hvv_) : "memory");                          \
    }                                                                             \
    {                                                                             \
        const float* px_ = &xp[(size_t)((B << 8) + sn) * 4096 + wrow];            \
        asm volatile("global_load_dword %0, %1, off"                              \
                     : "=&v"(XPC) : "v"(px_) : "memory");                         \
    }                                                                             \
} while (0)

__global__ __launch_bounds__(256) void lstm_kernel(
    const float* __restrict__ xp, const float* __restrict__ W_hh,
    unsigned* __restrict__ rec, float* __restrict__ h_all,
    const float* __restrict__ keys, const float* __restrict__ imp,
    float* __restrict__ rnk, unsigned short* __restrict__ kb)
{
    __shared__ float h_lds[4][1024];
    const int t = threadIdx.x;

    if (blockIdx.x >= NWG_LSTM) {
        // ---- key-prep rider: 256 rows per block ----
        const int base_row = (blockIdx.x - NWG_LSTM) << 8;
        const int lane = t & 63;
        for (int it = 0; it < 64; ++it) {
            const int row = base_row + (it << 2) + (t >> 6);
            float4 v = *(const float4*)&keys[(size_t)row * 256 + (lane << 2)];
            float ss = v.x * v.x + v.y * v.y + v.z * v.z + v.w * v.w;
#pragma unroll
            for (int o = 1; o < 64; o <<= 1) ss += __shfl_xor(ss, o);
            const float sc = imp[row] / fmaxf(sqrtf(ss), 1e-12f);
            if (lane == 0) rnk[row] = sc;
            if (kb) {
                uint2 p;
                p.x = pack_bf16(v.x * sc, v.y * sc);
                p.y = pack_bf16(v.z * sc, v.w * sc);
                *(uint2*)&kb[(size_t)row * 256 + (lane << 2)] = p;
            }
        }
        return;
    }

    const int wave = t >> 6, lane = t & 63;
    const int gt = lane >> 4, ksub = lane & 15;   // gate 0..3 (i,f,g,o), k-sub 0..15
    const int unit = (blockIdx.x << 2) + wave;
    const int wrow = (gt << 10) + unit;           // W_hh row

    float4 w4[16];
#pragma unroll
    for (int j = 0; j < 16; ++j)
        w4[j] = *(const float4*)&W_hh[(size_t)wrow * 1024 + (ksub << 2) + (j << 6)];

    float c40 = 0.f, c41 = 0.f, c42 = 0.f, c43 = 0.f;   // cell state (per-lane)
    float xpc0 = xp[(size_t)(0 * 256 + 0) * 4096 + wrow];
    float xpc1 = xp[(size_t)(1 * 256 + 0) * 4096 + wrow];
    float xpc2 = xp[(size_t)(2 * 256 + 0) * 4096 + wrow];
    float xpc3 = xp[(size_t)(3 * 256 + 0) * 4096 + wrow];

    uint4 u0 = make_uint4(~0u, ~0u, ~0u, ~0u);    // tag 0xFF -> retry path on
    uint4 u1 = u0, u2 = u0, u3 = u0;              // first use (never a step tag)

    // prologue: issue poll for (s=0,b=0) and drain so the pipeline count is exact
    {
        const unsigned* p00 = rec + (t << 2);
        asm volatile("global_load_dwordx4 %0, %1, off sc0 sc1\n\ts_waitcnt vmcnt(0)"
                     : "=&v"(u0) : "v"(p00) : "memory");
        __builtin_amdgcn_sched_barrier(0);
    }

    for (int s = 0; s < 256; ++s) {
        const int slot = s & 1;
        const unsigned st = (unsigned)s & 0xFFu;
        const int sn = (s < 255) ? s + 1 : 255;   // clamped next-step xp row
        SUBSTEP(0, u0, u1, c40, xpc0);
        SUBSTEP(1, u1, u2, c41, xpc1);
        SUBSTEP(2, u2, u3, c42, xpc2);
        SUBSTEP(3, u3, u0, c43, xpc3);
    }
}

// ---------------------------------------------------------------------------
// Static-register top-8 insertion (sorted v0>=...>=v7).
// ---------------------------------------------------------------------------
#define SWAP1(A, B, IA, IB) { float _t = A; A = B; B = _t; int _u = IA; IA = IB; IB = _u; }
#define INS8G(P, V, ID) do {                                          \
    const float _v = (V); const int _id = (ID);                       \
    if (_v > P##v7) {                                                 \
        P##v7 = _v; P##i7 = _id;                                      \
        if (P##v7 > P##v6) SWAP1(P##v6, P##v7, P##i6, P##i7);         \
        if (P##v6 > P##v5) SWAP1(P##v5, P##v6, P##i5, P##i6);         \
        if (P##v5 > P##v4) SWAP1(P##v4, P##v5, P##i4, P##i5);         \
        if (P##v4 > P##v3) SWAP1(P##v3, P##v4, P##i3, P##i4);         \
        if (P##v3 > P##v2) SWAP1(P##v2, P##v3, P##i2, P##i3);         \
        if (P##v2 > P##v1) SWAP1(P##v1, P##v2, P##i1, P##i2);         \
        if (P##v1 > P##v0) SWAP1(P##v0, P##v1, P##i0, P##i1);         \
    }                                                                 \
} while (0)
#define DECL8(P) float P##v0=-3e38f,P##v1=-3e38f,P##v2=-3e38f,P##v3=-3e38f, \
                       P##v4=-3e38f,P##v5=-3e38f,P##v6=-3e38f,P##v7=-3e38f; \
                 int P##i0=0x7fffffff,P##i1=0x7fffffff,P##i2=0x7fffffff,P##i3=0x7fffffff, \
                     P##i4=0x7fffffff,P##i5=0x7fffffff,P##i6=0x7fffffff,P##i7=0x7fffffff;

// ---------------------------------------------------------------------------
// sim_mfma_b8: bf16 MFMA candidate scoring from pre-converted bf16 keys,
// 8 waves per block sharing one staged key tile. Grid (KSPLITS=32, 8) =
// 256 blocks x 512 threads = 8 waves/CU = 2 waves/SIMD (same occupancy as
// the proven 4-wave config; only the block boundary moves). Per-wave work
// identical to r12 (16 queries, one bq set). Key traffic: 8 query-splits
// x 32 MB = 256 MB (was 512). Merge: cand arrays alias onto k_lds.
// ---------------------------------------------------------------------------
__global__ __launch_bounds__(512) void sim_mfma_b8(
    const float* __restrict__ qn, const unsigned short* __restrict__ kb,
    float* __restrict__ part_v8, int* __restrict__ part_i8)
{
    __shared__ unsigned short k_lds[64 * 264];    // 33 KB; merge aliases onto it
    const int t = threadIdx.x;
    const int wave = t >> 6, lane = t & 63;
    const int ks = blockIdx.x, qs = blockIdx.y;
    const int key_base = ks * KPB;
    const int q0 = qs << 7;                       // 128 queries per block
    const int qrow = q0 + (wave << 4) + (lane & 15);
    const int kg = lane >> 4;                     // k-group 0..3

    bf16x8 bq[8];
#pragma unroll
    for (int kc = 0; kc < 8; ++kc) {
        const float* qp = &qn[(size_t)qrow * 256 + (kc << 5) + (kg << 3)];
        const float4 f0 = *(const float4*)qp;
        const float4 f1 = *(const float4*)(qp + 4);
        union { unsigned int u[4]; bf16x8 h; } cv;
        cv.u[0] = pack_bf16(f0.x, f0.y);
        cv.u[1] = pack_bf16(f0.z, f0.w);
        cv.u[2] = pack_bf16(f1.x, f1.y);
        cv.u[3] = pack_bf16(f1.z, f1.w);
        bq[kc] = cv.h;
    }

    DECL8(t)

    const int srow = t >> 3, scol0 = (t & 7) << 5;   // staging: row, 32-col slice

    for (int stg = 0; stg < KPB / 64; ++stg) {
        __syncthreads();
        {
            const unsigned short* kp = &kb[(size_t)(key_base + (stg << 6) + srow) * 256 + scol0];
#pragma unroll
            for (int i = 0; i < 4; ++i)
                *(u16x8*)&k_lds[srow * 264 + scol0 + (i << 3)] = *(const u16x8*)(kp + (i << 3));
        }
        __syncthreads();

#pragma unroll
        for (int kt = 0; kt < 4; ++kt) {
            f32x4 a0 = {0.f, 0.f, 0.f, 0.f};
            f32x4 a1 = {0.f, 0.f, 0.f, 0.f};
#pragma unroll
            for (int kc = 0; kc < 4; ++kc) {
                const bf16x8 af = *(const bf16x8*)&k_lds[((kt << 4) + (lane & 15)) * 264 +
                                                         (kc << 5) + (kg << 3)];
                a0 = __builtin_amdgcn_mfma_f32_16x16x32_bf16(af, bq[kc], a0, 0, 0, 0);
            }
#pragma unroll
            for (int kc = 4; kc < 8; ++kc) {
                const bf16x8 af = *(const bf16x8*)&k_lds[((kt << 4) + (lane & 15)) * 264 +
                                                         (kc << 5) + (kg << 3)];
                a1 = __builtin_amdgcn_mfma_f32_16x16x32_bf16(af, bq[kc], a1, 0, 0, 0);
            }
            const int kidx = key_base + (stg << 6) + (kt << 4) + (kg << 2);
            INS8G(t, a0[0] + a1[0], kidx + 0);
            INS8G(t, a0[1] + a1[1], kidx + 1);
            INS8G(t, a0[2] + a1[2], kidx + 2);
            INS8G(t, a0[3] + a1[3], kidx + 3);
        }
    }

    // ---- merge phase: alias cand arrays onto k_lds (32 KB <= 33 KB) ----
    float* cand_v = (float*)k_lds;                 // [512][8] floats, 16 KB
    int*   cand_i = (int*)(k_lds + 8192);          // [512][8] ints,   16 KB
    __syncthreads();
    cand_v[t * 8 + 0] = tv0; cand_i[t * 8 + 0] = ti0;
    cand_v[t * 8 + 1] = tv1; cand_i[t * 8 + 1] = ti1;
    cand_v[t * 8 + 2] = tv2; cand_i[t * 8 + 2] = ti2;
    cand_v[t * 8 + 3] = tv3; cand_i[t * 8 + 3] = ti3;
    cand_v[t * 8 + 4] = tv4; cand_i[t * 8 + 4] = ti4;
    cand_v[t * 8 + 5] = tv5; cand_i[t * 8 + 5] = ti5;
    cand_v[t * 8 + 6] = tv6; cand_i[t * 8 + 6] = ti6;
    cand_v[t * 8 + 7] = tv7; cand_i[t * 8 + 7] = ti7;
    __syncthreads();
    if (t < 128) {
        DECL8(m)
        const int w = t >> 4, c = t & 15;          // query q0+t = wave w, col c
        for (int g = 0; g < 4; ++g) {
            const int src = ((w << 6) + (g << 4) + c) * 8;
            for (int r = 0; r < 8; ++r)
                INS8G(m, cand_v[src + r], cand_i[src + r]);
        }
        const size_t base = (size_t)(q0 + t) * (KSPLITS * 8) + ks * 8;
        part_v8[base + 0] = mv0; part_i8[base + 0] = mi0;
        part_v8[base + 1] = mv1; part_i8[base + 1] = mi1;
        part_v8[base + 2] = mv2; part_i8[base + 2] = mi2;
        part_v8[base + 3] = mv3; part_i8[base + 3] = mi3;
        part_v8[base + 4] = mv4; part_i8[base + 4] = mi4;
        part_v8[base + 5] = mv5; part_i8[base + 5] = mi5;
        part_v8[base + 6] = mv6; part_i8[base + 6] = mi6;
        part_v8[base + 7] = mv7; part_i8[base + 7] = mi7;
    }
}

// ---------------------------------------------------------------------------
// sim_mfma_f: fp32-key fallback (r12 config) if ws too small for kb.
// ---------------------------------------------------------------------------
__global__ __launch_bounds__(256) void sim_mfma_f(
    const float* __restrict__ qn, const float* __restrict__ keys,
    const float* __restrict__ rnk, float* __restrict__ part_v8, int* __restrict__ part_i8)
{
    __shared__ unsigned short k_lds[64 * 264];
    __shared__ float cand_v[256 * 8];
    __shared__ int   cand_i[256 * 8];
    const int t = threadIdx.x;
    const int wave = t >> 6, lane = t & 63;
    const int ks = blockIdx.x, qs = blockIdx.y;
    const int key_base = ks * KPB;
    const int q0 = qs << 6;
    const int qrow = q0 + (wave << 4) + (lane & 15);
    const int kg = lane >> 4;

    bf16x8 bq[8];
#pragma unroll
    for (int kc = 0; kc < 8; ++kc) {
        const float* qp = &qn[(size_t)qrow * 256 + (kc << 5) + (kg << 3)];
        const float4 f0 = *(const float4*)qp;
        const float4 f1 = *(const float4*)(qp + 4);
        union { unsigned int u[4]; bf16x8 h; } cv;
        cv.u[0] = pack_bf16(f0.x, f0.y);
        cv.u[1] = pack_bf16(f0.z, f0.w);
        cv.u[2] = pack_bf16(f1.x, f1.y);
        cv.u[3] = pack_bf16(f1.z, f1.w);
        bq[kc] = cv.h;
    }

    DECL8(t)

    for (int stg = 0; stg < KPB / 64; ++stg) {
        __syncthreads();
#pragma unroll
        for (int i = 0; i < 8; ++i) {
            const int g = (i << 11) + (t << 3);
            const int row = g >> 8, col = g & 255;
            const int krow = key_base + (stg << 6) + row;
            const float sc = rnk[krow];
            const float* kp = &keys[(size_t)krow * 256 + col];
            float4 f0 = *(const float4*)kp;
            float4 f1 = *(const float4*)(kp + 4);
            f0.x *= sc; f0.y *= sc; f0.z *= sc; f0.w *= sc;
            f1.x *= sc; f1.y *= sc; f1.z *= sc; f1.w *= sc;
            union { unsigned int u[4]; u16x8 h; } cv;
            cv.u[0] = pack_bf16(f0.x, f0.y);
            cv.u[1] = pack_bf16(f0.z, f0.w);
            cv.u[2] = pack_bf16(f1.x, f1.y);
            cv.u[3] = pack_bf16(f1.z, f1.w);
            *(u16x8*)&k_lds[row * 264 + col] = cv.h;
        }
        __syncthreads();

#pragma unroll
        for (int kt = 0; kt < 4; ++kt) {
            f32x4 a0 = {0.f, 0.f, 0.f, 0.f};
            f32x4 a1 = {0.f, 0.f, 0.f, 0.f};
#pragma unroll
            for (int kc = 0; kc < 4; ++kc) {
                const bf16x8 af = *(const bf16x8*)&k_lds[((kt << 4) + (lane & 15)) * 264 +
                                                         (kc << 5) + (kg << 3)];
                a0 = __builtin_amdgcn_mfma_f32_16x16x32_bf16(af, bq[kc], a0, 0, 0, 0);
            }
#pragma unroll
            for (int kc = 4; kc < 8; ++kc) {
                const bf16x8 af = *(const bf16x8*)&k_lds[((kt << 4) + (lane & 15)) * 264 +
                                                         (kc << 5) + (kg << 3)];
                a1 = __builtin_amdgcn_mfma_f32_16x16x32_bf16(af, bq[kc], a1, 0, 0, 0);
            }
            const int kidx = key_base + (stg << 6) + (kt << 4) + (kg << 2);
            INS8G(t, a0[0] + a1[0], kidx + 0);
            INS8G(t, a0[1] + a1[1], kidx + 1);
            INS8G(t, a0[2] + a1[2], kidx + 2);
            INS8G(t, a0[3] + a1[3], kidx + 3);
        }
    }

    __syncthreads();
    cand_v[t * 8 + 0] = tv0; cand_i[t * 8 + 0] = ti0;
    cand_v[t * 8 + 1] = tv1; cand_i[t * 8 + 1] = ti1;
    cand_v[t * 8 + 2] = tv2; cand_i[t * 8 + 2] = ti2;
    cand_v[t * 8 + 3] = tv3; cand_i[t * 8 + 3] = ti3;
    cand_v[t * 8 + 4] = tv4; cand_i[t * 8 + 4] = ti4;
    cand_v[t * 8 + 5] = tv5; cand_i[t * 8 + 5] = ti5;
    cand_v[t * 8 + 6] = tv6; cand_i[t * 8 + 6] = ti6;
    cand_v[t * 8 + 7] = tv7; cand_i[t * 8 + 7] = ti7;
    __syncthreads();
    if (t < 64) {
        DECL8(m)
        const int w = t >> 4, c = t & 15;
        for (int g = 0; g < 4; ++g) {
            const int src = ((w << 6) + c + (g << 4)) * 8;
            for (int r = 0; r < 8; ++r)
                INS8G(m, cand_v[src + r], cand_i[src + r]);
        }
        const size_t base = (size_t)(q0 + t) * (KSPLITS * 8) + ks * 8;
        part_v8[base + 0] = mv0; part_i8[base + 0] = mi0;
        part_v8[base + 1] = mv1; part_i8[base + 1] = mi1;
        part_v8[base + 2] = mv2; part_i8[base + 2] = mi2;
        part_v8[base + 3] = mv3; part_i8[base + 3] = mi3;
        part_v8[base + 4] = mv4; part_i8[base + 4] = mi4;
        part_v8[base + 5] = mv5; part_i8[base + 5] = mi5;
        part_v8[base + 6] = mv6; part_i8[base + 6] = mi6;
        part_v8[base + 7] = mv7; part_i8[base + 7] = mi7;
    }
}

// ---------------------------------------------------------------------------
// cand_merge: two-stage. Grid 32 blocks x 256 threads; 32 queries/block,
// 8 threads/query (each scans 4 splits' sorted top-8s = 32 entries), then
// one thread per query merges the 8 partial top-8s from LDS.
// ---------------------------------------------------------------------------
__global__ __launch_bounds__(256) void cand_merge(
    const float* __restrict__ part_v8, const int* __restrict__ part_i8,
    int* __restrict__ cand8_i)
{
    __shared__ float pv[256 * 8];
    __shared__ int   pi[256 * 8];
    const int t = threadIdx.x;
    const int qq = t >> 3, sl = t & 7;             // query-in-block, slice
    const int q = (blockIdx.x << 5) + qq;
    {
        DECL8(p)
        const size_t base = (size_t)q * (KSPLITS * 8) + sl * 32;
        for (int j = 0; j < 32; ++j)
            INS8G(p, part_v8[base + j], part_i8[base + j]);
        pv[t * 8 + 0] = pv0; pi[t * 8 + 0] = pi0;
        pv[t * 8 + 1] = pv1; pi[t * 8 + 1] = pi1;
        pv[t * 8 + 2] = pv2; pi[t * 8 + 2] = pi2;
        pv[t * 8 + 3] = pv3; pi[t * 8 + 3] = pi3;
        pv[t * 8 + 4] = pv4; pi[t * 8 + 4] = pi4;
        pv[t * 8 + 5] = pv5; pi[t * 8 + 5] = pi5;
        pv[t * 8 + 6] = pv6; pi[t * 8 + 6] = pi6;
        pv[t * 8 + 7] = pv7; pi[t * 8 + 7] = pi7;
    }
    __syncthreads();
    if (sl == 0) {
        DECL8(c)
        const int b0 = (qq << 3) * 8;
        for (int j = 0; j < 64; ++j)
            INS8G(c, pv[b0 + j], pi[b0 + j]);
        cand8_i[q * 8 + 0] = ci0; cand8_i[q * 8 + 1] = ci1;
        cand8_i[q * 8 + 2] = ci2; cand8_i[q * 8 + 3] = ci3;
        cand8_i[q * 8 + 4] = ci4; cand8_i[q * 8 + 5] = ci5;
        cand8_i[q * 8 + 6] = ci6; cand8_i[q * 8 + 7] = ci7;
    }
}

// ---------------------------------------------------------------------------
// Fused: fp32 rescore of the 8 candidates -> exact top-3 (reference
// tie-break) -> gather values -> attention softmax -> weighted sum.
// ---------------------------------------------------------------------------
__global__ void rescore_gather(const float* __restrict__ qn, const float* __restrict__ keys,
                               const float* __restrict__ rnk, const int* __restrict__ cand8_i,
                               const float* __restrict__ values, const float* __restrict__ Wa,
                               const float* __restrict__ ba, float* __restrict__ mem_raw)
{
    const int q = blockIdx.x;
    const int lane = threadIdx.x;
    const float4 qv = *(const float4*)&qn[(size_t)q * 256 + (lane << 2)];
    float s0, s1, s2, s3, s4, s5, s6, s7;
    int j0, j1, j2, j3, j4, j5, j6, j7;
#define RES(R, S, J) { J = cand8_i[q * 8 + R]; \
    const float4 kv = *(const float4*)&keys[(size_t)J * 256 + (lane << 2)]; \
    float d = qv.x * kv.x + qv.y * kv.y + qv.z * kv.z + qv.w * kv.w; \
    d += __shfl_xor(d, 1); d += __shfl_xor(d, 2); d += __shfl_xor(d, 4); \
    d += __shfl_xor(d, 8); d += __shfl_xor(d, 16); d += __shfl_xor(d, 32); \
    S = d * rnk[J]; }
    RES(0, s0, j0) RES(1, s1, j1) RES(2, s2, j2) RES(3, s3, j3)
    RES(4, s4, j4) RES(5, s5, j5) RES(6, s6, j6) RES(7, s7, j7)
#undef RES
    int top[3];
#define BET(SV, JV) if (SV > bv || (SV == bv && JV < bi)) { bv = SV; bi = JV; }
#pragma unroll
    for (int k = 0; k < 3; ++k) {
        float bv = s0; int bi = j0;
        BET(s1, j1) BET(s2, j2) BET(s3, j3) BET(s4, j4)
        BET(s5, j5) BET(s6, j6) BET(s7, j7)
        top[k] = bi;
        if (j0 == bi) s0 = -3e38f;
        if (j1 == bi) s1 = -3e38f;
        if (j2 == bi) s2 = -3e38f;
        if (j3 == bi) s3 = -3e38f;
        if (j4 == bi) s4 = -3e38f;
        if (j5 == bi) s5 = -3e38f;
        if (j6 == bi) s6 = -3e38f;
        if (j7 == bi) s7 = -3e38f;
    }
#undef BET
    const float4 wa = *(const float4*)&Wa[lane << 2];
    float4 vr[3];
    float lg[3];
#pragma unroll
    for (int r = 0; r < 3; ++r) {
        const float4 v = *(const float4*)&values[(size_t)top[r] * 256 + (lane << 2)];
        vr[r] = v;
        float d = v.x * wa.x + v.y * wa.y + v.z * wa.z + v.w * wa.w;
#pragma unroll
        for (int o = 1; o < 64; o <<= 1) d += __shfl_xor(d, o);
        lg[r] = d + ba[0];
    }
    const float mx = fmaxf(lg[0], fmaxf(lg[1], lg[2]));
    float e0 = __expf(lg[0] - mx), e1 = __expf(lg[1] - mx), e2 = __expf(lg[2] - mx);
    const float inv = 1.f / (e0 + e1 + e2);
    e0 *= inv; e1 *= inv; e2 *= inv;
    float4 m;
    m.x = e0 * vr[0].x + e1 * vr[1].x + e2 * vr[2].x;
    m.y = e0 * vr[0].y + e1 * vr[1].y + e2 * vr[2].y;
    m.z = e0 * vr[0].z + e1 * vr[1].z + e2 * vr[2].z;
    m.w = e0 * vr[0].w + e1 * vr[1].w + e2 * vr[2].w;
    *(float4*)&mem_raw[(size_t)q * 256 + (lane << 2)] = m;
}

// ---------------------------------------------------------------------------
extern "C" void kernel_launch(void* const* d_in, const int* in_sizes, int n_in,
                              void* d_out, int out_size, void* d_ws, size_t ws_size,
                              hipStream_t stream)
{
    (void)in_sizes; (void)n_in; (void)out_size;
    const float* x     = (const float*)d_in[0];
    const float* keys  = (const float*)d_in[1];
    const float* values= (const float*)d_in[2];
    const float* imp   = (const float*)d_in[3];
    const float* W_ih  = (const float*)d_in[4];
    const float* W_hh  = (const float*)d_in[5];
    const float* b_ih  = (const float*)d_in[6];
    const float* b_hh  = (const float*)d_in[7];
    const float* Wq    = (const float*)d_in[8];
    const float* bq    = (const float*)d_in[9];
    const float* Wa    = (const float*)d_in[10];
    const float* ba    = (const float*)d_in[11];
    const float* Wc    = (const float*)d_in[12];
    const float* bc    = (const float*)d_in[13];
    const float* Wo    = (const float*)d_in[14];
    const float* bo    = (const float*)d_in[15];
    float* out = (float*)d_out;

    float* ws = (float*)d_ws;
    size_t o = 0;
    float* xp      = ws + o; o += (size_t)1024 * 4096;           // 16 MB
    float* h_all   = ws + o; o += (size_t)1024 * 1024;           // 4 MB
    unsigned* rec  = (unsigned*)(ws + o); o += 2 * 4096;         // tagged records
    float* rnk     = ws + o; o += NKEY;                          // imp/||key||
    float* qbuf    = ws + o; o += (size_t)ROWS * 256;
    float* qn      = ws + o; o += (size_t)ROWS * 256;
    float* part_v8 = ws + o; o += (size_t)ROWS * KSPLITS * 8;    // 1 MB
    int*   part_i8 = (int*)(ws + o); o += (size_t)ROWS * KSPLITS * 8;
    int*   cand8_i = (int*)(ws + o); o += ROWS * 8;
    float* mem_raw = ws + o; o += (size_t)ROWS * 256;
    float* memb    = ws + o; o += (size_t)ROWS * 256;
    unsigned short* kb = (unsigned short*)(ws + o);              // bf16 keys, 32 MB
    const size_t need_bf16 = (o + (size_t)NKEY * 256 / 2) * sizeof(float);
    const bool use_bf16 = ws_size >= need_bf16;                  // deterministic

    // zero records: slot-0 tag byte = 0 (= step-0 tag) with h = +0.0
    hipMemsetAsync(rec, 0, 2 * 4096 * 4, stream);

    // x_proj = x @ W_ih^T + b_ih + b_hh : [1024, 4096]
    sgemm_nt_w<<<dim3(32, 16), 256, 0, stream>>>(x, W_ih, xp, b_ih, b_hh);

    // LSTM recurrence (blocks 0-255) + key-prep riders (blocks 256-511)
    lstm_kernel<<<2 * NWG_LSTM, NTH_LSTM, 0, stream>>>(
        xp, W_hh, rec, h_all, keys, imp, rnk, use_bf16 ? kb : nullptr);

    // q = h @ Wq^T + bq : [1024, 256]
    sgemm_nt<<<dim3(4, 16), 256, 0, stream>>>(h_all, HD, Wq, HD, qbuf, MD, HD, bq, nullptr, 0);

    rownorm<<<ROWS / 4, 256, 0, stream>>>(qbuf, qn, ROWS);

    // bf16 MFMA candidate scoring + fp32 rescore -> exact top-3 + gather
    if (use_bf16)
        sim_mfma_b8<<<dim3(KSPLITS, 8), 512, 0, stream>>>(qn, kb, part_v8, part_i8);
    else
        sim_mfma_f<<<dim3(KSPLITS, 16), 256, 0, stream>>>(qn, keys, rnk, part_v8, part_i8);
    cand_merge<<<32, 256, 0, stream>>>(part_v8, part_i8, cand8_i);
    rescore_gather<<<ROWS, 64, 0, stream>>>(qn, keys, rnk, cand8_i, values, Wa, ba, mem_raw);

    // mem = mem_raw @ Wc^T + bc
    sgemm_nt<<<dim3(4, 16), 256, 0, stream>>>(mem_raw, MD, Wc, MD, memb, MD, MD, bc, nullptr, 0);

    // out = [h, mem] @ Wo^T + bo  (split K)
    sgemm_nt<<<dim3(8, 16), 256, 0, stream>>>(h_all, HD, Wo, HD + MD, out, OD, HD, bo, nullptr, 0);
    sgemm_nt<<<dim3(8, 16), 256, 0, stream>>>(memb, MD, Wo + HD, HD + MD, out, OD, MD, nullptr, nullptr, 1);
}

// Round 19
// 1187.697 us; speedup vs baseline: 1.1765x; 1.0624x over previous
//
#include <hip/hip_runtime.h>
#include <hip/hip_bf16.h>
#include <cstdint>
#include <cstddef>

// Problem constants
#define BB 4
#define SS 256
#define ID 512
#define HD 1024
#define MD 256
#define NKEY 65536
#define OD 512
#define ROWS 1024          // B*S
#define NWG_LSTM 256
#define NTH_LSTM 256
#define KPB 2048           // keys per sim block
#define KSPLITS (NKEY / KPB)   // 32

typedef __attribute__((ext_vector_type(8))) short bf16x8;
typedef __attribute__((ext_vector_type(4))) float f32x4;
typedef __attribute__((ext_vector_type(8))) unsigned short u16x8;

// ---------------------------------------------------------------------------
// Generic SGEMM: C[M,N] = A[M,K] * Bm[N,K]^T (+bias) or C += ...
// 64x64 tile, 256 threads, 4x4 micro-tile. Grid: (N/64, M/64).
// (kept for the selection-critical fp32 Wq GEMM)
// ---------------------------------------------------------------------------
__global__ __launch_bounds__(256) void sgemm_nt(
    const float* __restrict__ A, int lda,
    const float* __restrict__ Bm, int ldb,
    float* __restrict__ C, int ldc, int K,
    const float* __restrict__ bias, const float* __restrict__ bias2,
    int accum)
{
    __shared__ float As[64][17];
    __shared__ float Bs[64][17];
    const int t = threadIdx.x;
    const int tx = t & 15, ty = t >> 4;
    const int bm = blockIdx.y << 6, bn = blockIdx.x << 6;
    const int lrow = t >> 2, lk4 = (t & 3) << 2;
    float acc[4][4] = {};

    for (int kb = 0; kb < K; kb += 16) {
        const float4 av = *(const float4*)&A[(size_t)(bm + lrow) * lda + kb + lk4];
        const float4 bv = *(const float4*)&Bm[(size_t)(bn + lrow) * ldb + kb + lk4];
        __syncthreads();
        As[lrow][lk4 + 0] = av.x; As[lrow][lk4 + 1] = av.y;
        As[lrow][lk4 + 2] = av.z; As[lrow][lk4 + 3] = av.w;
        Bs[lrow][lk4 + 0] = bv.x; Bs[lrow][lk4 + 1] = bv.y;
        Bs[lrow][lk4 + 2] = bv.z; Bs[lrow][lk4 + 3] = bv.w;
        __syncthreads();
#pragma unroll
        for (int k = 0; k < 16; ++k) {
            const float a0 = As[4 * ty + 0][k], a1 = As[4 * ty + 1][k];
            const float a2 = As[4 * ty + 2][k], a3 = As[4 * ty + 3][k];
            const float b0 = Bs[4 * tx + 0][k], b1 = Bs[4 * tx + 1][k];
            const float b2 = Bs[4 * tx + 2][k], b3 = Bs[4 * tx + 3][k];
            acc[0][0] += a0 * b0; acc[0][1] += a0 * b1; acc[0][2] += a0 * b2; acc[0][3] += a0 * b3;
            acc[1][0] += a1 * b0; acc[1][1] += a1 * b1; acc[1][2] += a1 * b2; acc[1][3] += a1 * b3;
            acc[2][0] += a2 * b0; acc[2][1] += a2 * b1; acc[2][2] += a2 * b2; acc[2][3] += a2 * b3;
            acc[3][0] += a3 * b0; acc[3][1] += a3 * b1; acc[3][2] += a3 * b2; acc[3][3] += a3 * b3;
        }
    }

#pragma unroll
    for (int i = 0; i < 4; ++i) {
        const int row = bm + 4 * ty + i;
        const int col = bn + 4 * tx;
        float4* cp = (float4*)&C[(size_t)row * ldc + col];
        float4 r;
        if (accum) {
            const float4 old = *cp;
            r.x = old.x + acc[i][0]; r.y = old.y + acc[i][1];
            r.z = old.z + acc[i][2]; r.w = old.w + acc[i][3];
        } else {
            float bx = bias[col + 0], by = bias[col + 1], bz = bias[col + 2], bw = bias[col + 3];
            if (bias2) { bx += bias2[col + 0]; by += bias2[col + 1]; bz += bias2[col + 2]; bw += bias2[col + 3]; }
            r.x = acc[i][0] + bx; r.y = acc[i][1] + by;
            r.z = acc[i][2] + bz; r.w = acc[i][3] + bw;
        }
        *cp = r;
    }
}

// ---------------------------------------------------------------------------
// x_proj GEMM: C[1024,4096] = A[1024,512] @ Bm[4096,512]^T + bias1 + bias2.
// 64(M) x 128(N) tile, 256 threads, micro 4x8, k-major LDS. Grid (32, 16).
// ---------------------------------------------------------------------------
__global__ __launch_bounds__(256) void sgemm_nt_w(
    const float* __restrict__ A, const float* __restrict__ Bm,
    float* __restrict__ C, const float* __restrict__ bias, const float* __restrict__ bias2)
{
    __shared__ float As[16][64];
    __shared__ float Bs[16][128];
    const int t = threadIdx.x;
    const int tx = t & 15, ty = t >> 4;
    const int bm = blockIdx.y << 6, bn = blockIdx.x << 7;
    const int arow = t & 63, akq = t >> 6;       // A: 1 float4 per thread
    const int brow = t & 127, bkq = t >> 7;      // B: 2 float4 per thread
    float acc[4][8] = {};

    for (int kb = 0; kb < 512; kb += 16) {
        const float4 av  = *(const float4*)&A[(size_t)(bm + arow) * 512 + kb + (akq << 2)];
        const float4 bv0 = *(const float4*)&Bm[(size_t)(bn + brow) * 512 + kb + (bkq << 3)];
        const float4 bv1 = *(const float4*)&Bm[(size_t)(bn + brow) * 512 + kb + (bkq << 3) + 4];
        __syncthreads();
        As[(akq << 2) + 0][arow] = av.x; As[(akq << 2) + 1][arow] = av.y;
        As[(akq << 2) + 2][arow] = av.z; As[(akq << 2) + 3][arow] = av.w;
        Bs[(bkq << 3) + 0][brow] = bv0.x; Bs[(bkq << 3) + 1][brow] = bv0.y;
        Bs[(bkq << 3) + 2][brow] = bv0.z; Bs[(bkq << 3) + 3][brow] = bv0.w;
        Bs[(bkq << 3) + 4][brow] = bv1.x; Bs[(bkq << 3) + 5][brow] = bv1.y;
        Bs[(bkq << 3) + 6][brow] = bv1.z; Bs[(bkq << 3) + 7][brow] = bv1.w;
        __syncthreads();
#pragma unroll
        for (int k = 0; k < 16; ++k) {
            const float4 a  = *(const float4*)&As[k][ty << 2];
            const float4 b0 = *(const float4*)&Bs[k][tx << 3];
            const float4 b1 = *(const float4*)&Bs[k][(tx << 3) + 4];
            acc[0][0] += a.x * b0.x; acc[0][1] += a.x * b0.y; acc[0][2] += a.x * b0.z; acc[0][3] += a.x * b0.w;
            acc[0][4] += a.x * b1.x; acc[0][5] += a.x * b1.y; acc[0][6] += a.x * b1.z; acc[0][7] += a.x * b1.w;
            acc[1][0] += a.y * b0.x; acc[1][1] += a.y * b0.y; acc[1][2] += a.y * b0.z; acc[1][3] += a.y * b0.w;
            acc[1][4] += a.y * b1.x; acc[1][5] += a.y * b1.y; acc[1][6] += a.y * b1.z; acc[1][7] += a.y * b1.w;
            acc[2][0] += a.z * b0.x; acc[2][1] += a.z * b0.y; acc[2][2] += a.z * b0.z; acc[2][3] += a.z * b0.w;
            acc[2][4] += a.z * b1.x; acc[2][5] += a.z * b1.y; acc[2][6] += a.z * b1.z; acc[2][7] += a.z * b1.w;
            acc[3][0] += a.w * b0.x; acc[3][1] += a.w * b0.y; acc[3][2] += a.w * b0.z; acc[3][3] += a.w * b0.w;
            acc[3][4] += a.w * b1.x; acc[3][5] += a.w * b1.y; acc[3][6] += a.w * b1.z; acc[3][7] += a.w * b1.w;
        }
    }

#pragma unroll
    for (int i = 0; i < 4; ++i) {
        const int row = bm + (ty << 2) + i;
        const int col = bn + (tx << 3);
        float4 r0, r1;
        r0.x = acc[i][0] + bias[col + 0] + bias2[col + 0];
        r0.y = acc[i][1] + bias[col + 1] + bias2[col + 1];
        r0.z = acc[i][2] + bias[col + 2] + bias2[col + 2];
        r0.w = acc[i][3] + bias[col + 3] + bias2[col + 3];
        r1.x = acc[i][4] + bias[col + 4] + bias2[col + 4];
        r1.y = acc[i][5] + bias[col + 5] + bias2[col + 5];
        r1.z = acc[i][6] + bias[col + 6] + bias2[col + 6];
        r1.w = acc[i][7] + bias[col + 7] + bias2[col + 7];
        *(float4*)&C[(size_t)row * 4096 + col] = r0;
        *(float4*)&C[(size_t)row * 4096 + col + 4] = r1;
    }
}

__device__ inline unsigned pack_bf16(float a, float b) {
    return (__float_as_uint(a) >> 16) | (__float_as_uint(b) & 0xFFFF0000u);
}

// ---------------------------------------------------------------------------
// Row L2-normalization (256-col rows), for qn.
// ---------------------------------------------------------------------------
__global__ void rownorm(const float* __restrict__ X, float* __restrict__ Xn, int nrows)
{
    const int row = blockIdx.x * 4 + (threadIdx.x >> 6);
    const int lane = threadIdx.x & 63;
    if (row >= nrows) return;
    float4 v = *(const float4*)&X[(size_t)row * 256 + (lane << 2)];
    float ss = v.x * v.x + v.y * v.y + v.z * v.z + v.w * v.w;
#pragma unroll
    for (int o = 1; o < 64; o <<= 1) ss += __shfl_xor(ss, o);
    const float sc = 1.f / fmaxf(sqrtf(ss), 1e-12f);
    v.x *= sc; v.y *= sc; v.z *= sc; v.w *= sc;
    *(float4*)&Xn[(size_t)row * 256 + (lane << 2)] = v;
}

// ---------------------------------------------------------------------------
// Persistent LSTM (blocks 0..255, proven round-10 depth-1 pipeline) +
// key-prep rider blocks (256..511).
// ---------------------------------------------------------------------------
__device__ inline float sigm_f(float x) { return 1.f / (1.f + __expf(-x)); }
__device__ inline float tanh_f(float x) { return 1.f - 2.f / (__expf(2.f * x) + 1.f); }

#define SUBSTEP(B, U, UN, C4, XPC) do {                                           \
    asm volatile("s_waitcnt vmcnt(3)" ::: "memory");                              \
    __builtin_amdgcn_sched_barrier(0);                                            \
    const unsigned* pb_ = rec + (slot << 12) + (B << 10) + (t << 2);              \
    while ((((U.x ^ st) | (U.y ^ st) | (U.z ^ st) | (U.w ^ st)) & 0xFFu) != 0u) { \
        __builtin_amdgcn_s_sleep(1);                                              \
        asm volatile("global_load_dwordx4 %0, %1, off sc0 sc1\n\ts_waitcnt vmcnt(0)" \
                     : "=&v"(U) : "v"(pb_) : "memory");                           \
    }                                                                             \
    {                                                                             \
        float4 hw_;                                                               \
        hw_.x = __uint_as_float(U.x & 0xFFFFFF00u);                               \
        hw_.y = __uint_as_float(U.y & 0xFFFFFF00u);                               \
        hw_.z = __uint_as_float(U.z & 0xFFFFFF00u);                               \
        hw_.w = __uint_as_float(U.w & 0xFFFFFF00u);                               \
        *(float4*)&h_lds[B][t << 2] = hw_;                                        \
    }                                                                             \
    asm volatile("s_waitcnt lgkmcnt(0)" ::: "memory");                            \
    __builtin_amdgcn_sched_barrier(0);                                            \
    __builtin_amdgcn_s_barrier();                                                 \
    {                                                                             \
        const unsigned* pn_ = rec + (((B == 3) ? (slot ^ 1) : slot) << 12)        \
                              + (((B + 1) & 3) << 10) + (t << 2);                 \
        asm volatile("global_load_dwordx4 %0, %1, off sc0 sc1"                    \
                     : "=&v"(UN) : "v"(pn_) : "memory");                          \
    }                                                                             \
    const float* hb_ = &h_lds[B][0];                                              \
    float ax_ = 0.f, ay_ = 0.f, az_ = 0.f, aw_ = 0.f;                             \
    _Pragma("unroll")                                                             \
    for (int j = 0; j < 16; ++j) {                                                \
        const float4 hv_ = *(const float4*)&hb_[(ksub << 2) + (j << 6)];          \
        ax_ += w4[j].x * hv_.x; ay_ += w4[j].y * hv_.y;                           \
        az_ += w4[j].z * hv_.z; aw_ += w4[j].w * hv_.w;                           \
    }                                                                             \
    float sm_ = (ax_ + ay_) + (az_ + aw_);                                        \
    sm_ += __shfl_xor(sm_, 1); sm_ += __shfl_xor(sm_, 2);                         \
    sm_ += __shfl_xor(sm_, 4); sm_ += __shfl_xor(sm_, 8);                         \
    sm_ += XPC;                                                                   \
    const float vi_ = __shfl(sm_, ksub);                                          \
    const float vf_ = __shfl(sm_, ksub + 16);                                     \
    const float vg_ = __shfl(sm_, ksub + 32);                                     \
    const float vo_ = __shfl(sm_, ksub + 48);                                     \
    const float iv_ = sigm_f(vi_), fv_ = sigm_f(vf_);                             \
    const float gv_ = tanh_f(vg_), ov_ = sigm_f(vo_);                             \
    C4 = fv_ * C4 + iv_ * gv_;                                                    \
    const float hvv_ = ov_ * tanh_f(C4);                                          \
    if (lane == 0) {                                                              \
        unsigned* dst_ = rec + ((slot ^ 1) << 12) + (B << 10) + unit;             \
        const unsigned uv_ = (__float_as_uint(hvv_) & 0xFFFFFF00u) |              \
                             ((unsigned)(s + 1) & 0xFFu);                         \
        float* ha_ = &h_all[(size_t)((B << 8) + s) * 1024 + unit];                \
        asm volatile("global_store_dword %0, %1, off sc0 sc1"                     \
                     :: "v"(dst_), "v"(uv_) : "memory");                          \
        asm volatile("global_store_dword %0, %1, off"                             \
                     :: "v"(ha_), "v"(hvv_) : "memory");                          \
    }                                                                             \
    {                                                                             \
        const float* px_ = &xp[(size_t)((B << 8) + sn) * 4096 + wrow];            \
        asm volatile("global_load_dword %0, %1, off"                              \
                     : "=&v"(XPC) : "v"(px_) : "memory");                         \
    }                                                                             \
} while (0)

__global__ __launch_bounds__(256) void lstm_kernel(
    const float* __restrict__ xp, const float* __restrict__ W_hh,
    unsigned* __restrict__ rec, float* __restrict__ h_all,
    const float* __restrict__ keys, const float* __restrict__ imp,
    float* __restrict__ rnk, unsigned short* __restrict__ kb)
{
    __shared__ float h_lds[4][1024];
    const int t = threadIdx.x;

    if (blockIdx.x >= NWG_LSTM) {
        // ---- key-prep rider: 256 rows per block ----
        const int base_row = (blockIdx.x - NWG_LSTM) << 8;
        const int lane = t & 63;
        for (int it = 0; it < 64; ++it) {
            const int row = base_row + (it << 2) + (t >> 6);
            float4 v = *(const float4*)&keys[(size_t)row * 256 + (lane << 2)];
            float ss = v.x * v.x + v.y * v.y + v.z * v.z + v.w * v.w;
#pragma unroll
            for (int o = 1; o < 64; o <<= 1) ss += __shfl_xor(ss, o);
            const float sc = imp[row] / fmaxf(sqrtf(ss), 1e-12f);
            if (lane == 0) rnk[row] = sc;
            if (kb) {
                uint2 p;
                p.x = pack_bf16(v.x * sc, v.y * sc);
                p.y = pack_bf16(v.z * sc, v.w * sc);
                *(uint2*)&kb[(size_t)row * 256 + (lane << 2)] = p;
            }
        }
        return;
    }

    const int wave = t >> 6, lane = t & 63;
    const int gt = lane >> 4, ksub = lane & 15;   // gate 0..3 (i,f,g,o), k-sub 0..15
    const int unit = (blockIdx.x << 2) + wave;
    const int wrow = (gt << 10) + unit;           // W_hh row

    float4 w4[16];
#pragma unroll
    for (int j = 0; j < 16; ++j)
        w4[j] = *(const float4*)&W_hh[(size_t)wrow * 1024 + (ksub << 2) + (j << 6)];

    float c40 = 0.f, c41 = 0.f, c42 = 0.f, c43 = 0.f;   // cell state (per-lane)
    float xpc0 = xp[(size_t)(0 * 256 + 0) * 4096 + wrow];
    float xpc1 = xp[(size_t)(1 * 256 + 0) * 4096 + wrow];
    float xpc2 = xp[(size_t)(2 * 256 + 0) * 4096 + wrow];
    float xpc3 = xp[(size_t)(3 * 256 + 0) * 4096 + wrow];

    uint4 u0 = make_uint4(~0u, ~0u, ~0u, ~0u);    // tag 0xFF -> retry path on
    uint4 u1 = u0, u2 = u0, u3 = u0;              // first use (never a step tag)

    // prologue: issue poll for (s=0,b=0) and drain so the pipeline count is exact
    {
        const unsigned* p00 = rec + (t << 2);
        asm volatile("global_load_dwordx4 %0, %1, off sc0 sc1\n\ts_waitcnt vmcnt(0)"
                     : "=&v"(u0) : "v"(p00) : "memory");
        __builtin_amdgcn_sched_barrier(0);
    }

    for (int s = 0; s < 256; ++s) {
        const int slot = s & 1;
        const unsigned st = (unsigned)s & 0xFFu;
        const int sn = (s < 255) ? s + 1 : 255;   // clamped next-step xp row
        SUBSTEP(0, u0, u1, c40, xpc0);
        SUBSTEP(1, u1, u2, c41, xpc1);
        SUBSTEP(2, u2, u3, c42, xpc2);
        SUBSTEP(3, u3, u0, c43, xpc3);
    }
}

// ---------------------------------------------------------------------------
// Static-register top-8 insertion (sorted v0>=...>=v7).
// ---------------------------------------------------------------------------
#define SWAP1(A, B, IA, IB) { float _t = A; A = B; B = _t; int _u = IA; IA = IB; IB = _u; }
#define INS8G(P, V, ID) do {                                          \
    const float _v = (V); const int _id = (ID);                       \
    if (_v > P##v7) {                                                 \
        P##v7 = _v; P##i7 = _id;                                      \
        if (P##v7 > P##v6) SWAP1(P##v6, P##v7, P##i6, P##i7);         \
        if (P##v6 > P##v5) SWAP1(P##v5, P##v6, P##i5, P##i6);         \
        if (P##v5 > P##v4) SWAP1(P##v4, P##v5, P##i4, P##i5);         \
        if (P##v4 > P##v3) SWAP1(P##v3, P##v4, P##i3, P##i4);         \
        if (P##v3 > P##v2) SWAP1(P##v2, P##v3, P##i2, P##i3);         \
        if (P##v2 > P##v1) SWAP1(P##v1, P##v2, P##i1, P##i2);         \
        if (P##v1 > P##v0) SWAP1(P##v0, P##v1, P##i0, P##i1);         \
    }                                                                 \
} while (0)
#define DECL8(P) float P##v0=-3e38f,P##v1=-3e38f,P##v2=-3e38f,P##v3=-3e38f, \
                       P##v4=-3e38f,P##v5=-3e38f,P##v6=-3e38f,P##v7=-3e38f; \
                 int P##i0=0x7fffffff,P##i1=0x7fffffff,P##i2=0x7fffffff,P##i3=0x7fffffff, \
                     P##i4=0x7fffffff,P##i5=0x7fffffff,P##i6=0x7fffffff,P##i7=0x7fffffff;

// ---------------------------------------------------------------------------
// sim_mfma_b8: bf16 MFMA candidate scoring from pre-converted bf16 keys,
// 8 waves per block sharing one staged key tile (proven r18 config).
// ---------------------------------------------------------------------------
__global__ __launch_bounds__(512) void sim_mfma_b8(
    const float* __restrict__ qn, const unsigned short* __restrict__ kb,
    float* __restrict__ part_v8, int* __restrict__ part_i8)
{
    __shared__ unsigned short k_lds[64 * 264];    // 33 KB; merge aliases onto it
    const int t = threadIdx.x;
    const int wave = t >> 6, lane = t & 63;
    const int ks = blockIdx.x, qs = blockIdx.y;
    const int key_base = ks * KPB;
    const int q0 = qs << 7;                       // 128 queries per block
    const int qrow = q0 + (wave << 4) + (lane & 15);
    const int kg = lane >> 4;                     // k-group 0..3

    bf16x8 bq[8];
#pragma unroll
    for (int kc = 0; kc < 8; ++kc) {
        const float* qp = &qn[(size_t)qrow * 256 + (kc << 5) + (kg << 3)];
        const float4 f0 = *(const float4*)qp;
        const float4 f1 = *(const float4*)(qp + 4);
        union { unsigned int u[4]; bf16x8 h; } cv;
        cv.u[0] = pack_bf16(f0.x, f0.y);
        cv.u[1] = pack_bf16(f0.z, f0.w);
        cv.u[2] = pack_bf16(f1.x, f1.y);
        cv.u[3] = pack_bf16(f1.z, f1.w);
        bq[kc] = cv.h;
    }

    DECL8(t)

    const int srow = t >> 3, scol0 = (t & 7) << 5;   // staging: row, 32-col slice

    for (int stg = 0; stg < KPB / 64; ++stg) {
        __syncthreads();
        {
            const unsigned short* kp = &kb[(size_t)(key_base + (stg << 6) + srow) * 256 + scol0];
#pragma unroll
            for (int i = 0; i < 4; ++i)
                *(u16x8*)&k_lds[srow * 264 + scol0 + (i << 3)] = *(const u16x8*)(kp + (i << 3));
        }
        __syncthreads();

#pragma unroll
        for (int kt = 0; kt < 4; ++kt) {
            f32x4 a0 = {0.f, 0.f, 0.f, 0.f};
            f32x4 a1 = {0.f, 0.f, 0.f, 0.f};
#pragma unroll
            for (int kc = 0; kc < 4; ++kc) {
                const bf16x8 af = *(const bf16x8*)&k_lds[((kt << 4) + (lane & 15)) * 264 +
                                                         (kc << 5) + (kg << 3)];
                a0 = __builtin_amdgcn_mfma_f32_16x16x32_bf16(af, bq[kc], a0, 0, 0, 0);
            }
#pragma unroll
            for (int kc = 4; kc < 8; ++kc) {
                const bf16x8 af = *(const bf16x8*)&k_lds[((kt << 4) + (lane & 15)) * 264 +
                                                         (kc << 5) + (kg << 3)];
                a1 = __builtin_amdgcn_mfma_f32_16x16x32_bf16(af, bq[kc], a1, 0, 0, 0);
            }
            const int kidx = key_base + (stg << 6) + (kt << 4) + (kg << 2);
            INS8G(t, a0[0] + a1[0], kidx + 0);
            INS8G(t, a0[1] + a1[1], kidx + 1);
            INS8G(t, a0[2] + a1[2], kidx + 2);
            INS8G(t, a0[3] + a1[3], kidx + 3);
        }
    }

    // ---- merge phase: alias cand arrays onto k_lds (32 KB <= 33 KB) ----
    float* cand_v = (float*)k_lds;                 // [512][8] floats, 16 KB
    int*   cand_i = (int*)(k_lds + 8192);          // [512][8] ints,   16 KB
    __syncthreads();
    cand_v[t * 8 + 0] = tv0; cand_i[t * 8 + 0] = ti0;
    cand_v[t * 8 + 1] = tv1; cand_i[t * 8 + 1] = ti1;
    cand_v[t * 8 + 2] = tv2; cand_i[t * 8 + 2] = ti2;
    cand_v[t * 8 + 3] = tv3; cand_i[t * 8 + 3] = ti3;
    cand_v[t * 8 + 4] = tv4; cand_i[t * 8 + 4] = ti4;
    cand_v[t * 8 + 5] = tv5; cand_i[t * 8 + 5] = ti5;
    cand_v[t * 8 + 6] = tv6; cand_i[t * 8 + 6] = ti6;
    cand_v[t * 8 + 7] = tv7; cand_i[t * 8 + 7] = ti7;
    __syncthreads();
    if (t < 128) {
        DECL8(m)
        const int w = t >> 4, c = t & 15;          // query q0+t = wave w, col c
        for (int g = 0; g < 4; ++g) {
            const int src = ((w << 6) + (g << 4) + c) * 8;
            for (int r = 0; r < 8; ++r)
                INS8G(m, cand_v[src + r], cand_i[src + r]);
        }
        const size_t base = (size_t)(q0 + t) * (KSPLITS * 8) + ks * 8;
        part_v8[base + 0] = mv0; part_i8[base + 0] = mi0;
        part_v8[base + 1] = mv1; part_i8[base + 1] = mi1;
        part_v8[base + 2] = mv2; part_i8[base + 2] = mi2;
        part_v8[base + 3] = mv3; part_i8[base + 3] = mi3;
        part_v8[base + 4] = mv4; part_i8[base + 4] = mi4;
        part_v8[base + 5] = mv5; part_i8[base + 5] = mi5;
        part_v8[base + 6] = mv6; part_i8[base + 6] = mi6;
        part_v8[base + 7] = mv7; part_i8[base + 7] = mi7;
    }
}

// ---------------------------------------------------------------------------
// sim_mfma_f: fp32-key fallback (r12 config) if ws too small for kb.
// ---------------------------------------------------------------------------
__global__ __launch_bounds__(256) void sim_mfma_f(
    const float* __restrict__ qn, const float* __restrict__ keys,
    const float* __restrict__ rnk, float* __restrict__ part_v8, int* __restrict__ part_i8)
{
    __shared__ unsigned short k_lds[64 * 264];
    __shared__ float cand_v[256 * 8];
    __shared__ int   cand_i[256 * 8];
    const int t = threadIdx.x;
    const int wave = t >> 6, lane = t & 63;
    const int ks = blockIdx.x, qs = blockIdx.y;
    const int key_base = ks * KPB;
    const int q0 = qs << 6;
    const int qrow = q0 + (wave << 4) + (lane & 15);
    const int kg = lane >> 4;

    bf16x8 bq[8];
#pragma unroll
    for (int kc = 0; kc < 8; ++kc) {
        const float* qp = &qn[(size_t)qrow * 256 + (kc << 5) + (kg << 3)];
        const float4 f0 = *(const float4*)qp;
        const float4 f1 = *(const float4*)(qp + 4);
        union { unsigned int u[4]; bf16x8 h; } cv;
        cv.u[0] = pack_bf16(f0.x, f0.y);
        cv.u[1] = pack_bf16(f0.z, f0.w);
        cv.u[2] = pack_bf16(f1.x, f1.y);
        cv.u[3] = pack_bf16(f1.z, f1.w);
        bq[kc] = cv.h;
    }

    DECL8(t)

    for (int stg = 0; stg < KPB / 64; ++stg) {
        __syncthreads();
#pragma unroll
        for (int i = 0; i < 8; ++i) {
            const int g = (i << 11) + (t << 3);
            const int row = g >> 8, col = g & 255;
            const int krow = key_base + (stg << 6) + row;
            const float sc = rnk[krow];
            const float* kp = &keys[(size_t)krow * 256 + col];
            float4 f0 = *(const float4*)kp;
            float4 f1 = *(const float4*)(kp + 4);
            f0.x *= sc; f0.y *= sc; f0.z *= sc; f0.w *= sc;
            f1.x *= sc; f1.y *= sc; f1.z *= sc; f1.w *= sc;
            union { unsigned int u[4]; u16x8 h; } cv;
            cv.u[0] = pack_bf16(f0.x, f0.y);
            cv.u[1] = pack_bf16(f0.z, f0.w);
            cv.u[2] = pack_bf16(f1.x, f1.y);
            cv.u[3] = pack_bf16(f1.z, f1.w);
            *(u16x8*)&k_lds[row * 264 + col] = cv.h;
        }
        __syncthreads();

#pragma unroll
        for (int kt = 0; kt < 4; ++kt) {
            f32x4 a0 = {0.f, 0.f, 0.f, 0.f};
            f32x4 a1 = {0.f, 0.f, 0.f, 0.f};
#pragma unroll
            for (int kc = 0; kc < 4; ++kc) {
                const bf16x8 af = *(const bf16x8*)&k_lds[((kt << 4) + (lane & 15)) * 264 +
                                                         (kc << 5) + (kg << 3)];
                a0 = __builtin_amdgcn_mfma_f32_16x16x32_bf16(af, bq[kc], a0, 0, 0, 0);
            }
#pragma unroll
            for (int kc = 4; kc < 8; ++kc) {
                const bf16x8 af = *(const bf16x8*)&k_lds[((kt << 4) + (lane & 15)) * 264 +
                                                         (kc << 5) + (kg << 3)];
                a1 = __builtin_amdgcn_mfma_f32_16x16x32_bf16(af, bq[kc], a1, 0, 0, 0);
            }
            const int kidx = key_base + (stg << 6) + (kt << 4) + (kg << 2);
            INS8G(t, a0[0] + a1[0], kidx + 0);
            INS8G(t, a0[1] + a1[1], kidx + 1);
            INS8G(t, a0[2] + a1[2], kidx + 2);
            INS8G(t, a0[3] + a1[3], kidx + 3);
        }
    }

    __syncthreads();
    cand_v[t * 8 + 0] = tv0; cand_i[t * 8 + 0] = ti0;
    cand_v[t * 8 + 1] = tv1; cand_i[t * 8 + 1] = ti1;
    cand_v[t * 8 + 2] = tv2; cand_i[t * 8 + 2] = ti2;
    cand_v[t * 8 + 3] = tv3; cand_i[t * 8 + 3] = ti3;
    cand_v[t * 8 + 4] = tv4; cand_i[t * 8 + 4] = ti4;
    cand_v[t * 8 + 5] = tv5; cand_i[t * 8 + 5] = ti5;
    cand_v[t * 8 + 6] = tv6; cand_i[t * 8 + 6] = ti6;
    cand_v[t * 8 + 7] = tv7; cand_i[t * 8 + 7] = ti7;
    __syncthreads();
    if (t < 64) {
        DECL8(m)
        const int w = t >> 4, c = t & 15;
        for (int g = 0; g < 4; ++g) {
            const int src = ((w << 6) + c + (g << 4)) * 8;
            for (int r = 0; r < 8; ++r)
                INS8G(m, cand_v[src + r], cand_i[src + r]);
        }
        const size_t base = (size_t)(q0 + t) * (KSPLITS * 8) + ks * 8;
        part_v8[base + 0] = mv0; part_i8[base + 0] = mi0;
        part_v8[base + 1] = mv1; part_i8[base + 1] = mi1;
        part_v8[base + 2] = mv2; part_i8[base + 2] = mi2;
        part_v8[base + 3] = mv3; part_i8[base + 3] = mi3;
        part_v8[base + 4] = mv4; part_i8[base + 4] = mi4;
        part_v8[base + 5] = mv5; part_i8[base + 5] = mi5;
        part_v8[base + 6] = mv6; part_i8[base + 6] = mi6;
        part_v8[base + 7] = mv7; part_i8[base + 7] = mi7;
    }
}

// ---------------------------------------------------------------------------
// cand_merge: two-stage (proven r18). Grid 32 x 256.
// ---------------------------------------------------------------------------
__global__ __launch_bounds__(256) void cand_merge(
    const float* __restrict__ part_v8, const int* __restrict__ part_i8,
    int* __restrict__ cand8_i)
{
    __shared__ float pv[256 * 8];
    __shared__ int   pi[256 * 8];
    const int t = threadIdx.x;
    const int qq = t >> 3, sl = t & 7;             // query-in-block, slice
    const int q = (blockIdx.x << 5) + qq;
    {
        DECL8(p)
        const size_t base = (size_t)q * (KSPLITS * 8) + sl * 32;
        for (int j = 0; j < 32; ++j)
            INS8G(p, part_v8[base + j], part_i8[base + j]);
        pv[t * 8 + 0] = pv0; pi[t * 8 + 0] = pi0;
        pv[t * 8 + 1] = pv1; pi[t * 8 + 1] = pi1;
        pv[t * 8 + 2] = pv2; pi[t * 8 + 2] = pi2;
        pv[t * 8 + 3] = pv3; pi[t * 8 + 3] = pi3;
        pv[t * 8 + 4] = pv4; pi[t * 8 + 4] = pi4;
        pv[t * 8 + 5] = pv5; pi[t * 8 + 5] = pi5;
        pv[t * 8 + 6] = pv6; pi[t * 8 + 6] = pi6;
        pv[t * 8 + 7] = pv7; pi[t * 8 + 7] = pi7;
    }
    __syncthreads();
    if (sl == 0) {
        DECL8(c)
        const int b0 = (qq << 3) * 8;
        for (int j = 0; j < 64; ++j)
            INS8G(c, pv[b0 + j], pi[b0 + j]);
        cand8_i[q * 8 + 0] = ci0; cand8_i[q * 8 + 1] = ci1;
        cand8_i[q * 8 + 2] = ci2; cand8_i[q * 8 + 3] = ci3;
        cand8_i[q * 8 + 4] = ci4; cand8_i[q * 8 + 5] = ci5;
        cand8_i[q * 8 + 6] = ci6; cand8_i[q * 8 + 7] = ci7;
    }
}

// ---------------------------------------------------------------------------
// Fused: fp32 rescore -> exact top-3 -> gather -> softmax -> weighted sum.
// ---------------------------------------------------------------------------
__global__ void rescore_gather(const float* __restrict__ qn, const float* __restrict__ keys,
                               const float* __restrict__ rnk, const int* __restrict__ cand8_i,
                               const float* __restrict__ values, const float* __restrict__ Wa,
                               const float* __restrict__ ba, float* __restrict__ mem_raw)
{
    const int q = blockIdx.x;
    const int lane = threadIdx.x;
    const float4 qv = *(const float4*)&qn[(size_t)q * 256 + (lane << 2)];
    float s0, s1, s2, s3, s4, s5, s6, s7;
    int j0, j1, j2, j3, j4, j5, j6, j7;
#define RES(R, S, J) { J = cand8_i[q * 8 + R]; \
    const float4 kv = *(const float4*)&keys[(size_t)J * 256 + (lane << 2)]; \
    float d = qv.x * kv.x + qv.y * kv.y + qv.z * kv.z + qv.w * kv.w; \
    d += __shfl_xor(d, 1); d += __shfl_xor(d, 2); d += __shfl_xor(d, 4); \
    d += __shfl_xor(d, 8); d += __shfl_xor(d, 16); d += __shfl_xor(d, 32); \
    S = d * rnk[J]; }
    RES(0, s0, j0) RES(1, s1, j1) RES(2, s2, j2) RES(3, s3, j3)
    RES(4, s4, j4) RES(5, s5, j5) RES(6, s6, j6) RES(7, s7, j7)
#undef RES
    int top[3];
#define BET(SV, JV) if (SV > bv || (SV == bv && JV < bi)) { bv = SV; bi = JV; }
#pragma unroll
    for (int k = 0; k < 3; ++k) {
        float bv = s0; int bi = j0;
        BET(s1, j1) BET(s2, j2) BET(s3, j3) BET(s4, j4)
        BET(s5, j5) BET(s6, j6) BET(s7, j7)
        top[k] = bi;
        if (j0 == bi) s0 = -3e38f;
        if (j1 == bi) s1 = -3e38f;
        if (j2 == bi) s2 = -3e38f;
        if (j3 == bi) s3 = -3e38f;
        if (j4 == bi) s4 = -3e38f;
        if (j5 == bi) s5 = -3e38f;
        if (j6 == bi) s6 = -3e38f;
        if (j7 == bi) s7 = -3e38f;
    }
#undef BET
    const float4 wa = *(const float4*)&Wa[lane << 2];
    float4 vr[3];
    float lg[3];
#pragma unroll
    for (int r = 0; r < 3; ++r) {
        const float4 v = *(const float4*)&values[(size_t)top[r] * 256 + (lane << 2)];
        vr[r] = v;
        float d = v.x * wa.x + v.y * wa.y + v.z * wa.z + v.w * wa.w;
#pragma unroll
        for (int o = 1; o < 64; o <<= 1) d += __shfl_xor(d, o);
        lg[r] = d + ba[0];
    }
    const float mx = fmaxf(lg[0], fmaxf(lg[1], lg[2]));
    float e0 = __expf(lg[0] - mx), e1 = __expf(lg[1] - mx), e2 = __expf(lg[2] - mx);
    const float inv = 1.f / (e0 + e1 + e2);
    e0 *= inv; e1 *= inv; e2 *= inv;
    float4 m;
    m.x = e0 * vr[0].x + e1 * vr[1].x + e2 * vr[2].x;
    m.y = e0 * vr[0].y + e1 * vr[1].y + e2 * vr[2].y;
    m.z = e0 * vr[0].z + e1 * vr[1].z + e2 * vr[2].z;
    m.w = e0 * vr[0].w + e1 * vr[1].w + e2 * vr[2].w;
    *(float4*)&mem_raw[(size_t)q * 256 + (lane << 2)] = m;
}

// ---------------------------------------------------------------------------
// gemm_bf16_nt: C[M,N] = concat(in1[.,K1], in2[.,K2]) @ Wm[N,K1+K2]^T + bias,
// bf16 MFMA. Tile 64m x 64n, 256 threads = 4 waves; wave w owns n-quadrant w.
// Grid (N/64, M/64). MFMA mapping copied from the VERIFIED sim kernel:
// A = Wm rows (n) from LDS, B = input rows (m) from LDS;
// D[lane,reg]: n = bn + w*16 + (lane>>4)*4 + reg, m = bm + mq*16 + (lane&15).
// ---------------------------------------------------------------------------
__global__ __launch_bounds__(256) void gemm_bf16_nt(
    const float* __restrict__ in1, int K1,
    const float* __restrict__ in2, int K2,
    const float* __restrict__ Wm,
    float* __restrict__ C, int N,
    const float* __restrict__ bias)
{
    __shared__ unsigned short a_lds[64 * 72];   // input rows (m), bf16, +8 pad
    __shared__ unsigned short w_lds[64 * 72];   // W rows (n), bf16, +8 pad
    const int t = threadIdx.x;
    const int wave = t >> 6, lane = t & 63;
    const int bn = blockIdx.x << 6, bm = blockIdx.y << 6;
    const int kg = lane >> 4;
    const int K = K1 + K2;

    f32x4 acc0 = {0.f, 0.f, 0.f, 0.f};
    f32x4 acc1 = {0.f, 0.f, 0.f, 0.f};
    f32x4 acc2 = {0.f, 0.f, 0.f, 0.f};
    f32x4 acc3 = {0.f, 0.f, 0.f, 0.f};

    const int srow = t >> 2, sc0 = (t & 3) << 4;   // staging: row, 16-col slice

    for (int kb = 0; kb < K; kb += 64) {
        __syncthreads();
        {
            // input rows (chunk entirely within in1 or in2: K1 % 64 == 0)
            const float* src; int ld; int col = kb + sc0;
            if (col < K1) { src = in1; ld = K1; } else { src = in2; ld = K2; col -= K1; }
            const float* p = &src[(size_t)(bm + srow) * ld + col];
#pragma unroll
            for (int i = 0; i < 4; ++i) {
                const float4 f = *(const float4*)(p + (i << 2));
                uint2 pk;
                pk.x = pack_bf16(f.x, f.y);
                pk.y = pack_bf16(f.z, f.w);
                *(uint2*)&a_lds[srow * 72 + sc0 + (i << 2)] = pk;
            }
            const float* pw = &Wm[(size_t)(bn + srow) * K + kb + sc0];
#pragma unroll
            for (int i = 0; i < 4; ++i) {
                const float4 f = *(const float4*)(pw + (i << 2));
                uint2 pk;
                pk.x = pack_bf16(f.x, f.y);
                pk.y = pack_bf16(f.z, f.w);
                *(uint2*)&w_lds[srow * 72 + sc0 + (i << 2)] = pk;
            }
        }
        __syncthreads();

#pragma unroll
        for (int ks = 0; ks < 2; ++ks) {
            const int koff = (ks << 5) + (kg << 3);
            const bf16x8 af = *(const bf16x8*)&w_lds[((wave << 4) + (lane & 15)) * 72 + koff];
            const bf16x8 b0 = *(const bf16x8*)&a_lds[((0 << 4) + (lane & 15)) * 72 + koff];
            const bf16x8 b1 = *(const bf16x8*)&a_lds[((1 << 4) + (lane & 15)) * 72 + koff];
            const bf16x8 b2 = *(const bf16x8*)&a_lds[((2 << 4) + (lane & 15)) * 72 + koff];
            const bf16x8 b3 = *(const bf16x8*)&a_lds[((3 << 4) + (lane & 15)) * 72 + koff];
            acc0 = __builtin_amdgcn_mfma_f32_16x16x32_bf16(af, b0, acc0, 0, 0, 0);
            acc1 = __builtin_amdgcn_mfma_f32_16x16x32_bf16(af, b1, acc1, 0, 0, 0);
            acc2 = __builtin_amdgcn_mfma_f32_16x16x32_bf16(af, b2, acc2, 0, 0, 0);
            acc3 = __builtin_amdgcn_mfma_f32_16x16x32_bf16(af, b3, acc3, 0, 0, 0);
        }
    }

    // epilogue: n = bn + wave*16 + kg*4 + r (contiguous 4), m = bm + mq*16 + (lane&15)
    const int ncol = bn + (wave << 4) + (kg << 2);
    const float4 bv = *(const float4*)&bias[ncol];
#define EPI(MQ, ACC) do {                                              \
        const int m_ = bm + (MQ << 4) + (lane & 15);                   \
        float4 r_;                                                     \
        r_.x = ACC[0] + bv.x; r_.y = ACC[1] + bv.y;                    \
        r_.z = ACC[2] + bv.z; r_.w = ACC[3] + bv.w;                    \
        *(float4*)&C[(size_t)m_ * N + ncol] = r_;                      \
    } while (0)
    EPI(0, acc0);
    EPI(1, acc1);
    EPI(2, acc2);
    EPI(3, acc3);
#undef EPI
}

// ---------------------------------------------------------------------------
extern "C" void kernel_launch(void* const* d_in, const int* in_sizes, int n_in,
                              void* d_out, int out_size, void* d_ws, size_t ws_size,
                              hipStream_t stream)
{
    (void)in_sizes; (void)n_in; (void)out_size;
    const float* x     = (const float*)d_in[0];
    const float* keys  = (const float*)d_in[1];
    const float* values= (const float*)d_in[2];
    const float* imp   = (const float*)d_in[3];
    const float* W_ih  = (const float*)d_in[4];
    const float* W_hh  = (const float*)d_in[5];
    const float* b_ih  = (const float*)d_in[6];
    const float* b_hh  = (const float*)d_in[7];
    const float* Wq    = (const float*)d_in[8];
    const float* bq    = (const float*)d_in[9];
    const float* Wa    = (const float*)d_in[10];
    const float* ba    = (const float*)d_in[11];
    const float* Wc    = (const float*)d_in[12];
    const float* bc    = (const float*)d_in[13];
    const float* Wo    = (const float*)d_in[14];
    const float* bo    = (const float*)d_in[15];
    float* out = (float*)d_out;

    float* ws = (float*)d_ws;
    size_t o = 0;
    float* xp      = ws + o; o += (size_t)1024 * 4096;           // 16 MB
    float* h_all   = ws + o; o += (size_t)1024 * 1024;           // 4 MB
    unsigned* rec  = (unsigned*)(ws + o); o += 2 * 4096;         // tagged records
    float* rnk     = ws + o; o += NKEY;                          // imp/||key||
    float* qbuf    = ws + o; o += (size_t)ROWS * 256;
    float* qn      = ws + o; o += (size_t)ROWS * 256;
    float* part_v8 = ws + o; o += (size_t)ROWS * KSPLITS * 8;    // 1 MB
    int*   part_i8 = (int*)(ws + o); o += (size_t)ROWS * KSPLITS * 8;
    int*   cand8_i = (int*)(ws + o); o += ROWS * 8;
    float* mem_raw = ws + o; o += (size_t)ROWS * 256;
    float* memb    = ws + o; o += (size_t)ROWS * 256;
    unsigned short* kb = (unsigned short*)(ws + o);              // bf16 keys, 32 MB
    const size_t need_bf16 = (o + (size_t)NKEY * 256 / 2) * sizeof(float);
    const bool use_bf16 = ws_size >= need_bf16;                  // deterministic

    // zero records: slot-0 tag byte = 0 (= step-0 tag) with h = +0.0
    hipMemsetAsync(rec, 0, 2 * 4096 * 4, stream);

    // x_proj = x @ W_ih^T + b_ih + b_hh : [1024, 4096]
    sgemm_nt_w<<<dim3(32, 16), 256, 0, stream>>>(x, W_ih, xp, b_ih, b_hh);

    // LSTM recurrence (blocks 0-255) + key-prep riders (blocks 256-511)
    lstm_kernel<<<2 * NWG_LSTM, NTH_LSTM, 0, stream>>>(
        xp, W_hh, rec, h_all, keys, imp, rnk, use_bf16 ? kb : nullptr);

    // q = h @ Wq^T + bq : [1024, 256]  (fp32: selection-critical)
    sgemm_nt<<<dim3(4, 16), 256, 0, stream>>>(h_all, HD, Wq, HD, qbuf, MD, HD, bq, nullptr, 0);

    rownorm<<<ROWS / 4, 256, 0, stream>>>(qbuf, qn, ROWS);

    // bf16 MFMA candidate scoring + fp32 rescore -> exact top-3 + gather
    if (use_bf16)
        sim_mfma_b8<<<dim3(KSPLITS, 8), 512, 0, stream>>>(qn, kb, part_v8, part_i8);
    else
        sim_mfma_f<<<dim3(KSPLITS, 16), 256, 0, stream>>>(qn, keys, rnk, part_v8, part_i8);
    cand_merge<<<32, 256, 0, stream>>>(part_v8, part_i8, cand8_i);
    rescore_gather<<<ROWS, 64, 0, stream>>>(qn, keys, rnk, cand8_i, values, Wa, ba, mem_raw);

    // mem = mem_raw @ Wc^T + bc  (bf16 MFMA; smooth path)
    gemm_bf16_nt<<<dim3(4, 16), 256, 0, stream>>>(mem_raw, MD, nullptr, 0, Wc, memb, MD, bc);

    // out = [h_all | memb] @ Wo^T + bo  (bf16 MFMA, single pass over K=1280)
    gemm_bf16_nt<<<dim3(8, 16), 256, 0, stream>>>(h_all, HD, memb, MD, Wo, out, OD, bo);
}

// Round 20
// 1182.779 us; speedup vs baseline: 1.1814x; 1.0042x over previous
//
#include <hip/hip_runtime.h>
#include <hip/hip_bf16.h>
#include <cstdint>
#include <cstddef>

// Problem constants
#define BB 4
#define SS 256
#define ID 512
#define HD 1024
#define MD 256
#define NKEY 65536
#define OD 512
#define ROWS 1024          // B*S
#define NWG_LSTM 256
#define NTH_LSTM 256
#define KPB 1024           // keys per sim block
#define KSPLITS (NKEY / KPB)   // 64

typedef __attribute__((ext_vector_type(8))) short bf16x8;
typedef __attribute__((ext_vector_type(4))) float f32x4;
typedef __attribute__((ext_vector_type(16))) float f32x16;
typedef __attribute__((ext_vector_type(8))) unsigned short u16x8;

// ---------------------------------------------------------------------------
// Generic SGEMM: C[M,N] = A[M,K] * Bm[N,K]^T (+bias) (fp32; selection path).
// ---------------------------------------------------------------------------
__global__ __launch_bounds__(256) void sgemm_nt(
    const float* __restrict__ A, int lda,
    const float* __restrict__ Bm, int ldb,
    float* __restrict__ C, int ldc, int K,
    const float* __restrict__ bias, const float* __restrict__ bias2,
    int accum)
{
    __shared__ float As[64][17];
    __shared__ float Bs[64][17];
    const int t = threadIdx.x;
    const int tx = t & 15, ty = t >> 4;
    const int bm = blockIdx.y << 6, bn = blockIdx.x << 6;
    const int lrow = t >> 2, lk4 = (t & 3) << 2;
    float acc[4][4] = {};

    for (int kb = 0; kb < K; kb += 16) {
        const float4 av = *(const float4*)&A[(size_t)(bm + lrow) * lda + kb + lk4];
        const float4 bv = *(const float4*)&Bm[(size_t)(bn + lrow) * ldb + kb + lk4];
        __syncthreads();
        As[lrow][lk4 + 0] = av.x; As[lrow][lk4 + 1] = av.y;
        As[lrow][lk4 + 2] = av.z; As[lrow][lk4 + 3] = av.w;
        Bs[lrow][lk4 + 0] = bv.x; Bs[lrow][lk4 + 1] = bv.y;
        Bs[lrow][lk4 + 2] = bv.z; Bs[lrow][lk4 + 3] = bv.w;
        __syncthreads();
#pragma unroll
        for (int k = 0; k < 16; ++k) {
            const float a0 = As[4 * ty + 0][k], a1 = As[4 * ty + 1][k];
            const float a2 = As[4 * ty + 2][k], a3 = As[4 * ty + 3][k];
            const float b0 = Bs[4 * tx + 0][k], b1 = Bs[4 * tx + 1][k];
            const float b2 = Bs[4 * tx + 2][k], b3 = Bs[4 * tx + 3][k];
            acc[0][0] += a0 * b0; acc[0][1] += a0 * b1; acc[0][2] += a0 * b2; acc[0][3] += a0 * b3;
            acc[1][0] += a1 * b0; acc[1][1] += a1 * b1; acc[1][2] += a1 * b2; acc[1][3] += a1 * b3;
            acc[2][0] += a2 * b0; acc[2][1] += a2 * b1; acc[2][2] += a2 * b2; acc[2][3] += a2 * b3;
            acc[3][0] += a3 * b0; acc[3][1] += a3 * b1; acc[3][2] += a3 * b2; acc[3][3] += a3 * b3;
        }
    }

#pragma unroll
    for (int i = 0; i < 4; ++i) {
        const int row = bm + 4 * ty + i;
        const int col = bn + 4 * tx;
        float4* cp = (float4*)&C[(size_t)row * ldc + col];
        float4 r;
        if (accum) {
            const float4 old = *cp;
            r.x = old.x + acc[i][0]; r.y = old.y + acc[i][1];
            r.z = old.z + acc[i][2]; r.w = old.w + acc[i][3];
        } else {
            float bx = bias[col + 0], by = bias[col + 1], bz = bias[col + 2], bw = bias[col + 3];
            if (bias2) { bx += bias2[col + 0]; by += bias2[col + 1]; bz += bias2[col + 2]; bw += bias2[col + 3]; }
            r.x = acc[i][0] + bx; r.y = acc[i][1] + by;
            r.z = acc[i][2] + bz; r.w = acc[i][3] + bw;
        }
        *cp = r;
    }
}

// ---------------------------------------------------------------------------
// x_proj GEMM: C[1024,4096] = A[1024,512] @ Bm[4096,512]^T + bias1 + bias2.
// ---------------------------------------------------------------------------
__global__ __launch_bounds__(256) void sgemm_nt_w(
    const float* __restrict__ A, const float* __restrict__ Bm,
    float* __restrict__ C, const float* __restrict__ bias, const float* __restrict__ bias2)
{
    __shared__ float As[16][64];
    __shared__ float Bs[16][128];
    const int t = threadIdx.x;
    const int tx = t & 15, ty = t >> 4;
    const int bm = blockIdx.y << 6, bn = blockIdx.x << 7;
    const int arow = t & 63, akq = t >> 6;       // A: 1 float4 per thread
    const int brow = t & 127, bkq = t >> 7;      // B: 2 float4 per thread
    float acc[4][8] = {};

    for (int kb = 0; kb < 512; kb += 16) {
        const float4 av  = *(const float4*)&A[(size_t)(bm + arow) * 512 + kb + (akq << 2)];
        const float4 bv0 = *(const float4*)&Bm[(size_t)(bn + brow) * 512 + kb + (bkq << 3)];
        const float4 bv1 = *(const float4*)&Bm[(size_t)(bn + brow) * 512 + kb + (bkq << 3) + 4];
        __syncthreads();
        As[(akq << 2) + 0][arow] = av.x; As[(akq << 2) + 1][arow] = av.y;
        As[(akq << 2) + 2][arow] = av.z; As[(akq << 2) + 3][arow] = av.w;
        Bs[(bkq << 3) + 0][brow] = bv0.x; Bs[(bkq << 3) + 1][brow] = bv0.y;
        Bs[(bkq << 3) + 2][brow] = bv0.z; Bs[(bkq << 3) + 3][brow] = bv0.w;
        Bs[(bkq << 3) + 4][brow] = bv1.x; Bs[(bkq << 3) + 5][brow] = bv1.y;
        Bs[(bkq << 3) + 6][brow] = bv1.z; Bs[(bkq << 3) + 7][brow] = bv1.w;
        __syncthreads();
#pragma unroll
        for (int k = 0; k < 16; ++k) {
            const float4 a  = *(const float4*)&As[k][ty << 2];
            const float4 b0 = *(const float4*)&Bs[k][tx << 3];
            const float4 b1 = *(const float4*)&Bs[k][(tx << 3) + 4];
            acc[0][0] += a.x * b0.x; acc[0][1] += a.x * b0.y; acc[0][2] += a.x * b0.z; acc[0][3] += a.x * b0.w;
            acc[0][4] += a.x * b1.x; acc[0][5] += a.x * b1.y; acc[0][6] += a.x * b1.z; acc[0][7] += a.x * b1.w;
            acc[1][0] += a.y * b0.x; acc[1][1] += a.y * b0.y; acc[1][2] += a.y * b0.z; acc[1][3] += a.y * b0.w;
            acc[1][4] += a.y * b1.x; acc[1][5] += a.y * b1.y; acc[1][6] += a.y * b1.z; acc[1][7] += a.y * b1.w;
            acc[2][0] += a.z * b0.x; acc[2][1] += a.z * b0.y; acc[2][2] += a.z * b0.z; acc[2][3] += a.z * b0.w;
            acc[2][4] += a.z * b1.x; acc[2][5] += a.z * b1.y; acc[2][6] += a.z * b1.z; acc[2][7] += a.z * b1.w;
            acc[3][0] += a.w * b0.x; acc[3][1] += a.w * b0.y; acc[3][2] += a.w * b0.z; acc[3][3] += a.w * b0.w;
            acc[3][4] += a.w * b1.x; acc[3][5] += a.w * b1.y; acc[3][6] += a.w * b1.z; acc[3][7] += a.w * b1.w;
        }
    }

#pragma unroll
    for (int i = 0; i < 4; ++i) {
        const int row = bm + (ty << 2) + i;
        const int col = bn + (tx << 3);
        float4 r0, r1;
        r0.x = acc[i][0] + bias[col + 0] + bias2[col + 0];
        r0.y = acc[i][1] + bias[col + 1] + bias2[col + 1];
        r0.z = acc[i][2] + bias[col + 2] + bias2[col + 2];
        r0.w = acc[i][3] + bias[col + 3] + bias2[col + 3];
        r1.x = acc[i][4] + bias[col + 4] + bias2[col + 4];
        r1.y = acc[i][5] + bias[col + 5] + bias2[col + 5];
        r1.z = acc[i][6] + bias[col + 6] + bias2[col + 6];
        r1.w = acc[i][7] + bias[col + 7] + bias2[col + 7];
        *(float4*)&C[(size_t)row * 4096 + col] = r0;
        *(float4*)&C[(size_t)row * 4096 + col + 4] = r1;
    }
}

__device__ inline unsigned pack_bf16(float a, float b) {
    return (__float_as_uint(a) >> 16) | (__float_as_uint(b) & 0xFFFF0000u);
}

// ---------------------------------------------------------------------------
// Row L2-normalization (256-col rows), for qn.
// ---------------------------------------------------------------------------
__global__ void rownorm(const float* __restrict__ X, float* __restrict__ Xn, int nrows)
{
    const int row = blockIdx.x * 4 + (threadIdx.x >> 6);
    const int lane = threadIdx.x & 63;
    if (row >= nrows) return;
    float4 v = *(const float4*)&X[(size_t)row * 256 + (lane << 2)];
    float ss = v.x * v.x + v.y * v.y + v.z * v.z + v.w * v.w;
#pragma unroll
    for (int o = 1; o < 64; o <<= 1) ss += __shfl_xor(ss, o);
    const float sc = 1.f / fmaxf(sqrtf(ss), 1e-12f);
    v.x *= sc; v.y *= sc; v.z *= sc; v.w *= sc;
    *(float4*)&Xn[(size_t)row * 256 + (lane << 2)] = v;
}

// ---------------------------------------------------------------------------
// Persistent LSTM (blocks 0..255, proven round-10 depth-1 pipeline) +
// key-prep rider blocks (256..511).
// ---------------------------------------------------------------------------
__device__ inline float sigm_f(float x) { return 1.f / (1.f + __expf(-x)); }
__device__ inline float tanh_f(float x) { return 1.f - 2.f / (__expf(2.f * x) + 1.f); }

#define SUBSTEP(B, U, UN, C4, XPC) do {                                           \
    asm volatile("s_waitcnt vmcnt(3)" ::: "memory");                              \
    __builtin_amdgcn_sched_barrier(0);                                            \
    const unsigned* pb_ = rec + (slot << 12) + (B << 10) + (t << 2);              \
    while ((((U.x ^ st) | (U.y ^ st) | (U.z ^ st) | (U.w ^ st)) & 0xFFu) != 0u) { \
        __builtin_amdgcn_s_sleep(1);                                              \
        asm volatile("global_load_dwordx4 %0, %1, off sc0 sc1\n\ts_waitcnt vmcnt(0)" \
                     : "=&v"(U) : "v"(pb_) : "memory");                           \
    }                                                                             \
    {                                                                             \
        float4 hw_;                                                               \
        hw_.x = __uint_as_float(U.x & 0xFFFFFF00u);                               \
        hw_.y = __uint_as_float(U.y & 0xFFFFFF00u);                               \
        hw_.z = __uint_as_float(U.z & 0xFFFFFF00u);                               \
        hw_.w = __uint_as_float(U.w & 0xFFFFFF00u);                               \
        *(float4*)&h_lds[B][t << 2] = hw_;                                        \
    }                                                                             \
    asm volatile("s_waitcnt lgkmcnt(0)" ::: "memory");                            \
    __builtin_amdgcn_sched_barrier(0);                                            \
    __builtin_amdgcn_s_barrier();                                                 \
    {                                                                             \
        const unsigned* pn_ = rec + (((B == 3) ? (slot ^ 1) : slot) << 12)        \
                              + (((B + 1) & 3) << 10) + (t << 2);                 \
        asm volatile("global_load_dwordx4 %0, %1, off sc0 sc1"                    \
                     : "=&v"(UN) : "v"(pn_) : "memory");                          \
    }                                                                             \
    const float* hb_ = &h_lds[B][0];                                              \
    float ax_ = 0.f, ay_ = 0.f, az_ = 0.f, aw_ = 0.f;                             \
    _Pragma("unroll")                                                             \
    for (int j = 0; j < 16; ++j) {                                                \
        const float4 hv_ = *(const float4*)&hb_[(ksub << 2) + (j << 6)];          \
        ax_ += w4[j].x * hv_.x; ay_ += w4[j].y * hv_.y;                           \
        az_ += w4[j].z * hv_.z; aw_ += w4[j].w * hv_.w;                           \
    }                                                                             \
    float sm_ = (ax_ + ay_) + (az_ + aw_);                                        \
    sm_ += __shfl_xor(sm_, 1); sm_ += __shfl_xor(sm_, 2);                         \
    sm_ += __shfl_xor(sm_, 4); sm_ += __shfl_xor(sm_, 8);                         \
    sm_ += XPC;                                                                   \
    const float vi_ = __shfl(sm_, ksub);                                          \
    const float vf_ = __shfl(sm_, ksub + 16);                                     \
    const float vg_ = __shfl(sm_, ksub + 32);                                     \
    const float vo_ = __shfl(sm_, ksub + 48);                                     \
    const float iv_ = sigm_f(vi_), fv_ = sigm_f(vf_);                             \
    const float gv_ = tanh_f(vg_), ov_ = sigm_f(vo_);                             \
    C4 = fv_ * C4 + iv_ * gv_;                                                    \
    const float hvv_ = ov_ * tanh_f(C4);                                          \
    if (lane == 0) {                                                              \
        unsigned* dst_ = rec + ((slot ^ 1) << 12) + (B << 10) + unit;             \
        const unsigned uv_ = (__float_as_uint(hvv_) & 0xFFFFFF00u) |              \
                             ((unsigned)(s + 1) & 0xFFu);                         \
        float* ha_ = &h_all[(size_t)((B << 8) + s) * 1024 + unit];                \
        asm volatile("global_store_dword %0, %1, off sc0 sc1"                     \
                     :: "v"(dst_), "v"(uv_) : "memory");                          \
        asm volatile("global_store_dword %0, %1, off"                             \
                     :: "v"(ha_), "v"(hvv_) : "memory");                          \
    }                                                                             \
    {                                                                             \
        const float* px_ = &xp[(size_t)((B << 8) + sn) * 4096 + wrow];            \
        asm volatile("global_load_dword %0, %1, off"                              \
                     : "=&v"(XPC) : "v"(px_) : "memory");                         \
    }                                                                             \
} while (0)

__global__ __launch_bounds__(256) void lstm_kernel(
    const float* __restrict__ xp, const float* __restrict__ W_hh,
    unsigned* __restrict__ rec, float* __restrict__ h_all,
    const float* __restrict__ keys, const float* __restrict__ imp,
    float* __restrict__ rnk, unsigned short* __restrict__ kb)
{
    __shared__ float h_lds[4][1024];
    const int t = threadIdx.x;

    if (blockIdx.x >= NWG_LSTM) {
        // ---- key-prep rider: 256 rows per block ----
        const int base_row = (blockIdx.x - NWG_LSTM) << 8;
        const int lane = t & 63;
        for (int it = 0; it < 64; ++it) {
            const int row = base_row + (it << 2) + (t >> 6);
            float4 v = *(const float4*)&keys[(size_t)row * 256 + (lane << 2)];
            float ss = v.x * v.x + v.y * v.y + v.z * v.z + v.w * v.w;
#pragma unroll
            for (int o = 1; o < 64; o <<= 1) ss += __shfl_xor(ss, o);
            const float sc = imp[row] / fmaxf(sqrtf(ss), 1e-12f);
            if (lane == 0) rnk[row] = sc;
            if (kb) {
                uint2 p;
                p.x = pack_bf16(v.x * sc, v.y * sc);
                p.y = pack_bf16(v.z * sc, v.w * sc);
                *(uint2*)&kb[(size_t)row * 256 + (lane << 2)] = p;
            }
        }
        return;
    }

    const int wave = t >> 6, lane = t & 63;
    const int gt = lane >> 4, ksub = lane & 15;   // gate 0..3 (i,f,g,o), k-sub 0..15
    const int unit = (blockIdx.x << 2) + wave;
    const int wrow = (gt << 10) + unit;           // W_hh row

    float4 w4[16];
#pragma unroll
    for (int j = 0; j < 16; ++j)
        w4[j] = *(const float4*)&W_hh[(size_t)wrow * 1024 + (ksub << 2) + (j << 6)];

    float c40 = 0.f, c41 = 0.f, c42 = 0.f, c43 = 0.f;   // cell state (per-lane)
    float xpc0 = xp[(size_t)(0 * 256 + 0) * 4096 + wrow];
    float xpc1 = xp[(size_t)(1 * 256 + 0) * 4096 + wrow];
    float xpc2 = xp[(size_t)(2 * 256 + 0) * 4096 + wrow];
    float xpc3 = xp[(size_t)(3 * 256 + 0) * 4096 + wrow];

    uint4 u0 = make_uint4(~0u, ~0u, ~0u, ~0u);    // tag 0xFF -> retry path on
    uint4 u1 = u0, u2 = u0, u3 = u0;              // first use (never a step tag)

    // prologue: issue poll for (s=0,b=0) and drain so the pipeline count is exact
    {
        const unsigned* p00 = rec + (t << 2);
        asm volatile("global_load_dwordx4 %0, %1, off sc0 sc1\n\ts_waitcnt vmcnt(0)"
                     : "=&v"(u0) : "v"(p00) : "memory");
        __builtin_amdgcn_sched_barrier(0);
    }

    for (int s = 0; s < 256; ++s) {
        const int slot = s & 1;
        const unsigned st = (unsigned)s & 0xFFu;
        const int sn = (s < 255) ? s + 1 : 255;   // clamped next-step xp row
        SUBSTEP(0, u0, u1, c40, xpc0);
        SUBSTEP(1, u1, u2, c41, xpc1);
        SUBSTEP(2, u2, u3, c42, xpc2);
        SUBSTEP(3, u3, u0, c43, xpc3);
    }
}

// ---------------------------------------------------------------------------
// Static-register top-8 insertion (sorted v0>=...>=v7).
// ---------------------------------------------------------------------------
#define SWAP1(A, B, IA, IB) { float _t = A; A = B; B = _t; int _u = IA; IA = IB; IB = _u; }
#define INS8G(P, V, ID) do {                                          \
    const float _v = (V); const int _id = (ID);                       \
    if (_v > P##v7) {                                                 \
        P##v7 = _v; P##i7 = _id;                                      \
        if (P##v7 > P##v6) SWAP1(P##v6, P##v7, P##i6, P##i7);         \
        if (P##v6 > P##v5) SWAP1(P##v5, P##v6, P##i5, P##i6);         \
        if (P##v5 > P##v4) SWAP1(P##v4, P##v5, P##i4, P##i5);         \
        if (P##v4 > P##v3) SWAP1(P##v3, P##v4, P##i3, P##i4);         \
        if (P##v3 > P##v2) SWAP1(P##v2, P##v3, P##i2, P##i3);         \
        if (P##v2 > P##v1) SWAP1(P##v1, P##v2, P##i1, P##i2);         \
        if (P##v1 > P##v0) SWAP1(P##v0, P##v1, P##i0, P##i1);         \
    }                                                                 \
} while (0)
#define DECL8(P) float P##v0=-3e38f,P##v1=-3e38f,P##v2=-3e38f,P##v3=-3e38f, \
                       P##v4=-3e38f,P##v5=-3e38f,P##v6=-3e38f,P##v7=-3e38f; \
                 int P##i0=0x7fffffff,P##i1=0x7fffffff,P##i2=0x7fffffff,P##i3=0x7fffffff, \
                     P##i4=0x7fffffff,P##i5=0x7fffffff,P##i6=0x7fffffff,P##i7=0x7fffffff;

// ---------------------------------------------------------------------------
// sim_mfma_b32: bf16 32x32x16 MFMA candidate scoring from pre-converted
// bf16 keys. Grid (KSPLITS=64, 8) = 512 blocks x 256 thr (4 waves) =
// 2 blocks/CU = 2 waves/SIMD (the proven occupancy). Wave w scores 32
// queries q0 + w*32 + (lane&31). A = keys from LDS (row = lane&31 within
// key-group, k = (lane>>5)*8+e), B = queries in regs (16 x bf16x8).
// D (verified m74/m101): col = lane&31 = query, row = (reg&3) + 8*(reg>>2)
// + 4*(lane>>5) = key-within-group. One A ds_read feeds one 32k-FLOP MFMA
// -> ds_read count halves vs the 16x16 version.
// ---------------------------------------------------------------------------
__global__ __launch_bounds__(256, 2) void sim_mfma_b32(
    const float* __restrict__ qn, const unsigned short* __restrict__ kb,
    float* __restrict__ part_v8, int* __restrict__ part_i8)
{
    __shared__ unsigned short k_lds[64 * 264];    // 33 KB; merge aliases onto it
    const int t = threadIdx.x;
    const int wave = t >> 6, lane = t & 63;
    const int ks = blockIdx.x, qs = blockIdx.y;
    const int key_base = ks * KPB;                // KPB = 1024
    const int q0 = qs << 7;                       // 128 queries per block
    const int qrow = q0 + (wave << 5) + (lane & 31);
    const int kh = lane >> 5;                     // k-half (8-elem group)

    // B fragments: 16 k-chunks of 16; lane holds 8 elems at kc*16 + kh*8
    bf16x8 bq[16];
#pragma unroll
    for (int kc = 0; kc < 16; ++kc) {
        const float* qp = &qn[(size_t)qrow * 256 + (kc << 4) + (kh << 3)];
        const float4 f0 = *(const float4*)qp;
        const float4 f1 = *(const float4*)(qp + 4);
        union { unsigned int u[4]; bf16x8 h; } cv;
        cv.u[0] = pack_bf16(f0.x, f0.y);
        cv.u[1] = pack_bf16(f0.z, f0.w);
        cv.u[2] = pack_bf16(f1.x, f1.y);
        cv.u[3] = pack_bf16(f1.z, f1.w);
        bq[kc] = cv.h;
    }

    DECL8(t)

    const int srow = t >> 2, sc0 = (t & 3) << 6;   // staging: row, 64-col slice

    for (int stg = 0; stg < KPB / 64; ++stg) {
        __syncthreads();
        {
            const unsigned short* kp = &kb[(size_t)(key_base + (stg << 6) + srow) * 256 + sc0];
#pragma unroll
            for (int i = 0; i < 8; ++i)
                *(u16x8*)&k_lds[srow * 264 + sc0 + (i << 3)] = *(const u16x8*)(kp + (i << 3));
        }
        __syncthreads();

        f32x16 a0 = {0.f};
        f32x16 a1 = {0.f};
#pragma unroll
        for (int kc = 0; kc < 16; ++kc) {
            const int col = (kc << 4) + (kh << 3);
            const bf16x8 k0 = *(const bf16x8*)&k_lds[((lane & 31)) * 264 + col];
            const bf16x8 k1 = *(const bf16x8*)&k_lds[(32 + (lane & 31)) * 264 + col];
            a0 = __builtin_amdgcn_mfma_f32_32x32x16_bf16(k0, bq[kc], a0, 0, 0, 0);
            a1 = __builtin_amdgcn_mfma_f32_32x32x16_bf16(k1, bq[kc], a1, 0, 0, 0);
        }

        // insert: key row(r) = (r&3) + 8*(r>>2) + 4*kh  (within 32-key group)
        const int kb0 = key_base + (stg << 6) + (kh << 2);
#define INSROW(ACC, BASE, R) INS8G(t, ACC[R], (BASE) + ((R) & 3) + (((R) >> 2) << 3))
#pragma unroll
        for (int r = 0; r < 16; ++r) INSROW(a0, kb0, r);
#pragma unroll
        for (int r = 0; r < 16; ++r) INSROW(a1, kb0 + 32, r);
#undef INSROW
    }

    // ---- merge phase: alias cand arrays onto k_lds (16 KB <= 33 KB) ----
    float* cand_v = (float*)k_lds;                 // [256][8] floats, 8 KB
    int*   cand_i = (int*)(k_lds + 4096);          // [256][8] ints,   8 KB
    __syncthreads();
    cand_v[t * 8 + 0] = tv0; cand_i[t * 8 + 0] = ti0;
    cand_v[t * 8 + 1] = tv1; cand_i[t * 8 + 1] = ti1;
    cand_v[t * 8 + 2] = tv2; cand_i[t * 8 + 2] = ti2;
    cand_v[t * 8 + 3] = tv3; cand_i[t * 8 + 3] = ti3;
    cand_v[t * 8 + 4] = tv4; cand_i[t * 8 + 4] = ti4;
    cand_v[t * 8 + 5] = tv5; cand_i[t * 8 + 5] = ti5;
    cand_v[t * 8 + 6] = tv6; cand_i[t * 8 + 6] = ti6;
    cand_v[t * 8 + 7] = tv7; cand_i[t * 8 + 7] = ti7;
    __syncthreads();
    if (t < 128) {
        DECL8(m)
        const int w = t >> 5, c = t & 31;          // query q0 + t = wave w, col c
        const int s0 = ((w << 6) + c) * 8;         // lane c (kh=0)
        const int s1 = ((w << 6) + 32 + c) * 8;    // lane c+32 (kh=1)
        for (int r = 0; r < 8; ++r) INS8G(m, cand_v[s0 + r], cand_i[s0 + r]);
        for (int r = 0; r < 8; ++r) INS8G(m, cand_v[s1 + r], cand_i[s1 + r]);
        const size_t base = (size_t)(q0 + t) * (KSPLITS * 8) + ks * 8;
        part_v8[base + 0] = mv0; part_i8[base + 0] = mi0;
        part_v8[base + 1] = mv1; part_i8[base + 1] = mi1;
        part_v8[base + 2] = mv2; part_i8[base + 2] = mi2;
        part_v8[base + 3] = mv3; part_i8[base + 3] = mi3;
        part_v8[base + 4] = mv4; part_i8[base + 4] = mi4;
        part_v8[base + 5] = mv5; part_i8[base + 5] = mi5;
        part_v8[base + 6] = mv6; part_i8[base + 6] = mi6;
        part_v8[base + 7] = mv7; part_i8[base + 7] = mi7;
    }
}

// ---------------------------------------------------------------------------
// sim_mfma_f: fp32-key fallback (16x16 shape, 4 waves), KPB=1024/KSPLITS=64.
// ---------------------------------------------------------------------------
__global__ __launch_bounds__(256) void sim_mfma_f(
    const float* __restrict__ qn, const float* __restrict__ keys,
    const float* __restrict__ rnk, float* __restrict__ part_v8, int* __restrict__ part_i8)
{
    __shared__ unsigned short k_lds[64 * 264];
    __shared__ float cand_v[256 * 8];
    __shared__ int   cand_i[256 * 8];
    const int t = threadIdx.x;
    const int wave = t >> 6, lane = t & 63;
    const int ks = blockIdx.x, qs = blockIdx.y;
    const int key_base = ks * KPB;
    const int q0 = qs << 6;
    const int qrow = q0 + (wave << 4) + (lane & 15);
    const int kg = lane >> 4;

    bf16x8 bq[8];
#pragma unroll
    for (int kc = 0; kc < 8; ++kc) {
        const float* qp = &qn[(size_t)qrow * 256 + (kc << 5) + (kg << 3)];
        const float4 f0 = *(const float4*)qp;
        const float4 f1 = *(const float4*)(qp + 4);
        union { unsigned int u[4]; bf16x8 h; } cv;
        cv.u[0] = pack_bf16(f0.x, f0.y);
        cv.u[1] = pack_bf16(f0.z, f0.w);
        cv.u[2] = pack_bf16(f1.x, f1.y);
        cv.u[3] = pack_bf16(f1.z, f1.w);
        bq[kc] = cv.h;
    }

    DECL8(t)

    for (int stg = 0; stg < KPB / 64; ++stg) {
        __syncthreads();
#pragma unroll
        for (int i = 0; i < 8; ++i) {
            const int g = (i << 11) + (t << 3);
            const int row = g >> 8, col = g & 255;
            const int krow = key_base + (stg << 6) + row;
            const float sc = rnk[krow];
            const float* kp = &keys[(size_t)krow * 256 + col];
            float4 f0 = *(const float4*)kp;
            float4 f1 = *(const float4*)(kp + 4);
            f0.x *= sc; f0.y *= sc; f0.z *= sc; f0.w *= sc;
            f1.x *= sc; f1.y *= sc; f1.z *= sc; f1.w *= sc;
            union { unsigned int u[4]; u16x8 h; } cv;
            cv.u[0] = pack_bf16(f0.x, f0.y);
            cv.u[1] = pack_bf16(f0.z, f0.w);
            cv.u[2] = pack_bf16(f1.x, f1.y);
            cv.u[3] = pack_bf16(f1.z, f1.w);
            *(u16x8*)&k_lds[row * 264 + col] = cv.h;
        }
        __syncthreads();

#pragma unroll
        for (int kt = 0; kt < 4; ++kt) {
            f32x4 a0 = {0.f, 0.f, 0.f, 0.f};
            f32x4 a1 = {0.f, 0.f, 0.f, 0.f};
#pragma unroll
            for (int kc = 0; kc < 4; ++kc) {
                const bf16x8 af = *(const bf16x8*)&k_lds[((kt << 4) + (lane & 15)) * 264 +
                                                         (kc << 5) + (kg << 3)];
                a0 = __builtin_amdgcn_mfma_f32_16x16x32_bf16(af, bq[kc], a0, 0, 0, 0);
            }
#pragma unroll
            for (int kc = 4; kc < 8; ++kc) {
                const bf16x8 af = *(const bf16x8*)&k_lds[((kt << 4) + (lane & 15)) * 264 +
                                                         (kc << 5) + (kg << 3)];
                a1 = __builtin_amdgcn_mfma_f32_16x16x32_bf16(af, bq[kc], a1, 0, 0, 0);
            }
            const int kidx = key_base + (stg << 6) + (kt << 4) + (kg << 2);
            INS8G(t, a0[0] + a1[0], kidx + 0);
            INS8G(t, a0[1] + a1[1], kidx + 1);
            INS8G(t, a0[2] + a1[2], kidx + 2);
            INS8G(t, a0[3] + a1[3], kidx + 3);
        }
    }

    __syncthreads();
    cand_v[t * 8 + 0] = tv0; cand_i[t * 8 + 0] = ti0;
    cand_v[t * 8 + 1] = tv1; cand_i[t * 8 + 1] = ti1;
    cand_v[t * 8 + 2] = tv2; cand_i[t * 8 + 2] = ti2;
    cand_v[t * 8 + 3] = tv3; cand_i[t * 8 + 3] = ti3;
    cand_v[t * 8 + 4] = tv4; cand_i[t * 8 + 4] = ti4;
    cand_v[t * 8 + 5] = tv5; cand_i[t * 8 + 5] = ti5;
    cand_v[t * 8 + 6] = tv6; cand_i[t * 8 + 6] = ti6;
    cand_v[t * 8 + 7] = tv7; cand_i[t * 8 + 7] = ti7;
    __syncthreads();
    if (t < 64) {
        DECL8(m)
        const int w = t >> 4, c = t & 15;
        for (int g = 0; g < 4; ++g) {
            const int src = ((w << 6) + c + (g << 4)) * 8;
            for (int r = 0; r < 8; ++r)
                INS8G(m, cand_v[src + r], cand_i[src + r]);
        }
        const size_t base = (size_t)(q0 + t) * (KSPLITS * 8) + ks * 8;
        part_v8[base + 0] = mv0; part_i8[base + 0] = mi0;
        part_v8[base + 1] = mv1; part_i8[base + 1] = mi1;
        part_v8[base + 2] = mv2; part_i8[base + 2] = mi2;
        part_v8[base + 3] = mv3; part_i8[base + 3] = mi3;
        part_v8[base + 4] = mv4; part_i8[base + 4] = mi4;
        part_v8[base + 5] = mv5; part_i8[base + 5] = mi5;
        part_v8[base + 6] = mv6; part_i8[base + 6] = mi6;
        part_v8[base + 7] = mv7; part_i8[base + 7] = mi7;
    }
}

// ---------------------------------------------------------------------------
// cand_merge: two-stage, KSPLITS=64. Grid 32 x 256; 32 queries/block,
// 8 threads/query each scanning 8 splits' sorted top-8s (64 entries).
// ---------------------------------------------------------------------------
__global__ __launch_bounds__(256) void cand_merge(
    const float* __restrict__ part_v8, const int* __restrict__ part_i8,
    int* __restrict__ cand8_i)
{
    __shared__ float pv[256 * 8];
    __shared__ int   pi[256 * 8];
    const int t = threadIdx.x;
    const int qq = t >> 3, sl = t & 7;             // query-in-block, slice
    const int q = (blockIdx.x << 5) + qq;
    {
        DECL8(p)
        const size_t base = (size_t)q * (KSPLITS * 8) + sl * 64;
        for (int j = 0; j < 64; ++j)
            INS8G(p, part_v8[base + j], part_i8[base + j]);
        pv[t * 8 + 0] = pv0; pi[t * 8 + 0] = pi0;
        pv[t * 8 + 1] = pv1; pi[t * 8 + 1] = pi1;
        pv[t * 8 + 2] = pv2; pi[t * 8 + 2] = pi2;
        pv[t * 8 + 3] = pv3; pi[t * 8 + 3] = pi3;
        pv[t * 8 + 4] = pv4; pi[t * 8 + 4] = pi4;
        pv[t * 8 + 5] = pv5; pi[t * 8 + 5] = pi5;
        pv[t * 8 + 6] = pv6; pi[t * 8 + 6] = pi6;
        pv[t * 8 + 7] = pv7; pi[t * 8 + 7] = pi7;
    }
    __syncthreads();
    if (sl == 0) {
        DECL8(c)
        const int b0 = (qq << 3) * 8;
        for (int j = 0; j < 64; ++j)
            INS8G(c, pv[b0 + j], pi[b0 + j]);
        cand8_i[q * 8 + 0] = ci0; cand8_i[q * 8 + 1] = ci1;
        cand8_i[q * 8 + 2] = ci2; cand8_i[q * 8 + 3] = ci3;
        cand8_i[q * 8 + 4] = ci4; cand8_i[q * 8 + 5] = ci5;
        cand8_i[q * 8 + 6] = ci6; cand8_i[q * 8 + 7] = ci7;
    }
}

// ---------------------------------------------------------------------------
// Fused: fp32 rescore -> exact top-3 -> gather -> softmax -> weighted sum.
// ---------------------------------------------------------------------------
__global__ void rescore_gather(const float* __restrict__ qn, const float* __restrict__ keys,
                               const float* __restrict__ rnk, const int* __restrict__ cand8_i,
                               const float* __restrict__ values, const float* __restrict__ Wa,
                               const float* __restrict__ ba, float* __restrict__ mem_raw)
{
    const int q = blockIdx.x;
    const int lane = threadIdx.x;
    const float4 qv = *(const float4*)&qn[(size_t)q * 256 + (lane << 2)];
    float s0, s1, s2, s3, s4, s5, s6, s7;
    int j0, j1, j2, j3, j4, j5, j6, j7;
#define RES(R, S, J) { J = cand8_i[q * 8 + R]; \
    const float4 kv = *(const float4*)&keys[(size_t)J * 256 + (lane << 2)]; \
    float d = qv.x * kv.x + qv.y * kv.y + qv.z * kv.z + qv.w * kv.w; \
    d += __shfl_xor(d, 1); d += __shfl_xor(d, 2); d += __shfl_xor(d, 4); \
    d += __shfl_xor(d, 8); d += __shfl_xor(d, 16); d += __shfl_xor(d, 32); \
    S = d * rnk[J]; }
    RES(0, s0, j0) RES(1, s1, j1) RES(2, s2, j2) RES(3, s3, j3)
    RES(4, s4, j4) RES(5, s5, j5) RES(6, s6, j6) RES(7, s7, j7)
#undef RES
    int top[3];
#define BET(SV, JV) if (SV > bv || (SV == bv && JV < bi)) { bv = SV; bi = JV; }
#pragma unroll
    for (int k = 0; k < 3; ++k) {
        float bv = s0; int bi = j0;
        BET(s1, j1) BET(s2, j2) BET(s3, j3) BET(s4, j4)
        BET(s5, j5) BET(s6, j6) BET(s7, j7)
        top[k] = bi;
        if (j0 == bi) s0 = -3e38f;
        if (j1 == bi) s1 = -3e38f;
        if (j2 == bi) s2 = -3e38f;
        if (j3 == bi) s3 = -3e38f;
        if (j4 == bi) s4 = -3e38f;
        if (j5 == bi) s5 = -3e38f;
        if (j6 == bi) s6 = -3e38f;
        if (j7 == bi) s7 = -3e38f;
    }
#undef BET
    const float4 wa = *(const float4*)&Wa[lane << 2];
    float4 vr[3];
    float lg[3];
#pragma unroll
    for (int r = 0; r < 3; ++r) {
        const float4 v = *(const float4*)&values[(size_t)top[r] * 256 + (lane << 2)];
        vr[r] = v;
        float d = v.x * wa.x + v.y * wa.y + v.z * wa.z + v.w * wa.w;
#pragma unroll
        for (int o = 1; o < 64; o <<= 1) d += __shfl_xor(d, o);
        lg[r] = d + ba[0];
    }
    const float mx = fmaxf(lg[0], fmaxf(lg[1], lg[2]));
    float e0 = __expf(lg[0] - mx), e1 = __expf(lg[1] - mx), e2 = __expf(lg[2] - mx);
    const float inv = 1.f / (e0 + e1 + e2);
    e0 *= inv; e1 *= inv; e2 *= inv;
    float4 m;
    m.x = e0 * vr[0].x + e1 * vr[1].x + e2 * vr[2].x;
    m.y = e0 * vr[0].y + e1 * vr[1].y + e2 * vr[2].y;
    m.z = e0 * vr[0].z + e1 * vr[1].z + e2 * vr[2].z;
    m.w = e0 * vr[0].w + e1 * vr[1].w + e2 * vr[2].w;
    *(float4*)&mem_raw[(size_t)q * 256 + (lane << 2)] = m;
}

// ---------------------------------------------------------------------------
// gemm_bf16_nt: C[M,N] = concat(in1[.,K1], in2[.,K2]) @ Wm[N,K1+K2]^T + bias,
// bf16 MFMA (proven r19).
// ---------------------------------------------------------------------------
__global__ __launch_bounds__(256) void gemm_bf16_nt(
    const float* __restrict__ in1, int K1,
    const float* __restrict__ in2, int K2,
    const float* __restrict__ Wm,
    float* __restrict__ C, int N,
    const float* __restrict__ bias)
{
    __shared__ unsigned short a_lds[64 * 72];   // input rows (m), bf16, +8 pad
    __shared__ unsigned short w_lds[64 * 72];   // W rows (n), bf16, +8 pad
    const int t = threadIdx.x;
    const int wave = t >> 6, lane = t & 63;
    const int bn = blockIdx.x << 6, bm = blockIdx.y << 6;
    const int kg = lane >> 4;
    const int K = K1 + K2;

    f32x4 acc0 = {0.f, 0.f, 0.f, 0.f};
    f32x4 acc1 = {0.f, 0.f, 0.f, 0.f};
    f32x4 acc2 = {0.f, 0.f, 0.f, 0.f};
    f32x4 acc3 = {0.f, 0.f, 0.f, 0.f};

    const int srow = t >> 2, sc0 = (t & 3) << 4;   // staging: row, 16-col slice

    for (int kb = 0; kb < K; kb += 64) {
        __syncthreads();
        {
            const float* src; int ld; int col = kb + sc0;
            if (col < K1) { src = in1; ld = K1; } else { src = in2; ld = K2; col -= K1; }
            const float* p = &src[(size_t)(bm + srow) * ld + col];
#pragma unroll
            for (int i = 0; i < 4; ++i) {
                const float4 f = *(const float4*)(p + (i << 2));
                uint2 pk;
                pk.x = pack_bf16(f.x, f.y);
                pk.y = pack_bf16(f.z, f.w);
                *(uint2*)&a_lds[srow * 72 + sc0 + (i << 2)] = pk;
            }
            const float* pw = &Wm[(size_t)(bn + srow) * K + kb + sc0];
#pragma unroll
            for (int i = 0; i < 4; ++i) {
                const float4 f = *(const float4*)(pw + (i << 2));
                uint2 pk;
                pk.x = pack_bf16(f.x, f.y);
                pk.y = pack_bf16(f.z, f.w);
                *(uint2*)&w_lds[srow * 72 + sc0 + (i << 2)] = pk;
            }
        }
        __syncthreads();

#pragma unroll
        for (int ks = 0; ks < 2; ++ks) {
            const int koff = (ks << 5) + (kg << 3);
            const bf16x8 af = *(const bf16x8*)&w_lds[((wave << 4) + (lane & 15)) * 72 + koff];
            const bf16x8 b0 = *(const bf16x8*)&a_lds[((0 << 4) + (lane & 15)) * 72 + koff];
            const bf16x8 b1 = *(const bf16x8*)&a_lds[((1 << 4) + (lane & 15)) * 72 + koff];
            const bf16x8 b2 = *(const bf16x8*)&a_lds[((2 << 4) + (lane & 15)) * 72 + koff];
            const bf16x8 b3 = *(const bf16x8*)&a_lds[((3 << 4) + (lane & 15)) * 72 + koff];
            acc0 = __builtin_amdgcn_mfma_f32_16x16x32_bf16(af, b0, acc0, 0, 0, 0);
            acc1 = __builtin_amdgcn_mfma_f32_16x16x32_bf16(af, b1, acc1, 0, 0, 0);
            acc2 = __builtin_amdgcn_mfma_f32_16x16x32_bf16(af, b2, acc2, 0, 0, 0);
            acc3 = __builtin_amdgcn_mfma_f32_16x16x32_bf16(af, b3, acc3, 0, 0, 0);
        }
    }

    const int ncol = bn + (wave << 4) + (kg << 2);
    const float4 bv = *(const float4*)&bias[ncol];
#define EPI(MQ, ACC) do {                                              \
        const int m_ = bm + (MQ << 4) + (lane & 15);                   \
        float4 r_;                                                     \
        r_.x = ACC[0] + bv.x; r_.y = ACC[1] + bv.y;                    \
        r_.z = ACC[2] + bv.z; r_.w = ACC[3] + bv.w;                    \
        *(float4*)&C[(size_t)m_ * N + ncol] = r_;                      \
    } while (0)
    EPI(0, acc0);
    EPI(1, acc1);
    EPI(2, acc2);
    EPI(3, acc3);
#undef EPI
}

// ---------------------------------------------------------------------------
extern "C" void kernel_launch(void* const* d_in, const int* in_sizes, int n_in,
                              void* d_out, int out_size, void* d_ws, size_t ws_size,
                              hipStream_t stream)
{
    (void)in_sizes; (void)n_in; (void)out_size;
    const float* x     = (const float*)d_in[0];
    const float* keys  = (const float*)d_in[1];
    const float* values= (const float*)d_in[2];
    const float* imp   = (const float*)d_in[3];
    const float* W_ih  = (const float*)d_in[4];
    const float* W_hh  = (const float*)d_in[5];
    const float* b_ih  = (const float*)d_in[6];
    const float* b_hh  = (const float*)d_in[7];
    const float* Wq    = (const float*)d_in[8];
    const float* bq    = (const float*)d_in[9];
    const float* Wa    = (const float*)d_in[10];
    const float* ba    = (const float*)d_in[11];
    const float* Wc    = (const float*)d_in[12];
    const float* bc    = (const float*)d_in[13];
    const float* Wo    = (const float*)d_in[14];
    const float* bo    = (const float*)d_in[15];
    float* out = (float*)d_out;

    float* ws = (float*)d_ws;
    size_t o = 0;
    float* xp      = ws + o; o += (size_t)1024 * 4096;           // 16 MB
    float* h_all   = ws + o; o += (size_t)1024 * 1024;           // 4 MB
    unsigned* rec  = (unsigned*)(ws + o); o += 2 * 4096;         // tagged records
    float* rnk     = ws + o; o += NKEY;                          // imp/||key||
    float* qbuf    = ws + o; o += (size_t)ROWS * 256;
    float* qn      = ws + o; o += (size_t)ROWS * 256;
    float* part_v8 = ws + o; o += (size_t)ROWS * KSPLITS * 8;    // 2 MB
    int*   part_i8 = (int*)(ws + o); o += (size_t)ROWS * KSPLITS * 8;
    int*   cand8_i = (int*)(ws + o); o += ROWS * 8;
    float* mem_raw = ws + o; o += (size_t)ROWS * 256;
    float* memb    = ws + o; o += (size_t)ROWS * 256;
    unsigned short* kb = (unsigned short*)(ws + o);              // bf16 keys, 32 MB
    const size_t need_bf16 = (o + (size_t)NKEY * 256 / 2) * sizeof(float);
    const bool use_bf16 = ws_size >= need_bf16;                  // deterministic

    // zero records: slot-0 tag byte = 0 (= step-0 tag) with h = +0.0
    hipMemsetAsync(rec, 0, 2 * 4096 * 4, stream);

    // x_proj = x @ W_ih^T + b_ih + b_hh : [1024, 4096]
    sgemm_nt_w<<<dim3(32, 16), 256, 0, stream>>>(x, W_ih, xp, b_ih, b_hh);

    // LSTM recurrence (blocks 0-255) + key-prep riders (blocks 256-511)
    lstm_kernel<<<2 * NWG_LSTM, NTH_LSTM, 0, stream>>>(
        xp, W_hh, rec, h_all, keys, imp, rnk, use_bf16 ? kb : nullptr);

    // q = h @ Wq^T + bq : [1024, 256]  (fp32: selection-critical)
    sgemm_nt<<<dim3(4, 16), 256, 0, stream>>>(h_all, HD, Wq, HD, qbuf, MD, HD, bq, nullptr, 0);

    rownorm<<<ROWS / 4, 256, 0, stream>>>(qbuf, qn, ROWS);

    // bf16 MFMA candidate scoring (32x32) + fp32 rescore -> exact top-3
    if (use_bf16)
        sim_mfma_b32<<<dim3(KSPLITS, 8), 256, 0, stream>>>(qn, kb, part_v8, part_i8);
    else
        sim_mfma_f<<<dim3(KSPLITS, 16), 256, 0, stream>>>(qn, keys, rnk, part_v8, part_i8);
    cand_merge<<<32, 256, 0, stream>>>(part_v8, part_i8, cand8_i);
    rescore_gather<<<ROWS, 64, 0, stream>>>(qn, keys, rnk, cand8_i, values, Wa, ba, mem_raw);

    // mem = mem_raw @ Wc^T + bc  (bf16 MFMA; smooth path)
    gemm_bf16_nt<<<dim3(4, 16), 256, 0, stream>>>(mem_raw, MD, nullptr, 0, Wc, memb, MD, bc);

    // out = [h_all | memb] @ Wo^T + bo  (bf16 MFMA, single pass over K=1280)
    gemm_bf16_nt<<<dim3(8, 16), 256, 0, stream>>>(h_all, HD, memb, MD, Wo, out, OD, bo);
}